// Round 18
// baseline (574.392 us; speedup 1.0000x reference)
//
#include <hip/hip_runtime.h>
#include <math.h>

#define B_ 2
#define M_ 32768
#define N_ 4096
#define D_ 128
#define K_ 8
#define G_ 16            // cells per axis
#define NC_ 4096         // cells per batch
#define CW_ 0.0625f      // cell width

// ---------------- frozen selection semantics (verified R15) ----------------
//   sp2 = (z*z + y*y) + x*x            descending plain, no FMA
//   sg2 = (gz*gz + gy*gy) + gx*gx      descending plain, no FMA
//   dot = fma(gz,pz, fma(gy,py, gx*px))  ascending FMA chain
//   d2  = fma(dot,-2, sg2+sp2)          == (sg2+sp2) - 2*dot bitwise
//   dist= sqrtf(fmaxf(d2,0)); order by (dist, index) lexicographic
// ---------------------------------------------------------------------------

__device__ __forceinline__ void lex_insert(float d, int i, float* bd, int* bi)
{
    if (d < bd[7] || (d == bd[7] && i < bi[7])) {
        bd[7] = d; bi[7] = i;
#pragma unroll
        for (int u = 6; u >= 0; --u) {
            const bool sw = (bd[u+1] < bd[u]) ||
                            (bd[u+1] == bd[u] && bi[u+1] < bi[u]);
            if (sw) {
                float tf = bd[u]; bd[u] = bd[u+1]; bd[u+1] = tf;
                int   ti = bi[u]; bi[u] = bi[u+1]; bi[u+1] = ti;
            }
        }
    }
}

__device__ __forceinline__ void scan_range(
    int s, int e, const float4* __restrict__ p4, const int* __restrict__ sx,
    float gx, float gy, float gz, float sg2, float* bd, int* bi)
{
#pragma clang fp contract(off)
    for (int t = s; t < e; ++t) {
        const float4 pp = p4[t];
        const float dot  = fmaf(gz, pp.z, fmaf(gy, pp.y, gx * pp.x));
        const float d2   = fmaf(dot, -2.0f, sg2 + pp.w);
        const float dist = sqrtf(fmaxf(d2, 0.0f));
        lex_insert(dist, sx[t], bd, bi);
    }
}

__device__ __forceinline__ void fold_merge(float* bd, int* bi, int mask)
{
    float od[8]; int oi[8];
#pragma unroll
    for (int u = 0; u < 8; ++u) {
        od[u] = __shfl_xor(bd[u], mask);
        oi[u] = __shfl_xor(bi[u], mask);
    }
#pragma unroll
    for (int u = 0; u < 8; ++u) lex_insert(od[u], oi[u], bd, bi);
}

// ---------------------------- prep kernels ---------------------------------
__global__ __launch_bounds__(256) void prep_zero(int* __restrict__ hist)
{
    const int i = blockIdx.x * 256 + threadIdx.x;
    if (i < B_ * NC_) hist[i] = 0;
}

__global__ __launch_bounds__(256) void prep_hist(
    const float* __restrict__ pts, int* __restrict__ hist)
{
    const int i = blockIdx.x * 256 + threadIdx.x;
    if (i >= B_ * N_) return;
    const float x = pts[i*3+0], y = pts[i*3+1], z = pts[i*3+2];
    const int cx = min(G_-1, (int)(x * 16.0f));
    const int cy = min(G_-1, (int)(y * 16.0f));
    const int cz = min(G_-1, (int)(z * 16.0f));
    atomicAdd(&hist[(i >> 12) * NC_ + cz*256 + cy*16 + cx], 1);
}

__global__ __launch_bounds__(1024) void prep_scan(
    const int* __restrict__ hist, int* __restrict__ cstart, int* __restrict__ ccur)
{
    __shared__ int lds[1024];
    const int b = blockIdx.x, t = threadIdx.x;
    int v[4]; int s = 0;
#pragma unroll
    for (int j = 0; j < 4; ++j) { v[j] = hist[b*NC_ + t*4 + j]; s += v[j]; }
    lds[t] = s;
    __syncthreads();
    for (int off = 1; off < 1024; off <<= 1) {
        int x = (t >= off) ? lds[t - off] : 0;
        __syncthreads();
        lds[t] += x;
        __syncthreads();
    }
    int excl = lds[t] - s;
#pragma unroll
    for (int j = 0; j < 4; ++j) {
        cstart[b*(NC_+1) + t*4 + j] = excl;
        ccur[b*NC_ + t*4 + j] = excl;
        excl += v[j];
    }
    if (t == 1023) cstart[b*(NC_+1) + NC_] = excl;
}

__global__ __launch_bounds__(256) void prep_scatter(
    const float* __restrict__ pts, int* __restrict__ ccur,
    float4* __restrict__ p4s, int* __restrict__ sidx)
{
#pragma clang fp contract(off)
    const int i = blockIdx.x * 256 + threadIdx.x;
    if (i >= B_ * N_) return;
    const int b = i >> 12, loc = i & (N_-1);
    const float x = pts[i*3+0], y = pts[i*3+1], z = pts[i*3+2];
    const int cx = min(G_-1, (int)(x * 16.0f));
    const int cy = min(G_-1, (int)(y * 16.0f));
    const int cz = min(G_-1, (int)(z * 16.0f));
    const int pos = atomicAdd(&ccur[b*NC_ + cz*256 + cy*16 + cx], 1);
    float4 v; v.x = x; v.y = y; v.z = z;
    v.w = (z * z + y * y) + x * x;              // FROZEN descending plain
    p4s[b*N_ + pos] = v;
    sidx[b*N_ + pos] = loc;
}

// ------------------------------- knn ---------------------------------------
// Block 256 = 64 queries x 4 sub-lanes. Each sub scans 1/4 of the cell rows
// (x-runs are contiguous cid ranges -> one [start,end) per row). Sub lists are
// disjoint -> shfl_xor fold merge is exact. Expansion shells scanned into a
// FRESH list (disjoint from main) then folded+inserted. Exact because any
// unsearched point is > R*CW_ away (margin 1e-5 >> oracle-vs-geometry error).
__global__ __launch_bounds__(256) void knn_kernel(
    const float* __restrict__ grid_c, const float4* __restrict__ p4s,
    const int* __restrict__ sidx, const int* __restrict__ cstart,
    int* __restrict__ out_idx, float* __restrict__ out_w)
{
#pragma clang fp contract(off)
    __shared__ int ldsS[NC_ + 1];

    const int tid  = threadIdx.x;
    const int qloc = tid >> 2;
    const int sub  = tid & 3;
    const int q    = blockIdx.x * 64 + qloc;    // 32768 % 64 == 0 -> uniform b
    const int b    = q >> 15;

    for (int i = tid; i < NC_ + 1; i += 256) ldsS[i] = cstart[b*(NC_+1) + i];
    __syncthreads();

    const float gx = grid_c[q*3+0], gy = grid_c[q*3+1], gz = grid_c[q*3+2];
    const float sg2 = (gz * gz + gy * gy) + gx * gx;   // FROZEN descending
    const int cx = min(G_-1, (int)(gx * 16.0f));
    const int cy = min(G_-1, (int)(gy * 16.0f));
    const int cz = min(G_-1, (int)(gz * 16.0f));

    const float4* p4 = p4s + (size_t)b * N_;
    const int*    sx = sidx + (size_t)b * N_;

    float bd[8]; int bi[8];
#pragma unroll
    for (int u = 0; u < 8; ++u) { bd[u] = 3.4e38f; bi[u] = 0x7fffffff; }

    // base box R=2 (clamped), rows split by sub
    {
        int m = 0;
        const int z0 = max(0, cz-2), z1 = min(G_-1, cz+2);
        const int y0 = max(0, cy-2), y1 = min(G_-1, cy+2);
        const int x0 = max(0, cx-2), x1 = min(G_-1, cx+2);
        for (int zz = z0; zz <= z1; ++zz)
            for (int yy = y0; yy <= y1; ++yy) {
                if (((m++) & 3) != sub) continue;
                const int cb = zz*256 + yy*16;
                scan_range(ldsS[cb+x0], ldsS[cb+x1+1], p4, sx, gx, gy, gz, sg2, bd, bi);
            }
    }
    fold_merge(bd, bi, 1);
    fold_merge(bd, bi, 2);

    // ring expansion (rare); `need` is uniform across the 4-lane group
    int R = 2;
    while (R < G_ - 1) {
        const bool need = !(bd[7] < (float)R * CW_ - 1e-5f);
        if (!__any(need)) break;
        ++R;
        if (need) {
            float fd[8]; int fi[8];
#pragma unroll
            for (int u = 0; u < 8; ++u) { fd[u] = 3.4e38f; fi[u] = 0x7fffffff; }
            int m2 = 0;
            for (int zz = cz - R; zz <= cz + R; ++zz) {
                if (zz < 0 || zz > G_-1) continue;
                for (int yy = cy - R; yy <= cy + R; ++yy) {
                    if (yy < 0 || yy > G_-1) continue;
                    const int ch = max(abs(zz - cz), abs(yy - cy));
                    if (((m2++) & 3) != sub) continue;
                    const int cb = zz*256 + yy*16;
                    if (ch == R) {
                        const int x0 = max(0, cx-R), x1 = min(G_-1, cx+R);
                        scan_range(ldsS[cb+x0], ldsS[cb+x1+1], p4, sx, gx, gy, gz, sg2, fd, fi);
                    } else {
                        const int xl = cx - R, xr = cx + R;
                        if (xl >= 0)
                            scan_range(ldsS[cb+xl], ldsS[cb+xl+1], p4, sx, gx, gy, gz, sg2, fd, fi);
                        if (xr <= G_-1)
                            scan_range(ldsS[cb+xr], ldsS[cb+xr+1], p4, sx, gx, gy, gz, sg2, fd, fi);
                    }
                }
            }
            fold_merge(fd, fi, 1);
            fold_merge(fd, fi, 2);
#pragma unroll
            for (int u = 0; u < 8; ++u) lex_insert(fd[u], fi[u], bd, bi);
        }
    }

    if (sub == 0) {
        // FROZEN weight rounding: f32, sequential ascending sum
        float wk8[8];
#pragma unroll
        for (int u = 0; u < 8; ++u)
            wk8[u] = 1.0f / (bd[u] + 1e-6f);
        float wsum = wk8[0];
#pragma unroll
        for (int u = 1; u < 8; ++u) wsum = wsum + wk8[u];
        const float winv = 1.0f / wsum;
#pragma unroll
        for (int u = 0; u < 8; ++u) {
            out_idx[q * 8 + u] = bi[u];
            out_w[q * 8 + u]   = wk8[u] * winv;
        }
    }
}

// ------------------------------- gno (unchanged) ---------------------------
__global__ __launch_bounds__(256) void gno_kernel(
    const float* __restrict__ grid_c, const float* __restrict__ pts,
    const float* __restrict__ feats,
    const float* __restrict__ W1, const float* __restrict__ b1,
    const float* __restrict__ W2, const float* __restrict__ b2,
    const float* __restrict__ gmm, const float* __restrict__ bta,
    const int* __restrict__ kidx, const float* __restrict__ kw,
    float* __restrict__ out)
{
    __shared__ float sh[8][8][D_];
    __shared__ float srel[8][8][4];
    __shared__ float swt[8][8];
    __shared__ int   sid[8][8];

    const int tid = threadIdx.x;
    const int qb8 = blockIdx.x * 8;

    if (tid < 64) {
        const int qq = tid >> 3, k = tid & 7;
        const int gq = qb8 + qq;
        const int id = kidx[gq * 8 + k];
        sid[qq][k] = id;
        swt[qq][k] = kw[gq * 8 + k];
        const int bb = gq >> 15;
        const float* pp = pts + ((size_t)bb * N_ + id) * 3;
        srel[qq][k][0] = grid_c[gq * 3 + 0] - pp[0];
        srel[qq][k][1] = grid_c[gq * 3 + 1] - pp[1];
        srel[qq][k][2] = grid_c[gq * 3 + 2] - pp[2];
    }

    const int qs = tid >> 5;
    const int dg = tid & 31;

    const float4 w1r0 = *(const float4*)(W1 + dg * 4);
    const float4 w1r1 = *(const float4*)(W1 + D_ + dg * 4);
    const float4 w1r2 = *(const float4*)(W1 + 2 * D_ + dg * 4);
    const float4 w1bb = *(const float4*)(b1 + dg * 4);
    __syncthreads();

#pragma unroll
    for (int k = 0; k < 8; ++k) {
        const float rx = srel[qs][k][0];
        const float ry = srel[qs][k][1];
        const float rz = srel[qs][k][2];
        float hr[4];
        {
            float u0 = rx * w1r0.x + ry * w1r1.x + rz * w1r2.x + w1bb.x;
            float u1 = rx * w1r0.y + ry * w1r1.y + rz * w1r2.y + w1bb.y;
            float u2 = rx * w1r0.z + ry * w1r1.z + rz * w1r2.z + w1bb.z;
            float u3 = rx * w1r0.w + ry * w1r1.w + rz * w1r2.w + w1bb.w;
            hr[0] = 0.5f * u0 * (1.0f + erff(u0 * 0.70710678118654752f));
            hr[1] = 0.5f * u1 * (1.0f + erff(u1 * 0.70710678118654752f));
            hr[2] = 0.5f * u2 * (1.0f + erff(u2 * 0.70710678118654752f));
            hr[3] = 0.5f * u3 * (1.0f + erff(u3 * 0.70710678118654752f));
        }
        *(float4*)&sh[qs][k][dg * 4] = *(float4*)hr;
    }
    __syncthreads();

    float acc[8][4];
#pragma unroll
    for (int k = 0; k < 8; ++k)
#pragma unroll
        for (int c = 0; c < 4; ++c) acc[k][c] = 0.0f;

    const float* w2p = W2 + dg * 4;
    for (int j0 = 0; j0 < D_; j0 += 4) {
        float4 hv[8];
#pragma unroll
        for (int k = 0; k < 8; ++k)
            hv[k] = *(const float4*)&sh[qs][k][j0];
        const float4 wa = *(const float4*)(w2p + (size_t)j0 * D_);
        const float4 wb = *(const float4*)(w2p + (size_t)(j0 + 1) * D_);
        const float4 wc = *(const float4*)(w2p + (size_t)(j0 + 2) * D_);
        const float4 wd = *(const float4*)(w2p + (size_t)(j0 + 3) * D_);
#pragma unroll
        for (int k = 0; k < 8; ++k) {
            acc[k][0] += hv[k].x * wa.x; acc[k][1] += hv[k].x * wa.y;
            acc[k][2] += hv[k].x * wa.z; acc[k][3] += hv[k].x * wa.w;
            acc[k][0] += hv[k].y * wb.x; acc[k][1] += hv[k].y * wb.y;
            acc[k][2] += hv[k].y * wb.z; acc[k][3] += hv[k].y * wb.w;
            acc[k][0] += hv[k].z * wc.x; acc[k][1] += hv[k].z * wc.y;
            acc[k][2] += hv[k].z * wc.z; acc[k][3] += hv[k].z * wc.w;
            acc[k][0] += hv[k].w * wd.x; acc[k][1] += hv[k].w * wd.y;
            acc[k][2] += hv[k].w * wd.z; acc[k][3] += hv[k].w * wd.w;
        }
    }

    const int gq = qb8 + qs;
    const int bb = gq >> 15;
    const float4 b2v = *(const float4*)(b2 + dg * 4);

    float o0 = 0.0f, o1 = 0.0f, o2 = 0.0f, o3 = 0.0f;
#pragma unroll
    for (int k = 0; k < 8; ++k) {
        const float4 f =
            *(const float4*)(feats + ((size_t)bb * N_ + sid[qs][k]) * D_ + dg * 4);
        const float wk = swt[qs][k];
        o0 += wk * f.x * (acc[k][0] + b2v.x);
        o1 += wk * f.y * (acc[k][1] + b2v.y);
        o2 += wk * f.z * (acc[k][2] + b2v.z);
        o3 += wk * f.w * (acc[k][3] + b2v.w);
    }

    float s = o0 + o1 + o2 + o3;
#pragma unroll
    for (int off = 16; off > 0; off >>= 1) s += __shfl_xor(s, off, 32);
    const float mu = s * (1.0f / 128.0f);
    const float v0 = o0 - mu, v1 = o1 - mu, v2 = o2 - mu, v3 = o3 - mu;
    float vs = v0 * v0 + v1 * v1 + v2 * v2 + v3 * v3;
#pragma unroll
    for (int off = 16; off > 0; off >>= 1) vs += __shfl_xor(vs, off, 32);
    const float inv = 1.0f / sqrtf(vs * (1.0f / 128.0f) + 1e-5f);

    const float4 gv = *(const float4*)(gmm + dg * 4);
    const float4 bv = *(const float4*)(bta + dg * 4);
    float4 ov;
    ov.x = v0 * inv * gv.x + bv.x;
    ov.y = v1 * inv * gv.y + bv.y;
    ov.z = v2 * inv * gv.z + bv.z;
    ov.w = v3 * inv * gv.w + bv.w;
    *(float4*)(out + (size_t)gq * D_ + dg * 4) = ov;
}

// ---------------------------------------------------------------------------
extern "C" void kernel_launch(void* const* d_in, const int* in_sizes, int n_in,
                              void* d_out, int out_size, void* d_ws, size_t ws_size,
                              hipStream_t stream)
{
    (void)in_sizes; (void)n_in; (void)out_size; (void)ws_size;
    const float* grid_c = (const float*)d_in[0];
    const float* pts    = (const float*)d_in[1];
    const float* feats  = (const float*)d_in[2];
    const float* W1     = (const float*)d_in[3];
    const float* b1     = (const float*)d_in[4];
    const float* W2     = (const float*)d_in[5];
    const float* b2     = (const float*)d_in[6];
    const float* gmm    = (const float*)d_in[7];
    const float* bta    = (const float*)d_in[8];
    float* out = (float*)d_out;

    char* w = (char*)d_ws;
    int*    kidx   = (int*)(w);                       // 2 MB
    float*  kw     = (float*)(w + 2097152);           // 2 MB
    float4* p4s    = (float4*)(w + 4194304);          // 128 KB (16B aligned)
    int*    sidx   = (int*)(w + 4325376);             // 32 KB
    int*    cstart = (int*)(w + 4358144);             // 2*4097*4
    int*    ccur   = (int*)(w + 4390920);             // 32 KB
    int*    hist   = (int*)(w + 4423688);             // 32 KB

    prep_zero   <<<(B_ * NC_ + 255) / 256, 256, 0, stream>>>(hist);
    prep_hist   <<<(B_ * N_ + 255) / 256, 256, 0, stream>>>(pts, hist);
    prep_scan   <<<B_, 1024, 0, stream>>>(hist, cstart, ccur);
    prep_scatter<<<(B_ * N_ + 255) / 256, 256, 0, stream>>>(pts, ccur, p4s, sidx);
    knn_kernel  <<<(B_ * M_) / 64, 256, 0, stream>>>(grid_c, p4s, sidx, cstart, kidx, kw);
    gno_kernel  <<<(B_ * M_) / 8, 256, 0, stream>>>(grid_c, pts, feats, W1, b1,
                                                    W2, b2, gmm, bta, kidx, kw, out);
}

// Round 19
// 469.638 us; speedup vs baseline: 1.2231x; 1.2231x over previous
//
#include <hip/hip_runtime.h>
#include <math.h>

#define B_ 2
#define M_ 32768
#define N_ 4096
#define D_ 128
#define K_ 8
#define G_ 16            // cells per axis
#define NC_ 4096         // cells per batch
#define CW_ 0.0625f      // cell width

// ---------------- frozen selection semantics (verified R15) ----------------
//   sp2 = (z*z + y*y) + x*x            descending plain, no FMA
//   sg2 = (gz*gz + gy*gy) + gx*gx      descending plain, no FMA
//   dot = fma(gz,pz, fma(gy,py, gx*px))  ascending FMA chain
//   d2  = fma(dot,-2, sg2+sp2)          == (sg2+sp2) - 2*dot bitwise
//   dist= sqrtf(fmaxf(d2,0)); order by (dist, index) lexicographic
// ---------------------------------------------------------------------------

__device__ __forceinline__ void lex_insert(float d, int i, float* bd, int* bi)
{
    if (d < bd[7] || (d == bd[7] && i < bi[7])) {
        bd[7] = d; bi[7] = i;
#pragma unroll
        for (int u = 6; u >= 0; --u) {
            const bool sw = (bd[u+1] < bd[u]) ||
                            (bd[u+1] == bd[u] && bi[u+1] < bi[u]);
            if (sw) {
                float tf = bd[u]; bd[u] = bd[u+1]; bd[u+1] = tf;
                int   ti = bi[u]; bi[u] = bi[u+1]; bi[u+1] = ti;
            }
        }
    }
}

__device__ __forceinline__ void scan_range(
    int s, int e, const float4* __restrict__ p4, const int* __restrict__ sx,
    float gx, float gy, float gz, float sg2, float* bd, int* bi)
{
#pragma clang fp contract(off)
    for (int t = s; t < e; ++t) {
        const float4 pp = p4[t];
        const float dot  = fmaf(gz, pp.z, fmaf(gy, pp.y, gx * pp.x));
        const float d2   = fmaf(dot, -2.0f, sg2 + pp.w);
        const float dist = sqrtf(fmaxf(d2, 0.0f));
        lex_insert(dist, sx[t], bd, bi);
    }
}

__device__ __forceinline__ void fold_merge(float* bd, int* bi, int mask)
{
    float od[8]; int oi[8];
#pragma unroll
    for (int u = 0; u < 8; ++u) {
        od[u] = __shfl_xor(bd[u], mask);
        oi[u] = __shfl_xor(bi[u], mask);
    }
#pragma unroll
    for (int u = 0; u < 8; ++u) lex_insert(od[u], oi[u], bd, bi);
}

// ---------------------------- prep kernels ---------------------------------
__global__ __launch_bounds__(256) void prep_zero(int* __restrict__ a, int n)
{
    const int i = blockIdx.x * 256 + threadIdx.x;
    if (i < n) a[i] = 0;
}

__global__ __launch_bounds__(256) void prep_hist(
    const float* __restrict__ xyz, int n_per_b, int* __restrict__ hist)
{
    const int i = blockIdx.x * 256 + threadIdx.x;
    if (i >= B_ * n_per_b) return;
    const int b = i / n_per_b;
    const float x = xyz[i*3+0], y = xyz[i*3+1], z = xyz[i*3+2];
    const int cx = min(G_-1, (int)(x * 16.0f));
    const int cy = min(G_-1, (int)(y * 16.0f));
    const int cz = min(G_-1, (int)(z * 16.0f));
    atomicAdd(&hist[b * NC_ + cz*256 + cy*16 + cx], 1);
}

__global__ __launch_bounds__(1024) void prep_scan(
    const int* __restrict__ hist, int* __restrict__ cstart, int* __restrict__ ccur)
{
    __shared__ int lds[1024];
    const int b = blockIdx.x, t = threadIdx.x;
    int v[4]; int s = 0;
#pragma unroll
    for (int j = 0; j < 4; ++j) { v[j] = hist[b*NC_ + t*4 + j]; s += v[j]; }
    lds[t] = s;
    __syncthreads();
    for (int off = 1; off < 1024; off <<= 1) {
        int x = (t >= off) ? lds[t - off] : 0;
        __syncthreads();
        lds[t] += x;
        __syncthreads();
    }
    int excl = lds[t] - s;
#pragma unroll
    for (int j = 0; j < 4; ++j) {
        cstart[b*(NC_+1) + t*4 + j] = excl;
        ccur[b*NC_ + t*4 + j] = excl;
        excl += v[j];
    }
    if (t == 1023) cstart[b*(NC_+1) + NC_] = excl;
}

// points: pack float4(x,y,z,sp2) sorted by cell; sp2 FROZEN descending plain
__global__ __launch_bounds__(256) void prep_scatter_p(
    const float* __restrict__ pts, int* __restrict__ ccur,
    float4* __restrict__ p4s, int* __restrict__ sidx)
{
#pragma clang fp contract(off)
    const int i = blockIdx.x * 256 + threadIdx.x;
    if (i >= B_ * N_) return;
    const int b = i >> 12, loc = i & (N_-1);
    const float x = pts[i*3+0], y = pts[i*3+1], z = pts[i*3+2];
    const int cx = min(G_-1, (int)(x * 16.0f));
    const int cy = min(G_-1, (int)(y * 16.0f));
    const int cz = min(G_-1, (int)(z * 16.0f));
    const int pos = atomicAdd(&ccur[b*NC_ + cz*256 + cy*16 + cx], 1);
    float4 v; v.x = x; v.y = y; v.z = z;
    v.w = (z * z + y * y) + x * x;              // FROZEN descending plain
    p4s[b*N_ + pos] = v;
    sidx[b*N_ + pos] = loc;
}

// queries: pack float4(gx,gy,gz,sg2) sorted by cell; qmap -> original index
__global__ __launch_bounds__(256) void prep_scatter_q(
    const float* __restrict__ grid_c, int* __restrict__ qcur,
    float4* __restrict__ q4s, int* __restrict__ qmap)
{
#pragma clang fp contract(off)
    const int i = blockIdx.x * 256 + threadIdx.x;
    if (i >= B_ * M_) return;
    const int b = i >> 15;
    const float x = grid_c[i*3+0], y = grid_c[i*3+1], z = grid_c[i*3+2];
    const int cx = min(G_-1, (int)(x * 16.0f));
    const int cy = min(G_-1, (int)(y * 16.0f));
    const int cz = min(G_-1, (int)(z * 16.0f));
    const int pos = atomicAdd(&qcur[b*NC_ + cz*256 + cy*16 + cx], 1);
    float4 v; v.x = x; v.y = y; v.z = z;
    v.w = (z * z + y * y) + x * x;              // FROZEN descending plain
    q4s[(size_t)b*M_ + pos] = v;
    qmap[(size_t)b*M_ + pos] = i;
}

// ------------------------------- knn ---------------------------------------
// Block 256 = 64 SORTED queries x 4 sub-lanes. Queries cell-sorted -> a wave's
// 16 queries live in ~1 cell: identical row bounds (no divergence), identical
// candidate addresses (L1 broadcast), correlated expansion. Sub lists are
// disjoint -> shfl_xor fold merge exact; shells go to a fresh list. Exact
// because any unsearched point is > R*CW_ away (1e-5 margin >> f32 error).
__global__ __launch_bounds__(256) void knn_kernel(
    const float4* __restrict__ q4s, const int* __restrict__ qmap,
    const float4* __restrict__ p4s, const int* __restrict__ sidx,
    const int* __restrict__ cstart,
    int* __restrict__ out_idx, float* __restrict__ out_w)
{
#pragma clang fp contract(off)
    __shared__ int ldsS[NC_ + 1];

    const int tid  = threadIdx.x;
    const int qloc = tid >> 2;
    const int sub  = tid & 3;
    const int s    = blockIdx.x * 64 + qloc;    // sorted slot; uniform batch
    const int b    = s >> 15;

    for (int i = tid; i < NC_ + 1; i += 256) ldsS[i] = cstart[b*(NC_+1) + i];
    __syncthreads();

    const float4 qv = q4s[s];
    const float gx = qv.x, gy = qv.y, gz = qv.z;
    const float sg2 = qv.w;                     // FROZEN (computed at scatter)
    const int qorig = qmap[s];
    const int cx = min(G_-1, (int)(gx * 16.0f));
    const int cy = min(G_-1, (int)(gy * 16.0f));
    const int cz = min(G_-1, (int)(gz * 16.0f));

    const float4* p4 = p4s + (size_t)b * N_;
    const int*    sx = sidx + (size_t)b * N_;

    float bd[8]; int bi[8];
#pragma unroll
    for (int u = 0; u < 8; ++u) { bd[u] = 3.4e38f; bi[u] = 0x7fffffff; }

    // base box R=2 (clamped), rows split by sub
    {
        int m = 0;
        const int z0 = max(0, cz-2), z1 = min(G_-1, cz+2);
        const int y0 = max(0, cy-2), y1 = min(G_-1, cy+2);
        const int x0 = max(0, cx-2), x1 = min(G_-1, cx+2);
        for (int zz = z0; zz <= z1; ++zz)
            for (int yy = y0; yy <= y1; ++yy) {
                if (((m++) & 3) != sub) continue;
                const int cb = zz*256 + yy*16;
                scan_range(ldsS[cb+x0], ldsS[cb+x1+1], p4, sx, gx, gy, gz, sg2, bd, bi);
            }
    }
    fold_merge(bd, bi, 1);
    fold_merge(bd, bi, 2);

    // ring expansion; with sorted queries `need` is coherent across the wave
    int R = 2;
    while (R < G_ - 1) {
        const bool need = !(bd[7] < (float)R * CW_ - 1e-5f);
        if (!__any(need)) break;
        ++R;
        if (need) {
            float fd[8]; int fi[8];
#pragma unroll
            for (int u = 0; u < 8; ++u) { fd[u] = 3.4e38f; fi[u] = 0x7fffffff; }
            int m2 = 0;
            for (int zz = cz - R; zz <= cz + R; ++zz) {
                if (zz < 0 || zz > G_-1) continue;
                for (int yy = cy - R; yy <= cy + R; ++yy) {
                    if (yy < 0 || yy > G_-1) continue;
                    const int ch = max(abs(zz - cz), abs(yy - cy));
                    if (((m2++) & 3) != sub) continue;
                    const int cb = zz*256 + yy*16;
                    if (ch == R) {
                        const int x0 = max(0, cx-R), x1 = min(G_-1, cx+R);
                        scan_range(ldsS[cb+x0], ldsS[cb+x1+1], p4, sx, gx, gy, gz, sg2, fd, fi);
                    } else {
                        const int xl = cx - R, xr = cx + R;
                        if (xl >= 0)
                            scan_range(ldsS[cb+xl], ldsS[cb+xl+1], p4, sx, gx, gy, gz, sg2, fd, fi);
                        if (xr <= G_-1)
                            scan_range(ldsS[cb+xr], ldsS[cb+xr+1], p4, sx, gx, gy, gz, sg2, fd, fi);
                    }
                }
            }
            fold_merge(fd, fi, 1);
            fold_merge(fd, fi, 2);
#pragma unroll
            for (int u = 0; u < 8; ++u) lex_insert(fd[u], fi[u], bd, bi);
        }
    }

    if (sub == 0) {
        // FROZEN weight rounding: f32, sequential ascending sum
        float wk8[8];
#pragma unroll
        for (int u = 0; u < 8; ++u)
            wk8[u] = 1.0f / (bd[u] + 1e-6f);
        float wsum = wk8[0];
#pragma unroll
        for (int u = 1; u < 8; ++u) wsum = wsum + wk8[u];
        const float winv = 1.0f / wsum;
#pragma unroll
        for (int u = 0; u < 8; ++u) {
            out_idx[qorig * 8 + u] = bi[u];
            out_w[qorig * 8 + u]   = wk8[u] * winv;
        }
    }
}

// ------------------------------- gno (unchanged) ---------------------------
__global__ __launch_bounds__(256) void gno_kernel(
    const float* __restrict__ grid_c, const float* __restrict__ pts,
    const float* __restrict__ feats,
    const float* __restrict__ W1, const float* __restrict__ b1,
    const float* __restrict__ W2, const float* __restrict__ b2,
    const float* __restrict__ gmm, const float* __restrict__ bta,
    const int* __restrict__ kidx, const float* __restrict__ kw,
    float* __restrict__ out)
{
    __shared__ float sh[8][8][D_];
    __shared__ float srel[8][8][4];
    __shared__ float swt[8][8];
    __shared__ int   sid[8][8];

    const int tid = threadIdx.x;
    const int qb8 = blockIdx.x * 8;

    if (tid < 64) {
        const int qq = tid >> 3, k = tid & 7;
        const int gq = qb8 + qq;
        const int id = kidx[gq * 8 + k];
        sid[qq][k] = id;
        swt[qq][k] = kw[gq * 8 + k];
        const int bb = gq >> 15;
        const float* pp = pts + ((size_t)bb * N_ + id) * 3;
        srel[qq][k][0] = grid_c[gq * 3 + 0] - pp[0];
        srel[qq][k][1] = grid_c[gq * 3 + 1] - pp[1];
        srel[qq][k][2] = grid_c[gq * 3 + 2] - pp[2];
    }

    const int qs = tid >> 5;
    const int dg = tid & 31;

    const float4 w1r0 = *(const float4*)(W1 + dg * 4);
    const float4 w1r1 = *(const float4*)(W1 + D_ + dg * 4);
    const float4 w1r2 = *(const float4*)(W1 + 2 * D_ + dg * 4);
    const float4 w1bb = *(const float4*)(b1 + dg * 4);
    __syncthreads();

#pragma unroll
    for (int k = 0; k < 8; ++k) {
        const float rx = srel[qs][k][0];
        const float ry = srel[qs][k][1];
        const float rz = srel[qs][k][2];
        float hr[4];
        {
            float u0 = rx * w1r0.x + ry * w1r1.x + rz * w1r2.x + w1bb.x;
            float u1 = rx * w1r0.y + ry * w1r1.y + rz * w1r2.y + w1bb.y;
            float u2 = rx * w1r0.z + ry * w1r1.z + rz * w1r2.z + w1bb.z;
            float u3 = rx * w1r0.w + ry * w1r1.w + rz * w1r2.w + w1bb.w;
            hr[0] = 0.5f * u0 * (1.0f + erff(u0 * 0.70710678118654752f));
            hr[1] = 0.5f * u1 * (1.0f + erff(u1 * 0.70710678118654752f));
            hr[2] = 0.5f * u2 * (1.0f + erff(u2 * 0.70710678118654752f));
            hr[3] = 0.5f * u3 * (1.0f + erff(u3 * 0.70710678118654752f));
        }
        *(float4*)&sh[qs][k][dg * 4] = *(float4*)hr;
    }
    __syncthreads();

    float acc[8][4];
#pragma unroll
    for (int k = 0; k < 8; ++k)
#pragma unroll
        for (int c = 0; c < 4; ++c) acc[k][c] = 0.0f;

    const float* w2p = W2 + dg * 4;
    for (int j0 = 0; j0 < D_; j0 += 4) {
        float4 hv[8];
#pragma unroll
        for (int k = 0; k < 8; ++k)
            hv[k] = *(const float4*)&sh[qs][k][j0];
        const float4 wa = *(const float4*)(w2p + (size_t)j0 * D_);
        const float4 wb = *(const float4*)(w2p + (size_t)(j0 + 1) * D_);
        const float4 wc = *(const float4*)(w2p + (size_t)(j0 + 2) * D_);
        const float4 wd = *(const float4*)(w2p + (size_t)(j0 + 3) * D_);
#pragma unroll
        for (int k = 0; k < 8; ++k) {
            acc[k][0] += hv[k].x * wa.x; acc[k][1] += hv[k].x * wa.y;
            acc[k][2] += hv[k].x * wa.z; acc[k][3] += hv[k].x * wa.w;
            acc[k][0] += hv[k].y * wb.x; acc[k][1] += hv[k].y * wb.y;
            acc[k][2] += hv[k].y * wb.z; acc[k][3] += hv[k].y * wb.w;
            acc[k][0] += hv[k].z * wc.x; acc[k][1] += hv[k].z * wc.y;
            acc[k][2] += hv[k].z * wc.z; acc[k][3] += hv[k].z * wc.w;
            acc[k][0] += hv[k].w * wd.x; acc[k][1] += hv[k].w * wd.y;
            acc[k][2] += hv[k].w * wd.z; acc[k][3] += hv[k].w * wd.w;
        }
    }

    const int gq = qb8 + qs;
    const int bb = gq >> 15;
    const float4 b2v = *(const float4*)(b2 + dg * 4);

    float o0 = 0.0f, o1 = 0.0f, o2 = 0.0f, o3 = 0.0f;
#pragma unroll
    for (int k = 0; k < 8; ++k) {
        const float4 f =
            *(const float4*)(feats + ((size_t)bb * N_ + sid[qs][k]) * D_ + dg * 4);
        const float wk = swt[qs][k];
        o0 += wk * f.x * (acc[k][0] + b2v.x);
        o1 += wk * f.y * (acc[k][1] + b2v.y);
        o2 += wk * f.z * (acc[k][2] + b2v.z);
        o3 += wk * f.w * (acc[k][3] + b2v.w);
    }

    float s = o0 + o1 + o2 + o3;
#pragma unroll
    for (int off = 16; off > 0; off >>= 1) s += __shfl_xor(s, off, 32);
    const float mu = s * (1.0f / 128.0f);
    const float v0 = o0 - mu, v1 = o1 - mu, v2 = o2 - mu, v3 = o3 - mu;
    float vs = v0 * v0 + v1 * v1 + v2 * v2 + v3 * v3;
#pragma unroll
    for (int off = 16; off > 0; off >>= 1) vs += __shfl_xor(vs, off, 32);
    const float inv = 1.0f / sqrtf(vs * (1.0f / 128.0f) + 1e-5f);

    const float4 gv = *(const float4*)(gmm + dg * 4);
    const float4 bv = *(const float4*)(bta + dg * 4);
    float4 ov;
    ov.x = v0 * inv * gv.x + bv.x;
    ov.y = v1 * inv * gv.y + bv.y;
    ov.z = v2 * inv * gv.z + bv.z;
    ov.w = v3 * inv * gv.w + bv.w;
    *(float4*)(out + (size_t)gq * D_ + dg * 4) = ov;
}

// ---------------------------------------------------------------------------
extern "C" void kernel_launch(void* const* d_in, const int* in_sizes, int n_in,
                              void* d_out, int out_size, void* d_ws, size_t ws_size,
                              hipStream_t stream)
{
    (void)in_sizes; (void)n_in; (void)out_size; (void)ws_size;
    const float* grid_c = (const float*)d_in[0];
    const float* pts    = (const float*)d_in[1];
    const float* feats  = (const float*)d_in[2];
    const float* W1     = (const float*)d_in[3];
    const float* b1     = (const float*)d_in[4];
    const float* W2     = (const float*)d_in[5];
    const float* b2     = (const float*)d_in[6];
    const float* gmm    = (const float*)d_in[7];
    const float* bta    = (const float*)d_in[8];
    float* out = (float*)d_out;

    char* w = (char*)d_ws;
    int*    kidx   = (int*)(w);                  // 2 MB
    float*  kw     = (float*)(w + 2097152);      // 2 MB  -> 4194304
    float4* p4s    = (float4*)(w + 4194304);     // 128 KB -> 4325376
    float4* q4s    = (float4*)(w + 4325376);     // 1 MB  -> 5373952
    int*    sidx   = (int*)(w + 5373952);        // 32 KB -> 5406720
    int*    qmap   = (int*)(w + 5406720);        // 256 KB -> 5668864
    int*    cstart = (int*)(w + 5668864);        // 32.8 KB -> 5701640
    int*    qstart = (int*)(w + 5701640);        // 32.8 KB -> 5734416
    int*    ccur   = (int*)(w + 5734416);        // 32 KB -> 5767184
    int*    qcur   = (int*)(w + 5767184);        // 32 KB -> 5799952
    int*    hist   = (int*)(w + 5799952);        // 32 KB -> 5832720
    int*    qhist  = (int*)(w + 5832720);        // 32 KB -> 5865488

    prep_zero<<<(B_ * NC_ * 2 + 255) / 256, 256, 0, stream>>>(hist, B_ * NC_);
    prep_zero<<<(B_ * NC_ + 255) / 256, 256, 0, stream>>>(qhist, B_ * NC_);
    prep_hist<<<(B_ * N_ + 255) / 256, 256, 0, stream>>>(pts, N_, hist);
    prep_hist<<<(B_ * M_ + 255) / 256, 256, 0, stream>>>(grid_c, M_, qhist);
    prep_scan<<<B_, 1024, 0, stream>>>(hist, cstart, ccur);
    prep_scan<<<B_, 1024, 0, stream>>>(qhist, qstart, qcur);
    prep_scatter_p<<<(B_ * N_ + 255) / 256, 256, 0, stream>>>(pts, ccur, p4s, sidx);
    prep_scatter_q<<<(B_ * M_ + 255) / 256, 256, 0, stream>>>(grid_c, qcur, q4s, qmap);
    knn_kernel<<<(B_ * M_) / 64, 256, 0, stream>>>(q4s, qmap, p4s, sidx, cstart, kidx, kw);
    gno_kernel<<<(B_ * M_) / 8, 256, 0, stream>>>(grid_c, pts, feats, W1, b1,
                                                  W2, b2, gmm, bta, kidx, kw, out);
}

// Round 21
// 467.428 us; speedup vs baseline: 1.2288x; 1.0047x over previous
//
#include <hip/hip_runtime.h>
#include <math.h>

#define B_ 2
#define M_ 32768
#define N_ 4096
#define D_ 128
#define K_ 8
#define G_ 16
#define NC_ 4096
#define CW_ 0.0625f

// ---------------- frozen selection semantics (verified R15) ----------------
//   sp2 = (z*z + y*y) + x*x            descending plain, no FMA
//   sg2 = (gz*gz + gy*gy) + gx*gx      descending plain, no FMA
//   dot = fma(gz,pz, fma(gy,py, gx*px))  ascending FMA chain
//   d2  = fma(dot,-2, sg2+sp2)          == (sg2+sp2) - 2*dot bitwise
//   dist= sqrtf(fmaxf(d2,0)); order by (dist, index) lexicographic
// ---------------------------------------------------------------------------

__device__ __forceinline__ void lex_insert(float d, int i, float* bd, int* bi)
{
    if (d < bd[7] || (d == bd[7] && i < bi[7])) {
        bd[7] = d; bi[7] = i;
#pragma unroll
        for (int u = 6; u >= 0; --u) {
            const bool sw = (bd[u+1] < bd[u]) ||
                            (bd[u+1] == bd[u] && bi[u+1] < bi[u]);
            if (sw) {
                float tf = bd[u]; bd[u] = bd[u+1]; bd[u+1] = tf;
                int   ti = bi[u]; bi[u] = bi[u+1]; bi[u+1] = ti;
            }
        }
    }
}

__device__ __forceinline__ void scan_range(
    int s, int e, const float4* __restrict__ p4, const int* __restrict__ sx,
    float gx, float gy, float gz, float sg2, float* bd, int* bi)
{
#pragma clang fp contract(off)
    for (int t = s; t < e; ++t) {
        const float4 pp = p4[t];
        const float dot  = fmaf(gz, pp.z, fmaf(gy, pp.y, gx * pp.x));
        const float d2   = fmaf(dot, -2.0f, sg2 + pp.w);
        const float dist = sqrtf(fmaxf(d2, 0.0f));
        lex_insert(dist, sx[t], bd, bi);
    }
}

__device__ __forceinline__ void fold_merge(float* bd, int* bi, int mask)
{
    float od[8]; int oi[8];
#pragma unroll
    for (int u = 0; u < 8; ++u) {
        od[u] = __shfl_xor(bd[u], mask);
        oi[u] = __shfl_xor(bi[u], mask);
    }
#pragma unroll
    for (int u = 0; u < 8; ++u) lex_insert(od[u], oi[u], bd, bi);
}

// ---------------------------- prep kernels ---------------------------------
__global__ __launch_bounds__(256) void prep_zero(int* __restrict__ a, int n)
{
    const int i = blockIdx.x * 256 + threadIdx.x;
    if (i < n) a[i] = 0;
}

__global__ __launch_bounds__(256) void prep_hist(
    const float* __restrict__ xyz, int n_per_b, int* __restrict__ hist)
{
    const int i = blockIdx.x * 256 + threadIdx.x;
    if (i >= B_ * n_per_b) return;
    const int b = i / n_per_b;
    const float x = xyz[i*3+0], y = xyz[i*3+1], z = xyz[i*3+2];
    const int cx = min(G_-1, (int)(x * 16.0f));
    const int cy = min(G_-1, (int)(y * 16.0f));
    const int cz = min(G_-1, (int)(z * 16.0f));
    atomicAdd(&hist[b * NC_ + cz*256 + cy*16 + cx], 1);
}

__global__ __launch_bounds__(1024) void prep_scan(
    const int* __restrict__ hist, int* __restrict__ cstart, int* __restrict__ ccur)
{
    __shared__ int lds[1024];
    const int b = blockIdx.x, t = threadIdx.x;
    int v[4]; int s = 0;
#pragma unroll
    for (int j = 0; j < 4; ++j) { v[j] = hist[b*NC_ + t*4 + j]; s += v[j]; }
    lds[t] = s;
    __syncthreads();
    for (int off = 1; off < 1024; off <<= 1) {
        int x = (t >= off) ? lds[t - off] : 0;
        __syncthreads();
        lds[t] += x;
        __syncthreads();
    }
    int excl = lds[t] - s;
#pragma unroll
    for (int j = 0; j < 4; ++j) {
        cstart[b*(NC_+1) + t*4 + j] = excl;
        ccur[b*NC_ + t*4 + j] = excl;
        excl += v[j];
    }
    if (t == 1023) cstart[b*(NC_+1) + NC_] = excl;
}

__global__ __launch_bounds__(256) void prep_scatter_p(
    const float* __restrict__ pts, int* __restrict__ ccur,
    float4* __restrict__ p4s, int* __restrict__ sidx)
{
#pragma clang fp contract(off)
    const int i = blockIdx.x * 256 + threadIdx.x;
    if (i >= B_ * N_) return;
    const int b = i >> 12, loc = i & (N_-1);
    const float x = pts[i*3+0], y = pts[i*3+1], z = pts[i*3+2];
    const int cx = min(G_-1, (int)(x * 16.0f));
    const int cy = min(G_-1, (int)(y * 16.0f));
    const int cz = min(G_-1, (int)(z * 16.0f));
    const int pos = atomicAdd(&ccur[b*NC_ + cz*256 + cy*16 + cx], 1);
    float4 v; v.x = x; v.y = y; v.z = z;
    v.w = (z * z + y * y) + x * x;              // FROZEN descending plain
    p4s[b*N_ + pos] = v;
    sidx[b*N_ + pos] = loc;
}

__global__ __launch_bounds__(256) void prep_scatter_q(
    const float* __restrict__ grid_c, int* __restrict__ qcur,
    float4* __restrict__ q4s, int* __restrict__ qmap)
{
#pragma clang fp contract(off)
    const int i = blockIdx.x * 256 + threadIdx.x;
    if (i >= B_ * M_) return;
    const int b = i >> 15;
    const float x = grid_c[i*3+0], y = grid_c[i*3+1], z = grid_c[i*3+2];
    const int cx = min(G_-1, (int)(x * 16.0f));
    const int cy = min(G_-1, (int)(y * 16.0f));
    const int cz = min(G_-1, (int)(z * 16.0f));
    const int pos = atomicAdd(&qcur[b*NC_ + cz*256 + cy*16 + cx], 1);
    float4 v; v.x = x; v.y = y; v.z = z;
    v.w = (z * z + y * y) + x * x;              // FROZEN descending plain
    q4s[(size_t)b*M_ + pos] = v;
    qmap[(size_t)b*M_ + pos] = i;
}

// ------------------------------- knn ---------------------------------------
// Block 256 = 64 SORTED queries x 4 sub-lanes. cstart bounds read DIRECTLY
// from global (wave-coherent with sorted queries -> L1 broadcast); no LDS.
__global__ __launch_bounds__(256) void knn_kernel(
    const float4* __restrict__ q4s, const int* __restrict__ qmap,
    const float4* __restrict__ p4s, const int* __restrict__ sidx,
    const int* __restrict__ cstart,
    int* __restrict__ out_idx, float* __restrict__ out_w)
{
#pragma clang fp contract(off)
    const int tid  = threadIdx.x;
    const int qloc = tid >> 2;
    const int sub  = tid & 3;
    const int s    = blockIdx.x * 64 + qloc;
    const int b    = s >> 15;

    const int* __restrict__ cs = cstart + b * (NC_ + 1);

    const float4 qv = q4s[s];
    const float gx = qv.x, gy = qv.y, gz = qv.z;
    const float sg2 = qv.w;                     // FROZEN (computed at scatter)
    const int qorig = qmap[s];
    const int cx = min(G_-1, (int)(gx * 16.0f));
    const int cy = min(G_-1, (int)(gy * 16.0f));
    const int cz = min(G_-1, (int)(gz * 16.0f));

    const float4* p4 = p4s + (size_t)b * N_;
    const int*    sx = sidx + (size_t)b * N_;

    float bd[8]; int bi[8];
#pragma unroll
    for (int u = 0; u < 8; ++u) { bd[u] = 3.4e38f; bi[u] = 0x7fffffff; }

    // base box R=2 (clamped), rows split by sub
    {
        int m = 0;
        const int z0 = max(0, cz-2), z1 = min(G_-1, cz+2);
        const int y0 = max(0, cy-2), y1 = min(G_-1, cy+2);
        const int x0 = max(0, cx-2), x1 = min(G_-1, cx+2);
        for (int zz = z0; zz <= z1; ++zz)
            for (int yy = y0; yy <= y1; ++yy) {
                if (((m++) & 3) != sub) continue;
                const int cb = zz*256 + yy*16;
                scan_range(cs[cb+x0], cs[cb+x1+1], p4, sx, gx, gy, gz, sg2, bd, bi);
            }
    }
    fold_merge(bd, bi, 1);
    fold_merge(bd, bi, 2);

    // ring expansion; with sorted queries `need` is coherent across the wave
    int R = 2;
    while (R < G_ - 1) {
        const bool need = !(bd[7] < (float)R * CW_ - 1e-5f);
        if (!__any(need)) break;
        ++R;
        if (need) {
            float fd[8]; int fi[8];
#pragma unroll
            for (int u = 0; u < 8; ++u) { fd[u] = 3.4e38f; fi[u] = 0x7fffffff; }
            int m2 = 0;
            for (int zz = cz - R; zz <= cz + R; ++zz) {
                if (zz < 0 || zz > G_-1) continue;
                for (int yy = cy - R; yy <= cy + R; ++yy) {
                    if (yy < 0 || yy > G_-1) continue;
                    const int ch = max(abs(zz - cz), abs(yy - cy));
                    if (((m2++) & 3) != sub) continue;
                    const int cb = zz*256 + yy*16;
                    if (ch == R) {
                        const int x0 = max(0, cx-R), x1 = min(G_-1, cx+R);
                        scan_range(cs[cb+x0], cs[cb+x1+1], p4, sx, gx, gy, gz, sg2, fd, fi);
                    } else {
                        const int xl = cx - R, xr = cx + R;
                        if (xl >= 0)
                            scan_range(cs[cb+xl], cs[cb+xl+1], p4, sx, gx, gy, gz, sg2, fd, fi);
                        if (xr <= G_-1)
                            scan_range(cs[cb+xr], cs[cb+xr+1], p4, sx, gx, gy, gz, sg2, fd, fi);
                    }
                }
            }
            fold_merge(fd, fi, 1);
            fold_merge(fd, fi, 2);
#pragma unroll
            for (int u = 0; u < 8; ++u) lex_insert(fd[u], fi[u], bd, bi);
        }
    }

    if (sub == 0) {
        // FROZEN weight rounding: f32, sequential ascending sum
        float wk8[8];
#pragma unroll
        for (int u = 0; u < 8; ++u)
            wk8[u] = 1.0f / (bd[u] + 1e-6f);
        float wsum = wk8[0];
#pragma unroll
        for (int u = 1; u < 8; ++u) wsum = wsum + wk8[u];
        const float winv = 1.0f / wsum;
#pragma unroll
        for (int u = 0; u < 8; ++u) {
            out_idx[qorig * 8 + u] = bi[u];
            out_w[qorig * 8 + u]   = wk8[u] * winv;
        }
    }
}

// ------------------------------- gno (R19 verified version) ----------------
__global__ __launch_bounds__(256) void gno_kernel(
    const float* __restrict__ grid_c, const float* __restrict__ pts,
    const float* __restrict__ feats,
    const float* __restrict__ W1, const float* __restrict__ b1,
    const float* __restrict__ W2, const float* __restrict__ b2,
    const float* __restrict__ gmm, const float* __restrict__ bta,
    const int* __restrict__ kidx, const float* __restrict__ kw,
    float* __restrict__ out)
{
    __shared__ float sh[8][8][D_];
    __shared__ float srel[8][8][4];
    __shared__ float swt[8][8];
    __shared__ int   sid[8][8];

    const int tid = threadIdx.x;
    const int qb8 = blockIdx.x * 8;

    if (tid < 64) {
        const int qq = tid >> 3, k = tid & 7;
        const int gq = qb8 + qq;
        const int id = kidx[gq * 8 + k];
        sid[qq][k] = id;
        swt[qq][k] = kw[gq * 8 + k];
        const int bb = gq >> 15;
        const float* pp = pts + ((size_t)bb * N_ + id) * 3;
        srel[qq][k][0] = grid_c[gq * 3 + 0] - pp[0];
        srel[qq][k][1] = grid_c[gq * 3 + 1] - pp[1];
        srel[qq][k][2] = grid_c[gq * 3 + 2] - pp[2];
    }

    const int qs = tid >> 5;
    const int dg = tid & 31;

    const float4 w1r0 = *(const float4*)(W1 + dg * 4);
    const float4 w1r1 = *(const float4*)(W1 + D_ + dg * 4);
    const float4 w1r2 = *(const float4*)(W1 + 2 * D_ + dg * 4);
    const float4 w1bb = *(const float4*)(b1 + dg * 4);
    __syncthreads();

#pragma unroll
    for (int k = 0; k < 8; ++k) {
        const float rx = srel[qs][k][0];
        const float ry = srel[qs][k][1];
        const float rz = srel[qs][k][2];
        float hr[4];
        {
            float u0 = rx * w1r0.x + ry * w1r1.x + rz * w1r2.x + w1bb.x;
            float u1 = rx * w1r0.y + ry * w1r1.y + rz * w1r2.y + w1bb.y;
            float u2 = rx * w1r0.z + ry * w1r1.z + rz * w1r2.z + w1bb.z;
            float u3 = rx * w1r0.w + ry * w1r1.w + rz * w1r2.w + w1bb.w;
            hr[0] = 0.5f * u0 * (1.0f + erff(u0 * 0.70710678118654752f));
            hr[1] = 0.5f * u1 * (1.0f + erff(u1 * 0.70710678118654752f));
            hr[2] = 0.5f * u2 * (1.0f + erff(u2 * 0.70710678118654752f));
            hr[3] = 0.5f * u3 * (1.0f + erff(u3 * 0.70710678118654752f));
        }
        *(float4*)&sh[qs][k][dg * 4] = *(float4*)hr;
    }
    __syncthreads();

    float acc[8][4];
#pragma unroll
    for (int k = 0; k < 8; ++k)
#pragma unroll
        for (int c = 0; c < 4; ++c) acc[k][c] = 0.0f;

    const float* w2p = W2 + dg * 4;
    for (int j0 = 0; j0 < D_; j0 += 4) {
        float4 hv[8];
#pragma unroll
        for (int k = 0; k < 8; ++k)
            hv[k] = *(const float4*)&sh[qs][k][j0];
        const float4 wa = *(const float4*)(w2p + (size_t)j0 * D_);
        const float4 wb = *(const float4*)(w2p + (size_t)(j0 + 1) * D_);
        const float4 wc = *(const float4*)(w2p + (size_t)(j0 + 2) * D_);
        const float4 wd = *(const float4*)(w2p + (size_t)(j0 + 3) * D_);
#pragma unroll
        for (int k = 0; k < 8; ++k) {
            acc[k][0] += hv[k].x * wa.x; acc[k][1] += hv[k].x * wa.y;
            acc[k][2] += hv[k].x * wa.z; acc[k][3] += hv[k].x * wa.w;
            acc[k][0] += hv[k].y * wb.x; acc[k][1] += hv[k].y * wb.y;
            acc[k][2] += hv[k].y * wb.z; acc[k][3] += hv[k].y * wb.w;
            acc[k][0] += hv[k].z * wc.x; acc[k][1] += hv[k].z * wc.y;
            acc[k][2] += hv[k].z * wc.z; acc[k][3] += hv[k].z * wc.w;
            acc[k][0] += hv[k].w * wd.x; acc[k][1] += hv[k].w * wd.y;
            acc[k][2] += hv[k].w * wd.z; acc[k][3] += hv[k].w * wd.w;
        }
    }

    const int gq = qb8 + qs;
    const int bb = gq >> 15;
    const float4 b2v = *(const float4*)(b2 + dg * 4);

    float o0 = 0.0f, o1 = 0.0f, o2 = 0.0f, o3 = 0.0f;
#pragma unroll
    for (int k = 0; k < 8; ++k) {
        const float4 f =
            *(const float4*)(feats + ((size_t)bb * N_ + sid[qs][k]) * D_ + dg * 4);
        const float wk = swt[qs][k];
        o0 += wk * f.x * (acc[k][0] + b2v.x);
        o1 += wk * f.y * (acc[k][1] + b2v.y);
        o2 += wk * f.z * (acc[k][2] + b2v.z);
        o3 += wk * f.w * (acc[k][3] + b2v.w);
    }

    float s = o0 + o1 + o2 + o3;
#pragma unroll
    for (int off = 16; off > 0; off >>= 1) s += __shfl_xor(s, off, 32);
    const float mu = s * (1.0f / 128.0f);
    const float v0 = o0 - mu, v1 = o1 - mu, v2 = o2 - mu, v3 = o3 - mu;
    float vs = v0 * v0 + v1 * v1 + v2 * v2 + v3 * v3;
#pragma unroll
    for (int off = 16; off > 0; off >>= 1) vs += __shfl_xor(vs, off, 32);
    const float inv = 1.0f / sqrtf(vs * (1.0f / 128.0f) + 1e-5f);

    const float4 gv = *(const float4*)(gmm + dg * 4);
    const float4 bv = *(const float4*)(bta + dg * 4);
    float4 ov;
    ov.x = v0 * inv * gv.x + bv.x;
    ov.y = v1 * inv * gv.y + bv.y;
    ov.z = v2 * inv * gv.z + bv.z;
    ov.w = v3 * inv * gv.w + bv.w;
    *(float4*)(out + (size_t)gq * D_ + dg * 4) = ov;
}

// ---------------------------------------------------------------------------
extern "C" void kernel_launch(void* const* d_in, const int* in_sizes, int n_in,
                              void* d_out, int out_size, void* d_ws, size_t ws_size,
                              hipStream_t stream)
{
    (void)in_sizes; (void)n_in; (void)out_size; (void)ws_size;
    const float* grid_c = (const float*)d_in[0];
    const float* pts    = (const float*)d_in[1];
    const float* feats  = (const float*)d_in[2];
    const float* W1     = (const float*)d_in[3];
    const float* b1     = (const float*)d_in[4];
    const float* W2     = (const float*)d_in[5];
    const float* b2     = (const float*)d_in[6];
    const float* gmm    = (const float*)d_in[7];
    const float* bta    = (const float*)d_in[8];
    float* out = (float*)d_out;

    char* w = (char*)d_ws;
    int*    kidx   = (int*)(w);                  // 2 MB
    float*  kw     = (float*)(w + 2097152);      // 2 MB  -> 4194304
    float4* p4s    = (float4*)(w + 4194304);     // 128 KB -> 4325376
    float4* q4s    = (float4*)(w + 4325376);     // 1 MB  -> 5373952
    int*    sidx   = (int*)(w + 5373952);        // 32 KB -> 5406720
    int*    qmap   = (int*)(w + 5406720);        // 256 KB -> 5668864
    int*    cstart = (int*)(w + 5668864);        // -> 5701640
    int*    qstart = (int*)(w + 5701640);        // -> 5734416
    int*    ccur   = (int*)(w + 5734416);        // -> 5767184
    int*    qcur   = (int*)(w + 5767184);        // -> 5799952
    int*    hist   = (int*)(w + 5799952);        // -> 5832720
    int*    qhist  = (int*)(w + 5832720);        // -> 5865488  (hist+8192 ints)

    // hist and qhist are adjacent: one zero pass covers both
    prep_zero<<<(2 * B_ * NC_ + 255) / 256, 256, 0, stream>>>(hist, 2 * B_ * NC_);
    prep_hist<<<(B_ * N_ + 255) / 256, 256, 0, stream>>>(pts, N_, hist);
    prep_hist<<<(B_ * M_ + 255) / 256, 256, 0, stream>>>(grid_c, M_, qhist);
    prep_scan<<<B_, 1024, 0, stream>>>(hist, cstart, ccur);
    prep_scan<<<B_, 1024, 0, stream>>>(qhist, qstart, qcur);
    prep_scatter_p<<<(B_ * N_ + 255) / 256, 256, 0, stream>>>(pts, ccur, p4s, sidx);
    prep_scatter_q<<<(B_ * M_ + 255) / 256, 256, 0, stream>>>(grid_c, qcur, q4s, qmap);
    knn_kernel<<<(B_ * M_) / 64, 256, 0, stream>>>(q4s, qmap, p4s, sidx, cstart, kidx, kw);
    gno_kernel<<<(B_ * M_) / 8, 256, 0, stream>>>(grid_c, pts, feats, W1, b1,
                                                  W2, b2, gmm, bta, kidx, kw, out);
}

// Round 22
// 414.696 us; speedup vs baseline: 1.3851x; 1.1272x over previous
//
#include <hip/hip_runtime.h>
#include <math.h>

#define B_ 2
#define M_ 32768
#define N_ 4096
#define D_ 128
#define K_ 8
#define G_ 16
#define NC_ 4096
#define CW_ 0.0625f

// ---------------- frozen selection semantics (verified R15) ----------------
//   sp2 = (z*z + y*y) + x*x            descending plain, no FMA
//   sg2 = (gz*gz + gy*gy) + gx*gx      descending plain, no FMA
//   dot = fma(gz,pz, fma(gy,py, gx*px))  ascending FMA chain
//   d2  = fma(dot,-2, sg2+sp2)          == (sg2+sp2) - 2*dot bitwise
//   dist= sqrtf(fmaxf(d2,0)); order by (dist, index) lexicographic
// ---------------------------------------------------------------------------

__device__ __forceinline__ void lex_insert(float d, int i, float* bd, int* bi)
{
    if (d < bd[7] || (d == bd[7] && i < bi[7])) {
        bd[7] = d; bi[7] = i;
#pragma unroll
        for (int u = 6; u >= 0; --u) {
            const bool sw = (bd[u+1] < bd[u]) ||
                            (bd[u+1] == bd[u] && bi[u+1] < bi[u]);
            if (sw) {
                float tf = bd[u]; bd[u] = bd[u+1]; bd[u+1] = tf;
                int   ti = bi[u]; bi[u] = bi[u+1]; bi[u+1] = ti;
            }
        }
    }
}

__device__ __forceinline__ void scan_range(
    int s, int e, const float4* __restrict__ p4, const int* __restrict__ sx,
    float gx, float gy, float gz, float sg2, float* bd, int* bi)
{
#pragma clang fp contract(off)
    for (int t = s; t < e; ++t) {
        const float4 pp = p4[t];
        const float dot  = fmaf(gz, pp.z, fmaf(gy, pp.y, gx * pp.x));
        const float d2   = fmaf(dot, -2.0f, sg2 + pp.w);
        const float dist = sqrtf(fmaxf(d2, 0.0f));
        lex_insert(dist, sx[t], bd, bi);
    }
}

__device__ __forceinline__ void fold_merge(float* bd, int* bi, int mask)
{
    float od[8]; int oi[8];
#pragma unroll
    for (int u = 0; u < 8; ++u) {
        od[u] = __shfl_xor(bd[u], mask);
        oi[u] = __shfl_xor(bi[u], mask);
    }
#pragma unroll
    for (int u = 0; u < 8; ++u) lex_insert(od[u], oi[u], bd, bi);
}

// ---------------------------- prep kernels ---------------------------------
__global__ __launch_bounds__(256) void prep_zero(int* __restrict__ a, int n)
{
    const int i = blockIdx.x * 256 + threadIdx.x;
    if (i < n) a[i] = 0;
}

__global__ __launch_bounds__(256) void prep_hist(
    const float* __restrict__ xyz, int n_per_b, int* __restrict__ hist)
{
    const int i = blockIdx.x * 256 + threadIdx.x;
    if (i >= B_ * n_per_b) return;
    const int b = i / n_per_b;
    const float x = xyz[i*3+0], y = xyz[i*3+1], z = xyz[i*3+2];
    const int cx = min(G_-1, (int)(x * 16.0f));
    const int cy = min(G_-1, (int)(y * 16.0f));
    const int cz = min(G_-1, (int)(z * 16.0f));
    atomicAdd(&hist[b * NC_ + cz*256 + cy*16 + cx], 1);
}

__global__ __launch_bounds__(1024) void prep_scan(
    const int* __restrict__ hist, int* __restrict__ cstart, int* __restrict__ ccur)
{
    __shared__ int lds[1024];
    const int b = blockIdx.x, t = threadIdx.x;
    int v[4]; int s = 0;
#pragma unroll
    for (int j = 0; j < 4; ++j) { v[j] = hist[b*NC_ + t*4 + j]; s += v[j]; }
    lds[t] = s;
    __syncthreads();
    for (int off = 1; off < 1024; off <<= 1) {
        int x = (t >= off) ? lds[t - off] : 0;
        __syncthreads();
        lds[t] += x;
        __syncthreads();
    }
    int excl = lds[t] - s;
#pragma unroll
    for (int j = 0; j < 4; ++j) {
        cstart[b*(NC_+1) + t*4 + j] = excl;
        ccur[b*NC_ + t*4 + j] = excl;
        excl += v[j];
    }
    if (t == 1023) cstart[b*(NC_+1) + NC_] = excl;
}

__global__ __launch_bounds__(256) void prep_scatter_p(
    const float* __restrict__ pts, int* __restrict__ ccur,
    float4* __restrict__ p4s, int* __restrict__ sidx)
{
#pragma clang fp contract(off)
    const int i = blockIdx.x * 256 + threadIdx.x;
    if (i >= B_ * N_) return;
    const int b = i >> 12, loc = i & (N_-1);
    const float x = pts[i*3+0], y = pts[i*3+1], z = pts[i*3+2];
    const int cx = min(G_-1, (int)(x * 16.0f));
    const int cy = min(G_-1, (int)(y * 16.0f));
    const int cz = min(G_-1, (int)(z * 16.0f));
    const int pos = atomicAdd(&ccur[b*NC_ + cz*256 + cy*16 + cx], 1);
    float4 v; v.x = x; v.y = y; v.z = z;
    v.w = (z * z + y * y) + x * x;              // FROZEN descending plain
    p4s[b*N_ + pos] = v;
    sidx[b*N_ + pos] = loc;
}

__global__ __launch_bounds__(256) void prep_scatter_q(
    const float* __restrict__ grid_c, int* __restrict__ qcur,
    float4* __restrict__ q4s, int* __restrict__ qmap)
{
#pragma clang fp contract(off)
    const int i = blockIdx.x * 256 + threadIdx.x;
    if (i >= B_ * M_) return;
    const int b = i >> 15;
    const float x = grid_c[i*3+0], y = grid_c[i*3+1], z = grid_c[i*3+2];
    const int cx = min(G_-1, (int)(x * 16.0f));
    const int cy = min(G_-1, (int)(y * 16.0f));
    const int cz = min(G_-1, (int)(z * 16.0f));
    const int pos = atomicAdd(&qcur[b*NC_ + cz*256 + cy*16 + cx], 1);
    float4 v; v.x = x; v.y = y; v.z = z;
    v.w = (z * z + y * y) + x * x;              // FROZEN descending plain
    q4s[(size_t)b*M_ + pos] = v;
    qmap[(size_t)b*M_ + pos] = i;
}

// ------------------------------- knn ---------------------------------------
// Block 256 = 64 SORTED queries x 4 sub-lanes. Base-box rows are CHUNK-split
// across subs (r in [sub*nrows/4,(sub+1)*nrows/4)) so all 64 lanes scan
// concurrently — the old round-robin `continue` scheme serialized the 4 subs
// under alternating exec masks (25%-active waves). Sub row-sets stay disjoint
// -> fold_merge exactness and lex-(dist,idx) order preserved bit-for-bit.
__global__ __launch_bounds__(256) void knn_kernel(
    const float4* __restrict__ q4s, const int* __restrict__ qmap,
    const float4* __restrict__ p4s, const int* __restrict__ sidx,
    const int* __restrict__ cstart,
    int* __restrict__ out_idx, float* __restrict__ out_w)
{
#pragma clang fp contract(off)
    const int tid  = threadIdx.x;
    const int qloc = tid >> 2;
    const int sub  = tid & 3;
    const int s    = blockIdx.x * 64 + qloc;
    const int b    = s >> 15;

    const int* __restrict__ cs = cstart + b * (NC_ + 1);

    const float4 qv = q4s[s];
    const float gx = qv.x, gy = qv.y, gz = qv.z;
    const float sg2 = qv.w;                     // FROZEN (computed at scatter)
    const int qorig = qmap[s];
    const int cx = min(G_-1, (int)(gx * 16.0f));
    const int cy = min(G_-1, (int)(gy * 16.0f));
    const int cz = min(G_-1, (int)(gz * 16.0f));

    const float4* p4 = p4s + (size_t)b * N_;
    const int*    sx = sidx + (size_t)b * N_;

    float bd[8]; int bi[8];
#pragma unroll
    for (int u = 0; u < 8; ++u) { bd[u] = 3.4e38f; bi[u] = 0x7fffffff; }

    // base box R=2 (clamped); contiguous row chunks per sub, all lanes active
    {
        const int z0 = max(0, cz-2), z1 = min(G_-1, cz+2);
        const int y0 = max(0, cy-2), y1 = min(G_-1, cy+2);
        const int x0 = max(0, cx-2), x1 = min(G_-1, cx+2);
        const int ny = y1 - y0 + 1;
        const int nrows = (z1 - z0 + 1) * ny;
        const int r0 = (sub * nrows) >> 2;
        const int r1 = ((sub + 1) * nrows) >> 2;
        int zz = z0 + r0 / ny;
        int yy = y0 + r0 % ny;
        for (int r = r0; r < r1; ++r) {
            const int cb = zz*256 + yy*16;
            scan_range(cs[cb+x0], cs[cb+x1+1], p4, sx, gx, gy, gz, sg2, bd, bi);
            if (++yy > y1) { yy = y0; ++zz; }
        }
    }
    fold_merge(bd, bi, 1);
    fold_merge(bd, bi, 2);

    // ring expansion (rare; sorted queries -> wave-coherent `need`)
    int R = 2;
    while (R < G_ - 1) {
        const bool need = !(bd[7] < (float)R * CW_ - 1e-5f);
        if (!__any(need)) break;
        ++R;
        if (need) {
            float fd[8]; int fi[8];
#pragma unroll
            for (int u = 0; u < 8; ++u) { fd[u] = 3.4e38f; fi[u] = 0x7fffffff; }
            int m2 = 0;
            for (int zz = cz - R; zz <= cz + R; ++zz) {
                if (zz < 0 || zz > G_-1) continue;
                for (int yy = cy - R; yy <= cy + R; ++yy) {
                    if (yy < 0 || yy > G_-1) continue;
                    const int ch = max(abs(zz - cz), abs(yy - cy));
                    if (((m2++) & 3) != sub) continue;
                    const int cb = zz*256 + yy*16;
                    if (ch == R) {
                        const int x0 = max(0, cx-R), x1 = min(G_-1, cx+R);
                        scan_range(cs[cb+x0], cs[cb+x1+1], p4, sx, gx, gy, gz, sg2, fd, fi);
                    } else {
                        const int xl = cx - R, xr = cx + R;
                        if (xl >= 0)
                            scan_range(cs[cb+xl], cs[cb+xl+1], p4, sx, gx, gy, gz, sg2, fd, fi);
                        if (xr <= G_-1)
                            scan_range(cs[cb+xr], cs[cb+xr+1], p4, sx, gx, gy, gz, sg2, fd, fi);
                    }
                }
            }
            fold_merge(fd, fi, 1);
            fold_merge(fd, fi, 2);
#pragma unroll
            for (int u = 0; u < 8; ++u) lex_insert(fd[u], fi[u], bd, bi);
        }
    }

    if (sub == 0) {
        // FROZEN weight rounding: f32, sequential ascending sum
        float wk8[8];
#pragma unroll
        for (int u = 0; u < 8; ++u)
            wk8[u] = 1.0f / (bd[u] + 1e-6f);
        float wsum = wk8[0];
#pragma unroll
        for (int u = 1; u < 8; ++u) wsum = wsum + wk8[u];
        const float winv = 1.0f / wsum;
#pragma unroll
        for (int u = 0; u < 8; ++u) {
            out_idx[qorig * 8 + u] = bi[u];
            out_w[qorig * 8 + u]   = wk8[u] * winv;
        }
    }
}

// ------------------------------- gno (R19 verified version) ----------------
__global__ __launch_bounds__(256) void gno_kernel(
    const float* __restrict__ grid_c, const float* __restrict__ pts,
    const float* __restrict__ feats,
    const float* __restrict__ W1, const float* __restrict__ b1,
    const float* __restrict__ W2, const float* __restrict__ b2,
    const float* __restrict__ gmm, const float* __restrict__ bta,
    const int* __restrict__ kidx, const float* __restrict__ kw,
    float* __restrict__ out)
{
    __shared__ float sh[8][8][D_];
    __shared__ float srel[8][8][4];
    __shared__ float swt[8][8];
    __shared__ int   sid[8][8];

    const int tid = threadIdx.x;
    const int qb8 = blockIdx.x * 8;

    if (tid < 64) {
        const int qq = tid >> 3, k = tid & 7;
        const int gq = qb8 + qq;
        const int id = kidx[gq * 8 + k];
        sid[qq][k] = id;
        swt[qq][k] = kw[gq * 8 + k];
        const int bb = gq >> 15;
        const float* pp = pts + ((size_t)bb * N_ + id) * 3;
        srel[qq][k][0] = grid_c[gq * 3 + 0] - pp[0];
        srel[qq][k][1] = grid_c[gq * 3 + 1] - pp[1];
        srel[qq][k][2] = grid_c[gq * 3 + 2] - pp[2];
    }

    const int qs = tid >> 5;
    const int dg = tid & 31;

    const float4 w1r0 = *(const float4*)(W1 + dg * 4);
    const float4 w1r1 = *(const float4*)(W1 + D_ + dg * 4);
    const float4 w1r2 = *(const float4*)(W1 + 2 * D_ + dg * 4);
    const float4 w1bb = *(const float4*)(b1 + dg * 4);
    __syncthreads();

#pragma unroll
    for (int k = 0; k < 8; ++k) {
        const float rx = srel[qs][k][0];
        const float ry = srel[qs][k][1];
        const float rz = srel[qs][k][2];
        float hr[4];
        {
            float u0 = rx * w1r0.x + ry * w1r1.x + rz * w1r2.x + w1bb.x;
            float u1 = rx * w1r0.y + ry * w1r1.y + rz * w1r2.y + w1bb.y;
            float u2 = rx * w1r0.z + ry * w1r1.z + rz * w1r2.z + w1bb.z;
            float u3 = rx * w1r0.w + ry * w1r1.w + rz * w1r2.w + w1bb.w;
            hr[0] = 0.5f * u0 * (1.0f + erff(u0 * 0.70710678118654752f));
            hr[1] = 0.5f * u1 * (1.0f + erff(u1 * 0.70710678118654752f));
            hr[2] = 0.5f * u2 * (1.0f + erff(u2 * 0.70710678118654752f));
            hr[3] = 0.5f * u3 * (1.0f + erff(u3 * 0.70710678118654752f));
        }
        *(float4*)&sh[qs][k][dg * 4] = *(float4*)hr;
    }
    __syncthreads();

    float acc[8][4];
#pragma unroll
    for (int k = 0; k < 8; ++k)
#pragma unroll
        for (int c = 0; c < 4; ++c) acc[k][c] = 0.0f;

    const float* w2p = W2 + dg * 4;
    for (int j0 = 0; j0 < D_; j0 += 4) {
        float4 hv[8];
#pragma unroll
        for (int k = 0; k < 8; ++k)
            hv[k] = *(const float4*)&sh[qs][k][j0];
        const float4 wa = *(const float4*)(w2p + (size_t)j0 * D_);
        const float4 wb = *(const float4*)(w2p + (size_t)(j0 + 1) * D_);
        const float4 wc = *(const float4*)(w2p + (size_t)(j0 + 2) * D_);
        const float4 wd = *(const float4*)(w2p + (size_t)(j0 + 3) * D_);
#pragma unroll
        for (int k = 0; k < 8; ++k) {
            acc[k][0] += hv[k].x * wa.x; acc[k][1] += hv[k].x * wa.y;
            acc[k][2] += hv[k].x * wa.z; acc[k][3] += hv[k].x * wa.w;
            acc[k][0] += hv[k].y * wb.x; acc[k][1] += hv[k].y * wb.y;
            acc[k][2] += hv[k].y * wb.z; acc[k][3] += hv[k].y * wb.w;
            acc[k][0] += hv[k].z * wc.x; acc[k][1] += hv[k].z * wc.y;
            acc[k][2] += hv[k].z * wc.z; acc[k][3] += hv[k].z * wc.w;
            acc[k][0] += hv[k].w * wd.x; acc[k][1] += hv[k].w * wd.y;
            acc[k][2] += hv[k].w * wd.z; acc[k][3] += hv[k].w * wd.w;
        }
    }

    const int gq = qb8 + qs;
    const int bb = gq >> 15;
    const float4 b2v = *(const float4*)(b2 + dg * 4);

    float o0 = 0.0f, o1 = 0.0f, o2 = 0.0f, o3 = 0.0f;
#pragma unroll
    for (int k = 0; k < 8; ++k) {
        const float4 f =
            *(const float4*)(feats + ((size_t)bb * N_ + sid[qs][k]) * D_ + dg * 4);
        const float wk = swt[qs][k];
        o0 += wk * f.x * (acc[k][0] + b2v.x);
        o1 += wk * f.y * (acc[k][1] + b2v.y);
        o2 += wk * f.z * (acc[k][2] + b2v.z);
        o3 += wk * f.w * (acc[k][3] + b2v.w);
    }

    float s = o0 + o1 + o2 + o3;
#pragma unroll
    for (int off = 16; off > 0; off >>= 1) s += __shfl_xor(s, off, 32);
    const float mu = s * (1.0f / 128.0f);
    const float v0 = o0 - mu, v1 = o1 - mu, v2 = o2 - mu, v3 = o3 - mu;
    float vs = v0 * v0 + v1 * v1 + v2 * v2 + v3 * v3;
#pragma unroll
    for (int off = 16; off > 0; off >>= 1) vs += __shfl_xor(vs, off, 32);
    const float inv = 1.0f / sqrtf(vs * (1.0f / 128.0f) + 1e-5f);

    const float4 gv = *(const float4*)(gmm + dg * 4);
    const float4 bv = *(const float4*)(bta + dg * 4);
    float4 ov;
    ov.x = v0 * inv * gv.x + bv.x;
    ov.y = v1 * inv * gv.y + bv.y;
    ov.z = v2 * inv * gv.z + bv.z;
    ov.w = v3 * inv * gv.w + bv.w;
    *(float4*)(out + (size_t)gq * D_ + dg * 4) = ov;
}

// ---------------------------------------------------------------------------
extern "C" void kernel_launch(void* const* d_in, const int* in_sizes, int n_in,
                              void* d_out, int out_size, void* d_ws, size_t ws_size,
                              hipStream_t stream)
{
    (void)in_sizes; (void)n_in; (void)out_size; (void)ws_size;
    const float* grid_c = (const float*)d_in[0];
    const float* pts    = (const float*)d_in[1];
    const float* feats  = (const float*)d_in[2];
    const float* W1     = (const float*)d_in[3];
    const float* b1     = (const float*)d_in[4];
    const float* W2     = (const float*)d_in[5];
    const float* b2     = (const float*)d_in[6];
    const float* gmm    = (const float*)d_in[7];
    const float* bta    = (const float*)d_in[8];
    float* out = (float*)d_out;

    char* w = (char*)d_ws;
    int*    kidx   = (int*)(w);                  // 2 MB
    float*  kw     = (float*)(w + 2097152);      // 2 MB  -> 4194304
    float4* p4s    = (float4*)(w + 4194304);     // 128 KB -> 4325376
    float4* q4s    = (float4*)(w + 4325376);     // 1 MB  -> 5373952
    int*    sidx   = (int*)(w + 5373952);        // 32 KB -> 5406720
    int*    qmap   = (int*)(w + 5406720);        // 256 KB -> 5668864
    int*    cstart = (int*)(w + 5668864);        // -> 5701640
    int*    qstart = (int*)(w + 5701640);        // -> 5734416
    int*    ccur   = (int*)(w + 5734416);        // -> 5767184
    int*    qcur   = (int*)(w + 5767184);        // -> 5799952
    int*    hist   = (int*)(w + 5799952);        // -> 5832720
    int*    qhist  = (int*)(w + 5832720);        // -> 5865488  (hist+8192 ints)

    prep_zero<<<(2 * B_ * NC_ + 255) / 256, 256, 0, stream>>>(hist, 2 * B_ * NC_);
    prep_hist<<<(B_ * N_ + 255) / 256, 256, 0, stream>>>(pts, N_, hist);
    prep_hist<<<(B_ * M_ + 255) / 256, 256, 0, stream>>>(grid_c, M_, qhist);
    prep_scan<<<B_, 1024, 0, stream>>>(hist, cstart, ccur);
    prep_scan<<<B_, 1024, 0, stream>>>(qhist, qstart, qcur);
    prep_scatter_p<<<(B_ * N_ + 255) / 256, 256, 0, stream>>>(pts, ccur, p4s, sidx);
    prep_scatter_q<<<(B_ * M_ + 255) / 256, 256, 0, stream>>>(grid_c, qcur, q4s, qmap);
    knn_kernel<<<(B_ * M_) / 64, 256, 0, stream>>>(q4s, qmap, p4s, sidx, cstart, kidx, kw);
    gno_kernel<<<(B_ * M_) / 8, 256, 0, stream>>>(grid_c, pts, feats, W1, b1,
                                                  W2, b2, gmm, bta, kidx, kw, out);
}

// Round 23
// 362.120 us; speedup vs baseline: 1.5862x; 1.1452x over previous
//
#include <hip/hip_runtime.h>
#include <math.h>

#define B_ 2
#define M_ 32768
#define N_ 4096
#define D_ 128
#define K_ 8
#define G_ 16
#define NC_ 4096
#define CW_ 0.0625f

typedef _Float16 half4_t __attribute__((ext_vector_type(4)));
typedef float f32x4 __attribute__((ext_vector_type(4)));

// ---------------- frozen selection semantics (verified R15) ----------------
__device__ __forceinline__ void lex_insert(float d, int i, float* bd, int* bi)
{
    if (d < bd[7] || (d == bd[7] && i < bi[7])) {
        bd[7] = d; bi[7] = i;
#pragma unroll
        for (int u = 6; u >= 0; --u) {
            const bool sw = (bd[u+1] < bd[u]) ||
                            (bd[u+1] == bd[u] && bi[u+1] < bi[u]);
            if (sw) {
                float tf = bd[u]; bd[u] = bd[u+1]; bd[u+1] = tf;
                int   ti = bi[u]; bi[u] = bi[u+1]; bi[u+1] = ti;
            }
        }
    }
}

__device__ __forceinline__ void scan_range(
    int s, int e, const float4* __restrict__ p4, const int* __restrict__ sx,
    float gx, float gy, float gz, float sg2, float* bd, int* bi)
{
#pragma clang fp contract(off)
    for (int t = s; t < e; ++t) {
        const float4 pp = p4[t];
        const float dot  = fmaf(gz, pp.z, fmaf(gy, pp.y, gx * pp.x));
        const float d2   = fmaf(dot, -2.0f, sg2 + pp.w);
        const float dist = sqrtf(fmaxf(d2, 0.0f));
        lex_insert(dist, sx[t], bd, bi);
    }
}

__device__ __forceinline__ void fold_merge(float* bd, int* bi, int mask)
{
    float od[8]; int oi[8];
#pragma unroll
    for (int u = 0; u < 8; ++u) {
        od[u] = __shfl_xor(bd[u], mask);
        oi[u] = __shfl_xor(bi[u], mask);
    }
#pragma unroll
    for (int u = 0; u < 8; ++u) lex_insert(od[u], oi[u], bd, bi);
}

// ---------------------------- prep kernels ---------------------------------
__global__ __launch_bounds__(256) void prep_zero(int* __restrict__ a, int n)
{
    const int i = blockIdx.x * 256 + threadIdx.x;
    if (i < n) a[i] = 0;
}

__global__ __launch_bounds__(256) void prep_hist(
    const float* __restrict__ xyz, int n_per_b, int* __restrict__ hist)
{
    const int i = blockIdx.x * 256 + threadIdx.x;
    if (i >= B_ * n_per_b) return;
    const int b = i / n_per_b;
    const float x = xyz[i*3+0], y = xyz[i*3+1], z = xyz[i*3+2];
    const int cx = min(G_-1, (int)(x * 16.0f));
    const int cy = min(G_-1, (int)(y * 16.0f));
    const int cz = min(G_-1, (int)(z * 16.0f));
    atomicAdd(&hist[b * NC_ + cz*256 + cy*16 + cx], 1);
}

__global__ __launch_bounds__(1024) void prep_scan(
    const int* __restrict__ hist, int* __restrict__ cstart, int* __restrict__ ccur)
{
    __shared__ int lds[1024];
    const int b = blockIdx.x, t = threadIdx.x;
    int v[4]; int s = 0;
#pragma unroll
    for (int j = 0; j < 4; ++j) { v[j] = hist[b*NC_ + t*4 + j]; s += v[j]; }
    lds[t] = s;
    __syncthreads();
    for (int off = 1; off < 1024; off <<= 1) {
        int x = (t >= off) ? lds[t - off] : 0;
        __syncthreads();
        lds[t] += x;
        __syncthreads();
    }
    int excl = lds[t] - s;
#pragma unroll
    for (int j = 0; j < 4; ++j) {
        cstart[b*(NC_+1) + t*4 + j] = excl;
        ccur[b*NC_ + t*4 + j] = excl;
        excl += v[j];
    }
    if (t == 1023) cstart[b*(NC_+1) + NC_] = excl;
}

__global__ __launch_bounds__(256) void prep_scatter_p(
    const float* __restrict__ pts, int* __restrict__ ccur,
    float4* __restrict__ p4s, int* __restrict__ sidx)
{
#pragma clang fp contract(off)
    const int i = blockIdx.x * 256 + threadIdx.x;
    if (i >= B_ * N_) return;
    const int b = i >> 12, loc = i & (N_-1);
    const float x = pts[i*3+0], y = pts[i*3+1], z = pts[i*3+2];
    const int cx = min(G_-1, (int)(x * 16.0f));
    const int cy = min(G_-1, (int)(y * 16.0f));
    const int cz = min(G_-1, (int)(z * 16.0f));
    const int pos = atomicAdd(&ccur[b*NC_ + cz*256 + cy*16 + cx], 1);
    float4 v; v.x = x; v.y = y; v.z = z;
    v.w = (z * z + y * y) + x * x;              // FROZEN descending plain
    p4s[b*N_ + pos] = v;
    sidx[b*N_ + pos] = loc;
}

__global__ __launch_bounds__(256) void prep_scatter_q(
    const float* __restrict__ grid_c, int* __restrict__ qcur,
    float4* __restrict__ q4s, int* __restrict__ qmap)
{
#pragma clang fp contract(off)
    const int i = blockIdx.x * 256 + threadIdx.x;
    if (i >= B_ * M_) return;
    const int b = i >> 15;
    const float x = grid_c[i*3+0], y = grid_c[i*3+1], z = grid_c[i*3+2];
    const int cx = min(G_-1, (int)(x * 16.0f));
    const int cy = min(G_-1, (int)(y * 16.0f));
    const int cz = min(G_-1, (int)(z * 16.0f));
    const int pos = atomicAdd(&qcur[b*NC_ + cz*256 + cy*16 + cx], 1);
    float4 v; v.x = x; v.y = y; v.z = z;
    v.w = (z * z + y * y) + x * x;              // FROZEN descending plain
    q4s[(size_t)b*M_ + pos] = v;
    qmap[(size_t)b*M_ + pos] = i;
}

// W2T f16 hi/lo: w2t[n*128+k] = split(W2[k][n]);  hi+lo carries ~22 mantissa
// bits (f16 has 11), so 3-product MFMA reconstruction has ~2^-22 rel error.
__global__ __launch_bounds__(256) void prep_w2t(
    const float* __restrict__ W2,
    _Float16* __restrict__ w2t_hi, _Float16* __restrict__ w2t_lo)
{
    const int i = blockIdx.x * 256 + threadIdx.x;
    if (i >= D_ * D_) return;
    const int n = i >> 7, k = i & 127;
    const float w = W2[k * D_ + n];
    const _Float16 hi = (_Float16)w;
    w2t_hi[i] = hi;
    w2t_lo[i] = (_Float16)(w - (float)hi);
}

// ------------------------------- knn (unchanged from R22) ------------------
__global__ __launch_bounds__(256) void knn_kernel(
    const float4* __restrict__ q4s, const int* __restrict__ qmap,
    const float4* __restrict__ p4s, const int* __restrict__ sidx,
    const int* __restrict__ cstart,
    int* __restrict__ out_idx, float* __restrict__ out_w)
{
#pragma clang fp contract(off)
    const int tid  = threadIdx.x;
    const int qloc = tid >> 2;
    const int sub  = tid & 3;
    const int s    = blockIdx.x * 64 + qloc;
    const int b    = s >> 15;

    const int* __restrict__ cs = cstart + b * (NC_ + 1);

    const float4 qv = q4s[s];
    const float gx = qv.x, gy = qv.y, gz = qv.z;
    const float sg2 = qv.w;
    const int qorig = qmap[s];
    const int cx = min(G_-1, (int)(gx * 16.0f));
    const int cy = min(G_-1, (int)(gy * 16.0f));
    const int cz = min(G_-1, (int)(gz * 16.0f));

    const float4* p4 = p4s + (size_t)b * N_;
    const int*    sx = sidx + (size_t)b * N_;

    float bd[8]; int bi[8];
#pragma unroll
    for (int u = 0; u < 8; ++u) { bd[u] = 3.4e38f; bi[u] = 0x7fffffff; }

    {
        const int z0 = max(0, cz-2), z1 = min(G_-1, cz+2);
        const int y0 = max(0, cy-2), y1 = min(G_-1, cy+2);
        const int x0 = max(0, cx-2), x1 = min(G_-1, cx+2);
        const int ny = y1 - y0 + 1;
        const int nrows = (z1 - z0 + 1) * ny;
        const int r0 = (sub * nrows) >> 2;
        const int r1 = ((sub + 1) * nrows) >> 2;
        int zz = z0 + r0 / ny;
        int yy = y0 + r0 % ny;
        for (int r = r0; r < r1; ++r) {
            const int cb = zz*256 + yy*16;
            scan_range(cs[cb+x0], cs[cb+x1+1], p4, sx, gx, gy, gz, sg2, bd, bi);
            if (++yy > y1) { yy = y0; ++zz; }
        }
    }
    fold_merge(bd, bi, 1);
    fold_merge(bd, bi, 2);

    int R = 2;
    while (R < G_ - 1) {
        const bool need = !(bd[7] < (float)R * CW_ - 1e-5f);
        if (!__any(need)) break;
        ++R;
        if (need) {
            float fd[8]; int fi[8];
#pragma unroll
            for (int u = 0; u < 8; ++u) { fd[u] = 3.4e38f; fi[u] = 0x7fffffff; }
            int m2 = 0;
            for (int zz = cz - R; zz <= cz + R; ++zz) {
                if (zz < 0 || zz > G_-1) continue;
                for (int yy = cy - R; yy <= cy + R; ++yy) {
                    if (yy < 0 || yy > G_-1) continue;
                    const int ch = max(abs(zz - cz), abs(yy - cy));
                    if (((m2++) & 3) != sub) continue;
                    const int cb = zz*256 + yy*16;
                    if (ch == R) {
                        const int x0 = max(0, cx-R), x1 = min(G_-1, cx+R);
                        scan_range(cs[cb+x0], cs[cb+x1+1], p4, sx, gx, gy, gz, sg2, fd, fi);
                    } else {
                        const int xl = cx - R, xr = cx + R;
                        if (xl >= 0)
                            scan_range(cs[cb+xl], cs[cb+xl+1], p4, sx, gx, gy, gz, sg2, fd, fi);
                        if (xr <= G_-1)
                            scan_range(cs[cb+xr], cs[cb+xr+1], p4, sx, gx, gy, gz, sg2, fd, fi);
                    }
                }
            }
            fold_merge(fd, fi, 1);
            fold_merge(fd, fi, 2);
#pragma unroll
            for (int u = 0; u < 8; ++u) lex_insert(fd[u], fi[u], bd, bi);
        }
    }

    if (sub == 0) {
        float wk8[8];
#pragma unroll
        for (int u = 0; u < 8; ++u)
            wk8[u] = 1.0f / (bd[u] + 1e-6f);
        float wsum = wk8[0];
#pragma unroll
        for (int u = 1; u < 8; ++u) wsum = wsum + wk8[u];
        const float winv = 1.0f / wsum;
#pragma unroll
        for (int u = 0; u < 8; ++u) {
            out_idx[qorig * 8 + u] = bi[u];
            out_w[qorig * 8 + u]   = wk8[u] * winv;
        }
    }
}

// ------------------------- gno: f16-MFMA (16x16x16) ------------------------
// kappa = h @ W2 via v_mfma_f32_16x16x16f16 (CDNA-classic layout, single
// k-group of 4 -> no k-stacking ambiguity; identical A/B placement makes the
// result exact under any consistent HW k-map). h split into f16 hi+lo in LDS;
// W2^T f16 hi/lo from prep. 3 products: hh + h*lo + lo*h (~2^-22 rel).
// D layout (m89-verified, shape-determined): col=lane&15, row=(lane>>4)*4+reg.
#define HSTR 132
__global__ __launch_bounds__(256) void gno_kernel(
    const float* __restrict__ grid_c, const float* __restrict__ pts,
    const float* __restrict__ feats,
    const float* __restrict__ W1, const float* __restrict__ b1,
    const _Float16* __restrict__ w2t_hi, const _Float16* __restrict__ w2t_lo,
    const float* __restrict__ b2,
    const float* __restrict__ gmm, const float* __restrict__ bta,
    const int* __restrict__ kidx, const float* __restrict__ kw,
    float* __restrict__ out)
{
    __shared__ __align__(16) _Float16 smem_h[2][64][HSTR];   // 33792 B
    float (*kappa)[HSTR] = (float(*)[HSTR])&smem_h[0][0][0]; // alias (33792 B)
    __shared__ float srel[8][8][4];
    __shared__ float swt[8][8];
    __shared__ int   sid[8][8];

    const int tid = threadIdx.x;
    const int qb8 = blockIdx.x * 8;

    if (tid < 64) {
        const int qq = tid >> 3, k = tid & 7;
        const int gq = qb8 + qq;
        const int id = kidx[gq * 8 + k];
        sid[qq][k] = id;
        swt[qq][k] = kw[gq * 8 + k];
        const int bb = gq >> 15;
        const float* pp = pts + ((size_t)bb * N_ + id) * 3;
        srel[qq][k][0] = grid_c[gq * 3 + 0] - pp[0];
        srel[qq][k][1] = grid_c[gq * 3 + 1] - pp[1];
        srel[qq][k][2] = grid_c[gq * 3 + 2] - pp[2];
    }

    const int qs = tid >> 5;
    const int dg = tid & 31;

    const float4 w1r0 = *(const float4*)(W1 + dg * 4);
    const float4 w1r1 = *(const float4*)(W1 + D_ + dg * 4);
    const float4 w1r2 = *(const float4*)(W1 + 2 * D_ + dg * 4);
    const float4 w1bb = *(const float4*)(b1 + dg * 4);
    __syncthreads();

    // ---- Phase A: h -> f16 hi/lo in LDS ---------------------------------
#pragma unroll
    for (int k = 0; k < 8; ++k) {
        const float rx = srel[qs][k][0];
        const float ry = srel[qs][k][1];
        const float rz = srel[qs][k][2];
        float hr[4];
        {
            float u0 = rx * w1r0.x + ry * w1r1.x + rz * w1r2.x + w1bb.x;
            float u1 = rx * w1r0.y + ry * w1r1.y + rz * w1r2.y + w1bb.y;
            float u2 = rx * w1r0.z + ry * w1r1.z + rz * w1r2.z + w1bb.z;
            float u3 = rx * w1r0.w + ry * w1r1.w + rz * w1r2.w + w1bb.w;
            hr[0] = 0.5f * u0 * (1.0f + erff(u0 * 0.70710678118654752f));
            hr[1] = 0.5f * u1 * (1.0f + erff(u1 * 0.70710678118654752f));
            hr[2] = 0.5f * u2 * (1.0f + erff(u2 * 0.70710678118654752f));
            hr[3] = 0.5f * u3 * (1.0f + erff(u3 * 0.70710678118654752f));
        }
        half4_t hv, lv;
#pragma unroll
        for (int c = 0; c < 4; ++c) {
            const _Float16 hi = (_Float16)hr[c];
            hv[c] = hi;
            lv[c] = (_Float16)(hr[c] - (float)hi);
        }
        const int row = qs * 8 + k;
        *(half4_t*)&smem_h[0][row][dg * 4] = hv;
        *(half4_t*)&smem_h[1][row][dg * 4] = lv;
    }
    __syncthreads();

    // ---- MFMA: kappa = h @ W2 -------------------------------------------
    const int wv   = tid >> 6;       // wave 0..3 -> N-cols [wv*32, wv*32+32)
    const int lane = tid & 63;
    const int mrow = lane & 15;
    const int kq   = lane >> 4;      // k-group 0..3; k = kq*4 + elem

    f32x4 acc[4][2];
#pragma unroll
    for (int mt = 0; mt < 4; ++mt)
#pragma unroll
        for (int ntl = 0; ntl < 2; ++ntl)
            acc[mt][ntl] = (f32x4){0.f, 0.f, 0.f, 0.f};

#pragma unroll
    for (int ntl = 0; ntl < 2; ++ntl) {
        const int n = (wv * 2 + ntl) * 16 + mrow;
        half4_t Bh[8], Bl[8];
#pragma unroll
        for (int ks = 0; ks < 8; ++ks) {
            const int off = n * D_ + ks * 16 + kq * 4;
            Bh[ks] = *(const half4_t*)(w2t_hi + off);
            Bl[ks] = *(const half4_t*)(w2t_lo + off);
        }
#pragma unroll
        for (int mt = 0; mt < 4; ++mt) {
            const int row = mt * 16 + mrow;
#pragma unroll
            for (int ks = 0; ks < 8; ++ks) {
                const int col = ks * 16 + kq * 4;
                const half4_t Ah = *(const half4_t*)&smem_h[0][row][col];
                const half4_t Al = *(const half4_t*)&smem_h[1][row][col];
                acc[mt][ntl] = __builtin_amdgcn_mfma_f32_16x16x16f16(
                    Ah, Bh[ks], acc[mt][ntl], 0, 0, 0);
                acc[mt][ntl] = __builtin_amdgcn_mfma_f32_16x16x16f16(
                    Ah, Bl[ks], acc[mt][ntl], 0, 0, 0);
                acc[mt][ntl] = __builtin_amdgcn_mfma_f32_16x16x16f16(
                    Al, Bh[ks], acc[mt][ntl], 0, 0, 0);
            }
        }
    }
    __syncthreads();   // all h reads done -> safe to alias kappa

    // D write: row = (lane>>4)*4 + reg, col = lane&15 (m89-verified)
#pragma unroll
    for (int mt = 0; mt < 4; ++mt)
#pragma unroll
        for (int ntl = 0; ntl < 2; ++ntl) {
            const int col = (wv * 2 + ntl) * 16 + mrow;
#pragma unroll
            for (int r = 0; r < 4; ++r)
                kappa[mt * 16 + kq * 4 + r][col] = acc[mt][ntl][r];
        }
    __syncthreads();

    // ---- Epilogue: gather feats, weighted reduce, LayerNorm -------------
    const int gq = qb8 + qs;
    const int bb = gq >> 15;
    const float4 b2v = *(const float4*)(b2 + dg * 4);

    float o0 = 0.0f, o1 = 0.0f, o2 = 0.0f, o3 = 0.0f;
#pragma unroll
    for (int k = 0; k < 8; ++k) {
        const float4 kp = *(const float4*)&kappa[qs * 8 + k][dg * 4];
        const float4 f =
            *(const float4*)(feats + ((size_t)bb * N_ + sid[qs][k]) * D_ + dg * 4);
        const float wk = swt[qs][k];
        o0 += wk * f.x * (kp.x + b2v.x);
        o1 += wk * f.y * (kp.y + b2v.y);
        o2 += wk * f.z * (kp.z + b2v.z);
        o3 += wk * f.w * (kp.w + b2v.w);
    }

    float s = o0 + o1 + o2 + o3;
#pragma unroll
    for (int off = 16; off > 0; off >>= 1) s += __shfl_xor(s, off, 32);
    const float mu = s * (1.0f / 128.0f);
    const float v0 = o0 - mu, v1 = o1 - mu, v2 = o2 - mu, v3 = o3 - mu;
    float vs = v0 * v0 + v1 * v1 + v2 * v2 + v3 * v3;
#pragma unroll
    for (int off = 16; off > 0; off >>= 1) vs += __shfl_xor(vs, off, 32);
    const float inv = 1.0f / sqrtf(vs * (1.0f / 128.0f) + 1e-5f);

    const float4 gv = *(const float4*)(gmm + dg * 4);
    const float4 bv = *(const float4*)(bta + dg * 4);
    float4 ov;
    ov.x = v0 * inv * gv.x + bv.x;
    ov.y = v1 * inv * gv.y + bv.y;
    ov.z = v2 * inv * gv.z + bv.z;
    ov.w = v3 * inv * gv.w + bv.w;
    *(float4*)(out + (size_t)gq * D_ + dg * 4) = ov;
}

// ---------------------------------------------------------------------------
extern "C" void kernel_launch(void* const* d_in, const int* in_sizes, int n_in,
                              void* d_out, int out_size, void* d_ws, size_t ws_size,
                              hipStream_t stream)
{
    (void)in_sizes; (void)n_in; (void)out_size; (void)ws_size;
    const float* grid_c = (const float*)d_in[0];
    const float* pts    = (const float*)d_in[1];
    const float* feats  = (const float*)d_in[2];
    const float* W1     = (const float*)d_in[3];
    const float* b1     = (const float*)d_in[4];
    const float* W2     = (const float*)d_in[5];
    const float* b2     = (const float*)d_in[6];
    const float* gmm    = (const float*)d_in[7];
    const float* bta    = (const float*)d_in[8];
    float* out = (float*)d_out;

    char* w = (char*)d_ws;
    int*    kidx   = (int*)(w);                  // 2 MB
    float*  kw     = (float*)(w + 2097152);      // -> 4194304
    float4* p4s    = (float4*)(w + 4194304);     // -> 4325376
    float4* q4s    = (float4*)(w + 4325376);     // -> 5373952
    int*    sidx   = (int*)(w + 5373952);        // -> 5406720
    int*    qmap   = (int*)(w + 5406720);        // -> 5668864
    int*    cstart = (int*)(w + 5668864);        // -> 5701640
    int*    qstart = (int*)(w + 5701640);        // -> 5734416
    int*    ccur   = (int*)(w + 5734416);        // -> 5767184
    int*    qcur   = (int*)(w + 5767184);        // -> 5799952
    int*    hist   = (int*)(w + 5799952);        // -> 5832720
    int*    qhist  = (int*)(w + 5832720);        // -> 5865488
    _Float16* w2t_hi = (_Float16*)(w + 5865488); // 32 KB -> 5898256
    _Float16* w2t_lo = (_Float16*)(w + 5898256); // 32 KB -> 5931024

    prep_zero<<<(2 * B_ * NC_ + 255) / 256, 256, 0, stream>>>(hist, 2 * B_ * NC_);
    prep_hist<<<(B_ * N_ + 255) / 256, 256, 0, stream>>>(pts, N_, hist);
    prep_hist<<<(B_ * M_ + 255) / 256, 256, 0, stream>>>(grid_c, M_, qhist);
    prep_w2t<<<(D_ * D_ + 255) / 256, 256, 0, stream>>>(W2, w2t_hi, w2t_lo);
    prep_scan<<<B_, 1024, 0, stream>>>(hist, cstart, ccur);
    prep_scan<<<B_, 1024, 0, stream>>>(qhist, qstart, qcur);
    prep_scatter_p<<<(B_ * N_ + 255) / 256, 256, 0, stream>>>(pts, ccur, p4s, sidx);
    prep_scatter_q<<<(B_ * M_ + 255) / 256, 256, 0, stream>>>(grid_c, qcur, q4s, qmap);
    knn_kernel<<<(B_ * M_) / 64, 256, 0, stream>>>(q4s, qmap, p4s, sidx, cstart, kidx, kw);
    gno_kernel<<<(B_ * M_) / 8, 256, 0, stream>>>(grid_c, pts, feats, W1, b1,
                                                  w2t_hi, w2t_lo, b2, gmm, bta,
                                                  kidx, kw, out);
}

// Round 24
// 350.765 us; speedup vs baseline: 1.6375x; 1.0324x over previous
//
#include <hip/hip_runtime.h>
#include <math.h>

#define B_ 2
#define M_ 32768
#define N_ 4096
#define D_ 128
#define K_ 8
#define G_ 16
#define NC_ 4096
#define CW_ 0.0625f
#define CAP_ 224

typedef _Float16 half4_t __attribute__((ext_vector_type(4)));
typedef float f32x4 __attribute__((ext_vector_type(4)));

// ---------------- frozen selection semantics (verified R15) ----------------
//   sp2 = (z*z + y*y) + x*x            descending plain, no FMA
//   sg2 = (gz*gz + gy*gy) + gx*gx      descending plain, no FMA
//   dot = fma(gz,pz, fma(gy,py, gx*px))  ascending FMA chain
//   d2  = fma(dot,-2, sg2+sp2)          == (sg2+sp2) - 2*dot bitwise
//   dist= sqrtf(fmaxf(d2,0)); order by (dist, index) lexicographic
// ---------------------------------------------------------------------------
__device__ __forceinline__ void lex_insert(float d, int i, float* bd, int* bi)
{
    if (d < bd[7] || (d == bd[7] && i < bi[7])) {
        bd[7] = d; bi[7] = i;
#pragma unroll
        for (int u = 6; u >= 0; --u) {
            const bool sw = (bd[u+1] < bd[u]) ||
                            (bd[u+1] == bd[u] && bi[u+1] < bi[u]);
            if (sw) {
                float tf = bd[u]; bd[u] = bd[u+1]; bd[u+1] = tf;
                int   ti = bi[u]; bi[u] = bi[u+1]; bi[u+1] = ti;
            }
        }
    }
}

// ---------------------------- prep kernels ---------------------------------
__global__ __launch_bounds__(256) void prep_zero(int* __restrict__ a, int n)
{
    const int i = blockIdx.x * 256 + threadIdx.x;
    if (i < n) a[i] = 0;
}

__global__ __launch_bounds__(256) void prep_hist(
    const float* __restrict__ xyz, int n_per_b, int* __restrict__ hist)
{
    const int i = blockIdx.x * 256 + threadIdx.x;
    if (i >= B_ * n_per_b) return;
    const int b = i / n_per_b;
    const float x = xyz[i*3+0], y = xyz[i*3+1], z = xyz[i*3+2];
    const int cx = min(G_-1, (int)(x * 16.0f));
    const int cy = min(G_-1, (int)(y * 16.0f));
    const int cz = min(G_-1, (int)(z * 16.0f));
    atomicAdd(&hist[b * NC_ + cz*256 + cy*16 + cx], 1);
}

__global__ __launch_bounds__(1024) void prep_scan(
    const int* __restrict__ hist, int* __restrict__ cstart, int* __restrict__ ccur)
{
    __shared__ int lds[1024];
    const int b = blockIdx.x, t = threadIdx.x;
    int v[4]; int s = 0;
#pragma unroll
    for (int j = 0; j < 4; ++j) { v[j] = hist[b*NC_ + t*4 + j]; s += v[j]; }
    lds[t] = s;
    __syncthreads();
    for (int off = 1; off < 1024; off <<= 1) {
        int x = (t >= off) ? lds[t - off] : 0;
        __syncthreads();
        lds[t] += x;
        __syncthreads();
    }
    int excl = lds[t] - s;
#pragma unroll
    for (int j = 0; j < 4; ++j) {
        cstart[b*(NC_+1) + t*4 + j] = excl;
        ccur[b*NC_ + t*4 + j] = excl;
        excl += v[j];
    }
    if (t == 1023) cstart[b*(NC_+1) + NC_] = excl;
}

__global__ __launch_bounds__(256) void prep_scatter_p(
    const float* __restrict__ pts, int* __restrict__ ccur,
    float4* __restrict__ p4s, int* __restrict__ sidx)
{
#pragma clang fp contract(off)
    const int i = blockIdx.x * 256 + threadIdx.x;
    if (i >= B_ * N_) return;
    const int b = i >> 12, loc = i & (N_-1);
    const float x = pts[i*3+0], y = pts[i*3+1], z = pts[i*3+2];
    const int cx = min(G_-1, (int)(x * 16.0f));
    const int cy = min(G_-1, (int)(y * 16.0f));
    const int cz = min(G_-1, (int)(z * 16.0f));
    const int pos = atomicAdd(&ccur[b*NC_ + cz*256 + cy*16 + cx], 1);
    float4 v; v.x = x; v.y = y; v.z = z;
    v.w = (z * z + y * y) + x * x;              // FROZEN descending plain
    p4s[b*N_ + pos] = v;
    sidx[b*N_ + pos] = loc;
}

__global__ __launch_bounds__(256) void prep_scatter_q(
    const float* __restrict__ grid_c, int* __restrict__ qcur,
    float4* __restrict__ q4s, int* __restrict__ qmap)
{
#pragma clang fp contract(off)
    const int i = blockIdx.x * 256 + threadIdx.x;
    if (i >= B_ * M_) return;
    const int b = i >> 15;
    const float x = grid_c[i*3+0], y = grid_c[i*3+1], z = grid_c[i*3+2];
    const int cx = min(G_-1, (int)(x * 16.0f));
    const int cy = min(G_-1, (int)(y * 16.0f));
    const int cz = min(G_-1, (int)(z * 16.0f));
    const int pos = atomicAdd(&qcur[b*NC_ + cz*256 + cy*16 + cx], 1);
    float4 v; v.x = x; v.y = y; v.z = z;
    v.w = (z * z + y * y) + x * x;              // FROZEN descending plain
    q4s[(size_t)b*M_ + pos] = v;
    qmap[(size_t)b*M_ + pos] = i;
}

__global__ __launch_bounds__(256) void prep_w2t(
    const float* __restrict__ W2,
    _Float16* __restrict__ w2t_hi, _Float16* __restrict__ w2t_lo)
{
    const int i = blockIdx.x * 256 + threadIdx.x;
    if (i >= D_ * D_) return;
    const int n = i >> 7, k = i & 127;
    const float w = W2[k * D_ + n];
    const _Float16 hi = (_Float16)w;
    w2t_hi[i] = hi;
    w2t_lo[i] = (_Float16)(w - (float)hi);
}

// ------------------------------- knn: cell-per-wave ------------------------
// Block = 256 thr = 4 waves; wave w handles cell gci = blockIdx.x*4+w.
// Stage the cell's clamped +-2 box candidates into LDS once (row-parallel,
// coalesced); each lane owns ONE query of the cell and scans the shared list
// in lockstep (LDS broadcast reads). The cell box == each member query's box
// (same cell), lex-(dist,idx) selection is scan-order independent, rings are
// disjoint shells -> bit-identical to the verified R15 selection.
__global__ __launch_bounds__(256) void knn_kernel(
    const float4* __restrict__ q4s, const int* __restrict__ qmap,
    const float4* __restrict__ p4s, const int* __restrict__ sidx,
    const int* __restrict__ cstart, const int* __restrict__ qstart,
    int* __restrict__ out_idx, float* __restrict__ out_w)
{
#pragma clang fp contract(off)
    __shared__ float4 spt[4][CAP_];
    __shared__ int    sil[4][CAP_];
    __shared__ int    rtab[4][32][3];   // [row]: {ldsoff or -1, globS, len}

    const int tid  = threadIdx.x;
    const int wv   = tid >> 6;
    const int lane = tid & 63;
    const int gci  = blockIdx.x * 4 + wv;
    const int b    = gci >> 12;                 // NC_ = 4096
    const int cid  = gci & (NC_ - 1);
    const int cx = cid & 15, cy = (cid >> 4) & 15, cz = cid >> 8;

    const int* __restrict__ cs = cstart + b * (NC_ + 1);
    const int qs0 = qstart[b * (NC_ + 1) + cid];
    const int nq  = qstart[b * (NC_ + 1) + cid + 1] - qs0;

    const float4* p4 = p4s + (size_t)b * N_;
    const int*    sx = sidx + (size_t)b * N_;

    const int z0 = max(0, cz-2), z1 = min(G_-1, cz+2);
    const int y0 = max(0, cy-2), y1 = min(G_-1, cy+2);
    const int x0 = max(0, cx-2), x1 = min(G_-1, cx+2);
    const int ny = y1 - y0 + 1;
    const int nrows = (z1 - z0 + 1) * ny;

    // ---- stage box rows (lane r stages row r) ---------------------------
    int myS = 0, myLen = 0;
    if (nq > 0 && lane < nrows) {
        const int zz = z0 + lane / ny;
        const int yy = y0 + lane % ny;
        const int cb = zz*256 + yy*16;
        myS   = cs[cb + x0];
        myLen = cs[cb + x1 + 1] - myS;
    }
    int inc = myLen;
#pragma unroll
    for (int o = 1; o < 64; o <<= 1) {
        int v = __shfl_up(inc, o);
        if (lane >= o) inc += v;
    }
    const int off = inc - myLen;
    if (nq > 0 && lane < nrows) {
        const bool stg = (off + myLen <= CAP_);
        rtab[wv][lane][0] = stg ? off : -1;
        rtab[wv][lane][1] = myS;
        rtab[wv][lane][2] = myLen;
        if (stg) {
            for (int t = 0; t < myLen; ++t) {
                spt[wv][off + t] = p4[myS + t];
                sil[wv][off + t] = sx[myS + t];
            }
        }
    }
    __syncthreads();   // single barrier; all waves reach it (no early return)

    // ---- each lane = one query of this cell -----------------------------
    for (int q0 = 0; q0 < nq; q0 += 64) {
        const bool act = (q0 + lane) < nq;
        float gx = 0.f, gy = 0.f, gz = 0.f, sg2 = 0.f;
        int qorig = 0;
        if (act) {
            const size_t slot = (size_t)b * M_ + qs0 + q0 + lane;
            const float4 qv = q4s[slot];
            gx = qv.x; gy = qv.y; gz = qv.z; sg2 = qv.w;   // FROZEN sg2
            qorig = qmap[slot];
        }

        float bd[8]; int bi[8];
#pragma unroll
        for (int u = 0; u < 8; ++u) { bd[u] = 3.4e38f; bi[u] = 0x7fffffff; }

        if (act) {
            for (int r = 0; r < nrows; ++r) {
                const int lo = rtab[wv][r][0];
                const int gs = rtab[wv][r][1];
                const int ln = rtab[wv][r][2];
                if (lo >= 0) {
                    for (int t = 0; t < ln; ++t) {
                        const float4 pp = spt[wv][lo + t];     // LDS broadcast
                        const float dot  = fmaf(gz, pp.z, fmaf(gy, pp.y, gx * pp.x));
                        const float d2   = fmaf(dot, -2.0f, sg2 + pp.w);
                        const float dist = sqrtf(fmaxf(d2, 0.0f));
                        lex_insert(dist, sil[wv][lo + t], bd, bi);
                    }
                } else {                                       // overflow row
                    for (int t = 0; t < ln; ++t) {
                        const float4 pp = p4[gs + t];
                        const float dot  = fmaf(gz, pp.z, fmaf(gy, pp.y, gx * pp.x));
                        const float d2   = fmaf(dot, -2.0f, sg2 + pp.w);
                        const float dist = sqrtf(fmaxf(d2, 0.0f));
                        lex_insert(dist, sx[gs + t], bd, bi);
                    }
                }
            }
        }

        // ring expansion; cell-uniform rows, wave-coherent global reads
        int R = 2;
        while (R < G_ - 1) {
            const bool need = act && !(bd[7] < (float)R * CW_ - 1e-5f);
            if (!__any(need)) break;
            ++R;
            if (need) {
                for (int zz = cz - R; zz <= cz + R; ++zz) {
                    if (zz < 0 || zz > G_-1) continue;
                    for (int yy = cy - R; yy <= cy + R; ++yy) {
                        if (yy < 0 || yy > G_-1) continue;
                        const int ch = max(abs(zz - cz), abs(yy - cy));
                        const int cb = zz*256 + yy*16;
                        int s0, e0, s1 = 0, e1 = 0;
                        if (ch == R) {
                            s0 = cs[cb + max(0, cx-R)];
                            e0 = cs[cb + min(G_-1, cx+R) + 1];
                        } else {
                            const int xl = cx - R, xr = cx + R;
                            s0 = (xl >= 0)    ? cs[cb+xl]   : 0;
                            e0 = (xl >= 0)    ? cs[cb+xl+1] : 0;
                            s1 = (xr <= G_-1) ? cs[cb+xr]   : 0;
                            e1 = (xr <= G_-1) ? cs[cb+xr+1] : 0;
                        }
                        for (int t = s0; t < e0; ++t) {
                            const float4 pp = p4[t];
                            const float dot  = fmaf(gz, pp.z, fmaf(gy, pp.y, gx * pp.x));
                            const float d2   = fmaf(dot, -2.0f, sg2 + pp.w);
                            const float dist = sqrtf(fmaxf(d2, 0.0f));
                            lex_insert(dist, sx[t], bd, bi);
                        }
                        for (int t = s1; t < e1; ++t) {
                            const float4 pp = p4[t];
                            const float dot  = fmaf(gz, pp.z, fmaf(gy, pp.y, gx * pp.x));
                            const float d2   = fmaf(dot, -2.0f, sg2 + pp.w);
                            const float dist = sqrtf(fmaxf(d2, 0.0f));
                            lex_insert(dist, sx[t], bd, bi);
                        }
                    }
                }
            }
        }

        if (act) {
            // FROZEN weight rounding: f32, sequential ascending sum
            float wk8[8];
#pragma unroll
            for (int u = 0; u < 8; ++u)
                wk8[u] = 1.0f / (bd[u] + 1e-6f);
            float wsum = wk8[0];
#pragma unroll
            for (int u = 1; u < 8; ++u) wsum = wsum + wk8[u];
            const float winv = 1.0f / wsum;
#pragma unroll
            for (int u = 0; u < 8; ++u) {
                out_idx[qorig * 8 + u] = bi[u];
                out_w[qorig * 8 + u]   = wk8[u] * winv;
            }
        }
    }
}

// ------------------------- gno: f16-MFMA (R23 verified) --------------------
#define HSTR 132
__global__ __launch_bounds__(256) void gno_kernel(
    const float* __restrict__ grid_c, const float* __restrict__ pts,
    const float* __restrict__ feats,
    const float* __restrict__ W1, const float* __restrict__ b1,
    const _Float16* __restrict__ w2t_hi, const _Float16* __restrict__ w2t_lo,
    const float* __restrict__ b2,
    const float* __restrict__ gmm, const float* __restrict__ bta,
    const int* __restrict__ kidx, const float* __restrict__ kw,
    float* __restrict__ out)
{
    __shared__ __align__(16) _Float16 smem_h[2][64][HSTR];   // 33792 B
    float (*kappa)[HSTR] = (float(*)[HSTR])&smem_h[0][0][0]; // alias
    __shared__ float srel[8][8][4];
    __shared__ float swt[8][8];
    __shared__ int   sid[8][8];

    const int tid = threadIdx.x;
    const int qb8 = blockIdx.x * 8;

    if (tid < 64) {
        const int qq = tid >> 3, k = tid & 7;
        const int gq = qb8 + qq;
        const int id = kidx[gq * 8 + k];
        sid[qq][k] = id;
        swt[qq][k] = kw[gq * 8 + k];
        const int bb = gq >> 15;
        const float* pp = pts + ((size_t)bb * N_ + id) * 3;
        srel[qq][k][0] = grid_c[gq * 3 + 0] - pp[0];
        srel[qq][k][1] = grid_c[gq * 3 + 1] - pp[1];
        srel[qq][k][2] = grid_c[gq * 3 + 2] - pp[2];
    }

    const int qs = tid >> 5;
    const int dg = tid & 31;

    const float4 w1r0 = *(const float4*)(W1 + dg * 4);
    const float4 w1r1 = *(const float4*)(W1 + D_ + dg * 4);
    const float4 w1r2 = *(const float4*)(W1 + 2 * D_ + dg * 4);
    const float4 w1bb = *(const float4*)(b1 + dg * 4);
    __syncthreads();

#pragma unroll
    for (int k = 0; k < 8; ++k) {
        const float rx = srel[qs][k][0];
        const float ry = srel[qs][k][1];
        const float rz = srel[qs][k][2];
        float hr[4];
        {
            float u0 = rx * w1r0.x + ry * w1r1.x + rz * w1r2.x + w1bb.x;
            float u1 = rx * w1r0.y + ry * w1r1.y + rz * w1r2.y + w1bb.y;
            float u2 = rx * w1r0.z + ry * w1r1.z + rz * w1r2.z + w1bb.z;
            float u3 = rx * w1r0.w + ry * w1r1.w + rz * w1r2.w + w1bb.w;
            hr[0] = 0.5f * u0 * (1.0f + erff(u0 * 0.70710678118654752f));
            hr[1] = 0.5f * u1 * (1.0f + erff(u1 * 0.70710678118654752f));
            hr[2] = 0.5f * u2 * (1.0f + erff(u2 * 0.70710678118654752f));
            hr[3] = 0.5f * u3 * (1.0f + erff(u3 * 0.70710678118654752f));
        }
        half4_t hv, lv;
#pragma unroll
        for (int c = 0; c < 4; ++c) {
            const _Float16 hi = (_Float16)hr[c];
            hv[c] = hi;
            lv[c] = (_Float16)(hr[c] - (float)hi);
        }
        const int row = qs * 8 + k;
        *(half4_t*)&smem_h[0][row][dg * 4] = hv;
        *(half4_t*)&smem_h[1][row][dg * 4] = lv;
    }
    __syncthreads();

    const int wv   = tid >> 6;
    const int lane = tid & 63;
    const int mrow = lane & 15;
    const int kq   = lane >> 4;

    f32x4 acc[4][2];
#pragma unroll
    for (int mt = 0; mt < 4; ++mt)
#pragma unroll
        for (int ntl = 0; ntl < 2; ++ntl)
            acc[mt][ntl] = (f32x4){0.f, 0.f, 0.f, 0.f};

#pragma unroll
    for (int ntl = 0; ntl < 2; ++ntl) {
        const int n = (wv * 2 + ntl) * 16 + mrow;
        half4_t Bh[8], Bl[8];
#pragma unroll
        for (int ks = 0; ks < 8; ++ks) {
            const int off = n * D_ + ks * 16 + kq * 4;
            Bh[ks] = *(const half4_t*)(w2t_hi + off);
            Bl[ks] = *(const half4_t*)(w2t_lo + off);
        }
#pragma unroll
        for (int mt = 0; mt < 4; ++mt) {
            const int row = mt * 16 + mrow;
#pragma unroll
            for (int ks = 0; ks < 8; ++ks) {
                const int col = ks * 16 + kq * 4;
                const half4_t Ah = *(const half4_t*)&smem_h[0][row][col];
                const half4_t Al = *(const half4_t*)&smem_h[1][row][col];
                acc[mt][ntl] = __builtin_amdgcn_mfma_f32_16x16x16f16(
                    Ah, Bh[ks], acc[mt][ntl], 0, 0, 0);
                acc[mt][ntl] = __builtin_amdgcn_mfma_f32_16x16x16f16(
                    Ah, Bl[ks], acc[mt][ntl], 0, 0, 0);
                acc[mt][ntl] = __builtin_amdgcn_mfma_f32_16x16x16f16(
                    Al, Bh[ks], acc[mt][ntl], 0, 0, 0);
            }
        }
    }
    __syncthreads();

#pragma unroll
    for (int mt = 0; mt < 4; ++mt)
#pragma unroll
        for (int ntl = 0; ntl < 2; ++ntl) {
            const int col = (wv * 2 + ntl) * 16 + mrow;
#pragma unroll
            for (int r = 0; r < 4; ++r)
                kappa[mt * 16 + kq * 4 + r][col] = acc[mt][ntl][r];
        }
    __syncthreads();

    const int gq = qb8 + qs;
    const int bb = gq >> 15;
    const float4 b2v = *(const float4*)(b2 + dg * 4);

    float o0 = 0.0f, o1 = 0.0f, o2 = 0.0f, o3 = 0.0f;
#pragma unroll
    for (int k = 0; k < 8; ++k) {
        const float4 kp = *(const float4*)&kappa[qs * 8 + k][dg * 4];
        const float4 f =
            *(const float4*)(feats + ((size_t)bb * N_ + sid[qs][k]) * D_ + dg * 4);
        const float wk = swt[qs][k];
        o0 += wk * f.x * (kp.x + b2v.x);
        o1 += wk * f.y * (kp.y + b2v.y);
        o2 += wk * f.z * (kp.z + b2v.z);
        o3 += wk * f.w * (kp.w + b2v.w);
    }

    float s = o0 + o1 + o2 + o3;
#pragma unroll
    for (int off = 16; off > 0; off >>= 1) s += __shfl_xor(s, off, 32);
    const float mu = s * (1.0f / 128.0f);
    const float v0 = o0 - mu, v1 = o1 - mu, v2 = o2 - mu, v3 = o3 - mu;
    float vs = v0 * v0 + v1 * v1 + v2 * v2 + v3 * v3;
#pragma unroll
    for (int off = 16; off > 0; off >>= 1) vs += __shfl_xor(vs, off, 32);
    const float inv = 1.0f / sqrtf(vs * (1.0f / 128.0f) + 1e-5f);

    const float4 gv = *(const float4*)(gmm + dg * 4);
    const float4 bv = *(const float4*)(bta + dg * 4);
    float4 ov;
    ov.x = v0 * inv * gv.x + bv.x;
    ov.y = v1 * inv * gv.y + bv.y;
    ov.z = v2 * inv * gv.z + bv.z;
    ov.w = v3 * inv * gv.w + bv.w;
    *(float4*)(out + (size_t)gq * D_ + dg * 4) = ov;
}

// ---------------------------------------------------------------------------
extern "C" void kernel_launch(void* const* d_in, const int* in_sizes, int n_in,
                              void* d_out, int out_size, void* d_ws, size_t ws_size,
                              hipStream_t stream)
{
    (void)in_sizes; (void)n_in; (void)out_size; (void)ws_size;
    const float* grid_c = (const float*)d_in[0];
    const float* pts    = (const float*)d_in[1];
    const float* feats  = (const float*)d_in[2];
    const float* W1     = (const float*)d_in[3];
    const float* b1     = (const float*)d_in[4];
    const float* W2     = (const float*)d_in[5];
    const float* b2     = (const float*)d_in[6];
    const float* gmm    = (const float*)d_in[7];
    const float* bta    = (const float*)d_in[8];
    float* out = (float*)d_out;

    char* w = (char*)d_ws;
    int*    kidx   = (int*)(w);                  // 2 MB
    float*  kw     = (float*)(w + 2097152);      // -> 4194304
    float4* p4s    = (float4*)(w + 4194304);     // -> 4325376
    float4* q4s    = (float4*)(w + 4325376);     // -> 5373952
    int*    sidx   = (int*)(w + 5373952);        // -> 5406720
    int*    qmap   = (int*)(w + 5406720);        // -> 5668864
    int*    cstart = (int*)(w + 5668864);        // -> 5701640
    int*    qstart = (int*)(w + 5701640);        // -> 5734416
    int*    ccur   = (int*)(w + 5734416);        // -> 5767184
    int*    qcur   = (int*)(w + 5767184);        // -> 5799952
    int*    hist   = (int*)(w + 5799952);        // -> 5832720
    int*    qhist  = (int*)(w + 5832720);        // -> 5865488
    _Float16* w2t_hi = (_Float16*)(w + 5865488); // 32 KB -> 5898256
    _Float16* w2t_lo = (_Float16*)(w + 5898256); // 32 KB -> 5931024

    prep_zero<<<(2 * B_ * NC_ + 255) / 256, 256, 0, stream>>>(hist, 2 * B_ * NC_);
    prep_hist<<<(B_ * N_ + 255) / 256, 256, 0, stream>>>(pts, N_, hist);
    prep_hist<<<(B_ * M_ + 255) / 256, 256, 0, stream>>>(grid_c, M_, qhist);
    prep_w2t<<<(D_ * D_ + 255) / 256, 256, 0, stream>>>(W2, w2t_hi, w2t_lo);
    prep_scan<<<B_, 1024, 0, stream>>>(hist, cstart, ccur);
    prep_scan<<<B_, 1024, 0, stream>>>(qhist, qstart, qcur);
    prep_scatter_p<<<(B_ * N_ + 255) / 256, 256, 0, stream>>>(pts, ccur, p4s, sidx);
    prep_scatter_q<<<(B_ * M_ + 255) / 256, 256, 0, stream>>>(grid_c, qcur, q4s, qmap);
    knn_kernel<<<(B_ * NC_) / 4, 256, 0, stream>>>(q4s, qmap, p4s, sidx, cstart,
                                                   qstart, kidx, kw);
    gno_kernel<<<(B_ * M_) / 8, 256, 0, stream>>>(grid_c, pts, feats, W1, b1,
                                                  w2t_hi, w2t_lo, b2, gmm, bta,
                                                  kidx, kw, out);
}

// Round 25
// 279.022 us; speedup vs baseline: 2.0586x; 1.2571x over previous
//
#include <hip/hip_runtime.h>
#include <math.h>

#define B_ 2
#define M_ 32768
#define N_ 4096
#define D_ 128
#define K_ 8
#define G_ 16
#define NC_ 4096
#define CW_ 0.0625f
#define CAP_ 224

typedef _Float16 half4_t __attribute__((ext_vector_type(4)));
typedef float f32x4 __attribute__((ext_vector_type(4)));
typedef unsigned long long u64;

// ---------------- frozen selection semantics (verified R15) ----------------
//   sp2 = (z*z + y*y) + x*x            descending plain, no FMA
//   sg2 = (gz*gz + gy*gy) + gx*gx      descending plain, no FMA
//   dot = fma(gz,pz, fma(gy,py, gx*px))  ascending FMA chain
//   d2  = fma(dot,-2, sg2+sp2)          == (sg2+sp2) - 2*dot bitwise
//   dist= sqrtf(fmaxf(d2,0)); order by (dist, index) lexicographic.
// u64 key = (dist_bits<<32)|idx: dist>=0 so u64 order == lex(dist,idx).
// ---------------------------------------------------------------------------
__device__ __forceinline__ void lex64_insert(u64 k, u64* kd)
{
    if (k < kd[7]) {
        kd[7] = k;
#pragma unroll
        for (int u = 6; u >= 0; --u) {
            if (kd[u+1] < kd[u]) { u64 t = kd[u]; kd[u] = kd[u+1]; kd[u+1] = t; }
        }
    }
}

__device__ __forceinline__ u64 mk_key(float dist, int idx)
{
    return ((u64)__float_as_uint(dist) << 32) | (unsigned)idx;
}

__device__ __forceinline__ void fold64(u64* kd, int mask)
{
    u64 ok[8];
#pragma unroll
    for (int u = 0; u < 8; ++u) ok[u] = __shfl_xor((long long)kd[u], mask);
#pragma unroll
    for (int u = 0; u < 8; ++u) lex64_insert(ok[u], kd);
}

// ---------------------------- prep kernels ---------------------------------
__global__ __launch_bounds__(256) void prep_zero(int* __restrict__ a, int n)
{
    const int i = blockIdx.x * 256 + threadIdx.x;
    if (i < n) a[i] = 0;
}

__global__ __launch_bounds__(256) void prep_hist(
    const float* __restrict__ xyz, int n_per_b, int* __restrict__ hist)
{
    const int i = blockIdx.x * 256 + threadIdx.x;
    if (i >= B_ * n_per_b) return;
    const int b = i / n_per_b;
    const float x = xyz[i*3+0], y = xyz[i*3+1], z = xyz[i*3+2];
    const int cx = min(G_-1, (int)(x * 16.0f));
    const int cy = min(G_-1, (int)(y * 16.0f));
    const int cz = min(G_-1, (int)(z * 16.0f));
    atomicAdd(&hist[b * NC_ + cz*256 + cy*16 + cx], 1);
}

__global__ __launch_bounds__(1024) void prep_scan(
    const int* __restrict__ hist, int* __restrict__ cstart, int* __restrict__ ccur)
{
    __shared__ int lds[1024];
    const int b = blockIdx.x, t = threadIdx.x;
    int v[4]; int s = 0;
#pragma unroll
    for (int j = 0; j < 4; ++j) { v[j] = hist[b*NC_ + t*4 + j]; s += v[j]; }
    lds[t] = s;
    __syncthreads();
    for (int off = 1; off < 1024; off <<= 1) {
        int x = (t >= off) ? lds[t - off] : 0;
        __syncthreads();
        lds[t] += x;
        __syncthreads();
    }
    int excl = lds[t] - s;
#pragma unroll
    for (int j = 0; j < 4; ++j) {
        cstart[b*(NC_+1) + t*4 + j] = excl;
        ccur[b*NC_ + t*4 + j] = excl;
        excl += v[j];
    }
    if (t == 1023) cstart[b*(NC_+1) + NC_] = excl;
}

__global__ __launch_bounds__(256) void prep_scatter_p(
    const float* __restrict__ pts, int* __restrict__ ccur,
    float4* __restrict__ p4s, int* __restrict__ sidx)
{
#pragma clang fp contract(off)
    const int i = blockIdx.x * 256 + threadIdx.x;
    if (i >= B_ * N_) return;
    const int b = i >> 12, loc = i & (N_-1);
    const float x = pts[i*3+0], y = pts[i*3+1], z = pts[i*3+2];
    const int cx = min(G_-1, (int)(x * 16.0f));
    const int cy = min(G_-1, (int)(y * 16.0f));
    const int cz = min(G_-1, (int)(z * 16.0f));
    const int pos = atomicAdd(&ccur[b*NC_ + cz*256 + cy*16 + cx], 1);
    float4 v; v.x = x; v.y = y; v.z = z;
    v.w = (z * z + y * y) + x * x;              // FROZEN descending plain
    p4s[b*N_ + pos] = v;
    sidx[b*N_ + pos] = loc;
}

__global__ __launch_bounds__(256) void prep_scatter_q(
    const float* __restrict__ grid_c, int* __restrict__ qcur,
    float4* __restrict__ q4s, int* __restrict__ qmap)
{
#pragma clang fp contract(off)
    const int i = blockIdx.x * 256 + threadIdx.x;
    if (i >= B_ * M_) return;
    const int b = i >> 15;
    const float x = grid_c[i*3+0], y = grid_c[i*3+1], z = grid_c[i*3+2];
    const int cx = min(G_-1, (int)(x * 16.0f));
    const int cy = min(G_-1, (int)(y * 16.0f));
    const int cz = min(G_-1, (int)(z * 16.0f));
    const int pos = atomicAdd(&qcur[b*NC_ + cz*256 + cy*16 + cx], 1);
    float4 v; v.x = x; v.y = y; v.z = z;
    v.w = (z * z + y * y) + x * x;              // FROZEN descending plain
    q4s[(size_t)b*M_ + pos] = v;
    qmap[(size_t)b*M_ + pos] = i;
}

__global__ __launch_bounds__(256) void prep_w2t(
    const float* __restrict__ W2,
    _Float16* __restrict__ w2t_hi, _Float16* __restrict__ w2t_lo)
{
    const int i = blockIdx.x * 256 + threadIdx.x;
    if (i >= D_ * D_) return;
    const int n = i >> 7, k = i & 127;
    const float w = W2[k * D_ + n];
    const _Float16 hi = (_Float16)w;
    w2t_hi[i] = hi;
    w2t_lo[i] = (_Float16)(w - (float)hi);
}

// ------------------------------- knn: cell-per-wave, 4 lanes/query ---------
// Wave = 1 cell. lane = qg*4+sub: query-group qg (0..15) x sub (0..3). The
// cell's +-2 box candidates staged flat in LDS; sub scans its quarter chunk
// (disjoint -> fold64 exact). All selection via u64 keys (== FROZEN lex).
__global__ __launch_bounds__(256) void knn_kernel(
    const float4* __restrict__ q4s, const int* __restrict__ qmap,
    const float4* __restrict__ p4s, const int* __restrict__ sidx,
    const int* __restrict__ cstart, const int* __restrict__ qstart,
    int* __restrict__ out_idx, float* __restrict__ out_w)
{
#pragma clang fp contract(off)
    __shared__ float4 spt[4][CAP_];
    __shared__ int    sil[4][CAP_];
    __shared__ int    rtab[4][32][2];   // {globS, len} per row (overflow path)

    const int tid  = threadIdx.x;
    const int wv   = tid >> 6;
    const int lane = tid & 63;
    const int gci  = blockIdx.x * 4 + wv;
    const int b    = gci >> 12;
    const int cid  = gci & (NC_ - 1);
    const int cx = cid & 15, cy = (cid >> 4) & 15, cz = cid >> 8;

    const int* __restrict__ cs = cstart + b * (NC_ + 1);
    const int qs0 = qstart[b * (NC_ + 1) + cid];
    const int nq  = qstart[b * (NC_ + 1) + cid + 1] - qs0;

    const float4* p4 = p4s + (size_t)b * N_;
    const int*    sx = sidx + (size_t)b * N_;

    const int z0 = max(0, cz-2), z1 = min(G_-1, cz+2);
    const int y0 = max(0, cy-2), y1 = min(G_-1, cy+2);
    const int x0 = max(0, cx-2), x1 = min(G_-1, cx+2);
    const int ny = y1 - y0 + 1;
    const int nrows = (z1 - z0 + 1) * ny;

    // ---- stage flat box list (lane r stages row r at prefix offset) -----
    int myS = 0, myLen = 0;
    if (nq > 0 && lane < nrows) {
        const int zz = z0 + lane / ny;
        const int yy = y0 + lane % ny;
        const int cb = zz*256 + yy*16;
        myS   = cs[cb + x0];
        myLen = cs[cb + x1 + 1] - myS;
    }
    int inc = myLen;
#pragma unroll
    for (int o = 1; o < 64; o <<= 1) {
        int v = __shfl_up(inc, o);
        if (lane >= o) inc += v;
    }
    const int off = inc - myLen;
    const int tot = __shfl(inc, 63);
    const bool ovf = (tot > CAP_);
    if (nq > 0 && lane < nrows) {
        rtab[wv][lane][0] = myS;
        rtab[wv][lane][1] = myLen;
        if (!ovf) {
            for (int t = 0; t < myLen; ++t) {
                spt[wv][off + t] = p4[myS + t];
                sil[wv][off + t] = sx[myS + t];
            }
        }
    }
    __syncthreads();

    const int qg  = lane >> 2;
    const int sub = lane & 3;

    for (int q0 = 0; q0 < nq; q0 += 16) {
        const bool act = (q0 + qg) < nq;
        float gx = 0.f, gy = 0.f, gz = 0.f, sg2 = 0.f;
        int qorig = 0;
        if (act) {
            const size_t slot = (size_t)b * M_ + qs0 + q0 + qg;
            const float4 qv = q4s[slot];
            gx = qv.x; gy = qv.y; gz = qv.z; sg2 = qv.w;   // FROZEN sg2
            qorig = qmap[slot];
        }

        u64 kd[8];
#pragma unroll
        for (int u = 0; u < 8; ++u) kd[u] = ~0ull;

        if (act) {
            if (!ovf) {
                const int ts = (sub * tot) >> 2;
                const int te = ((sub + 1) * tot) >> 2;
                for (int t = ts; t < te; ++t) {
                    const float4 pp = spt[wv][t];
                    const float dot  = fmaf(gz, pp.z, fmaf(gy, pp.y, gx * pp.x));
                    const float d2   = fmaf(dot, -2.0f, sg2 + pp.w);
                    const float dist = sqrtf(fmaxf(d2, 0.0f));
                    lex64_insert(mk_key(dist, sil[wv][t]), kd);
                }
            } else {                       // ultra-rare: rows from global
                const int r0 = (sub * nrows) >> 2;
                const int r1 = ((sub + 1) * nrows) >> 2;
                for (int r = r0; r < r1; ++r) {
                    const int gs = rtab[wv][r][0];
                    const int ln = rtab[wv][r][1];
                    for (int t = 0; t < ln; ++t) {
                        const float4 pp = p4[gs + t];
                        const float dot  = fmaf(gz, pp.z, fmaf(gy, pp.y, gx * pp.x));
                        const float d2   = fmaf(dot, -2.0f, sg2 + pp.w);
                        const float dist = sqrtf(fmaxf(d2, 0.0f));
                        lex64_insert(mk_key(dist, sx[gs + t]), kd);
                    }
                }
            }
        }
        fold64(kd, 1);
        fold64(kd, 2);

        // ring expansion (rare; rows wave-uniform, round-robin by sub)
        int R = 2;
        while (R < G_ - 1) {
            const float bd7 = __uint_as_float((unsigned)(kd[7] >> 32));
            const bool need = act && !(bd7 < (float)R * CW_ - 1e-5f);
            if (!__any(need)) break;
            ++R;
            if (need) {
                u64 fk[8];
#pragma unroll
                for (int u = 0; u < 8; ++u) fk[u] = ~0ull;
                int m2 = 0;
                for (int zz = cz - R; zz <= cz + R; ++zz) {
                    if (zz < 0 || zz > G_-1) continue;
                    for (int yy = cy - R; yy <= cy + R; ++yy) {
                        if (yy < 0 || yy > G_-1) continue;
                        const int ch = max(abs(zz - cz), abs(yy - cy));
                        if (((m2++) & 3) != sub) continue;
                        const int cb = zz*256 + yy*16;
                        int s0, e0, s1 = 0, e1 = 0;
                        if (ch == R) {
                            s0 = cs[cb + max(0, cx-R)];
                            e0 = cs[cb + min(G_-1, cx+R) + 1];
                        } else {
                            const int xl = cx - R, xr = cx + R;
                            s0 = (xl >= 0)    ? cs[cb+xl]   : 0;
                            e0 = (xl >= 0)    ? cs[cb+xl+1] : 0;
                            s1 = (xr <= G_-1) ? cs[cb+xr]   : 0;
                            e1 = (xr <= G_-1) ? cs[cb+xr+1] : 0;
                        }
                        for (int t = s0; t < e0; ++t) {
                            const float4 pp = p4[t];
                            const float dot  = fmaf(gz, pp.z, fmaf(gy, pp.y, gx * pp.x));
                            const float d2   = fmaf(dot, -2.0f, sg2 + pp.w);
                            const float dist = sqrtf(fmaxf(d2, 0.0f));
                            lex64_insert(mk_key(dist, sx[t]), kd ? fk : fk);
                        }
                        for (int t = s1; t < e1; ++t) {
                            const float4 pp = p4[t];
                            const float dot  = fmaf(gz, pp.z, fmaf(gy, pp.y, gx * pp.x));
                            const float d2   = fmaf(dot, -2.0f, sg2 + pp.w);
                            const float dist = sqrtf(fmaxf(d2, 0.0f));
                            lex64_insert(mk_key(dist, sx[t]), fk);
                        }
                    }
                }
                fold64(fk, 1);
                fold64(fk, 2);
#pragma unroll
                for (int u = 0; u < 8; ++u) lex64_insert(fk[u], kd);
            }
        }

        if (act && sub == 0) {
            // FROZEN weight rounding: f32, sequential ascending sum
            float wk8[8];
#pragma unroll
            for (int u = 0; u < 8; ++u) {
                const float dist = __uint_as_float((unsigned)(kd[u] >> 32));
                wk8[u] = 1.0f / (dist + 1e-6f);
            }
            float wsum = wk8[0];
#pragma unroll
            for (int u = 1; u < 8; ++u) wsum = wsum + wk8[u];
            const float winv = 1.0f / wsum;
#pragma unroll
            for (int u = 0; u < 8; ++u) {
                out_idx[qorig * 8 + u] = (int)(kd[u] & 0xffffffffu);
                out_w[qorig * 8 + u]   = wk8[u] * winv;
            }
        }
    }
}

// ------------------------- gno: f16-MFMA + poly-erf ------------------------
// GELU erf via Taylor series (|t|<=0.5: err < 4e-10; |u| <~0.3 in practice),
// per-lane erff fallback guard (execz-skipped). Continuous path: delta ~1e-9.
__device__ __forceinline__ float gelu_f(float u)
{
    const float t  = u * 0.70710678118654752f;
    const float t2 = t * t;
    float p = fmaf(t2, 1.0f/9360.0f, -1.0f/1320.0f);
    p = fmaf(t2, p, 1.0f/216.0f);
    p = fmaf(t2, p, -1.0f/42.0f);
    p = fmaf(t2, p, 1.0f/10.0f);
    p = fmaf(t2, p, -1.0f/3.0f);
    p = fmaf(t2, p, 1.0f);
    float er = 1.1283791670955126f * t * p;
    if (fabsf(t) > 0.5f) er = erff(t);      // rare: skipped when execz
    return 0.5f * u * (1.0f + er);
}

#define HSTR 132
__global__ __launch_bounds__(256) void gno_kernel(
    const float* __restrict__ grid_c, const float* __restrict__ pts,
    const float* __restrict__ feats,
    const float* __restrict__ W1, const float* __restrict__ b1,
    const _Float16* __restrict__ w2t_hi, const _Float16* __restrict__ w2t_lo,
    const float* __restrict__ b2,
    const float* __restrict__ gmm, const float* __restrict__ bta,
    const int* __restrict__ kidx, const float* __restrict__ kw,
    float* __restrict__ out)
{
    __shared__ __align__(16) _Float16 smem_h[2][64][HSTR];   // 33792 B
    float (*kappa)[HSTR] = (float(*)[HSTR])&smem_h[0][0][0]; // alias
    __shared__ float srel[8][8][4];
    __shared__ float swt[8][8];
    __shared__ int   sid[8][8];

    const int tid = threadIdx.x;
    const int qb8 = blockIdx.x * 8;

    if (tid < 64) {
        const int qq = tid >> 3, k = tid & 7;
        const int gq = qb8 + qq;
        const int id = kidx[gq * 8 + k];
        sid[qq][k] = id;
        swt[qq][k] = kw[gq * 8 + k];
        const int bb = gq >> 15;
        const float* pp = pts + ((size_t)bb * N_ + id) * 3;
        srel[qq][k][0] = grid_c[gq * 3 + 0] - pp[0];
        srel[qq][k][1] = grid_c[gq * 3 + 1] - pp[1];
        srel[qq][k][2] = grid_c[gq * 3 + 2] - pp[2];
    }

    const int qs = tid >> 5;
    const int dg = tid & 31;

    const float4 w1r0 = *(const float4*)(W1 + dg * 4);
    const float4 w1r1 = *(const float4*)(W1 + D_ + dg * 4);
    const float4 w1r2 = *(const float4*)(W1 + 2 * D_ + dg * 4);
    const float4 w1bb = *(const float4*)(b1 + dg * 4);
    __syncthreads();

#pragma unroll
    for (int k = 0; k < 8; ++k) {
        const float rx = srel[qs][k][0];
        const float ry = srel[qs][k][1];
        const float rz = srel[qs][k][2];
        float hr[4];
        hr[0] = gelu_f(rx * w1r0.x + ry * w1r1.x + rz * w1r2.x + w1bb.x);
        hr[1] = gelu_f(rx * w1r0.y + ry * w1r1.y + rz * w1r2.y + w1bb.y);
        hr[2] = gelu_f(rx * w1r0.z + ry * w1r1.z + rz * w1r2.z + w1bb.z);
        hr[3] = gelu_f(rx * w1r0.w + ry * w1r1.w + rz * w1r2.w + w1bb.w);
        half4_t hv, lv;
#pragma unroll
        for (int c = 0; c < 4; ++c) {
            const _Float16 hi = (_Float16)hr[c];
            hv[c] = hi;
            lv[c] = (_Float16)(hr[c] - (float)hi);
        }
        const int row = qs * 8 + k;
        *(half4_t*)&smem_h[0][row][dg * 4] = hv;
        *(half4_t*)&smem_h[1][row][dg * 4] = lv;
    }
    __syncthreads();

    const int wv   = tid >> 6;
    const int lane = tid & 63;
    const int mrow = lane & 15;
    const int kq   = lane >> 4;

    f32x4 acc[4][2];
#pragma unroll
    for (int mt = 0; mt < 4; ++mt)
#pragma unroll
        for (int ntl = 0; ntl < 2; ++ntl)
            acc[mt][ntl] = (f32x4){0.f, 0.f, 0.f, 0.f};

#pragma unroll
    for (int ntl = 0; ntl < 2; ++ntl) {
        const int n = (wv * 2 + ntl) * 16 + mrow;
        half4_t Bh[8], Bl[8];
#pragma unroll
        for (int ks = 0; ks < 8; ++ks) {
            const int off = n * D_ + ks * 16 + kq * 4;
            Bh[ks] = *(const half4_t*)(w2t_hi + off);
            Bl[ks] = *(const half4_t*)(w2t_lo + off);
        }
#pragma unroll
        for (int mt = 0; mt < 4; ++mt) {
            const int row = mt * 16 + mrow;
#pragma unroll
            for (int ks = 0; ks < 8; ++ks) {
                const int col = ks * 16 + kq * 4;
                const half4_t Ah = *(const half4_t*)&smem_h[0][row][col];
                const half4_t Al = *(const half4_t*)&smem_h[1][row][col];
                acc[mt][ntl] = __builtin_amdgcn_mfma_f32_16x16x16f16(
                    Ah, Bh[ks], acc[mt][ntl], 0, 0, 0);
                acc[mt][ntl] = __builtin_amdgcn_mfma_f32_16x16x16f16(
                    Ah, Bl[ks], acc[mt][ntl], 0, 0, 0);
                acc[mt][ntl] = __builtin_amdgcn_mfma_f32_16x16x16f16(
                    Al, Bh[ks], acc[mt][ntl], 0, 0, 0);
            }
        }
    }
    __syncthreads();

#pragma unroll
    for (int mt = 0; mt < 4; ++mt)
#pragma unroll
        for (int ntl = 0; ntl < 2; ++ntl) {
            const int col = (wv * 2 + ntl) * 16 + mrow;
#pragma unroll
            for (int r = 0; r < 4; ++r)
                kappa[mt * 16 + kq * 4 + r][col] = acc[mt][ntl][r];
        }
    __syncthreads();

    const int gq = qb8 + qs;
    const int bb = gq >> 15;
    const float4 b2v = *(const float4*)(b2 + dg * 4);

    float o0 = 0.0f, o1 = 0.0f, o2 = 0.0f, o3 = 0.0f;
#pragma unroll
    for (int k = 0; k < 8; ++k) {
        const float4 kp = *(const float4*)&kappa[qs * 8 + k][dg * 4];
        const float4 f =
            *(const float4*)(feats + ((size_t)bb * N_ + sid[qs][k]) * D_ + dg * 4);
        const float wk = swt[qs][k];
        o0 += wk * f.x * (kp.x + b2v.x);
        o1 += wk * f.y * (kp.y + b2v.y);
        o2 += wk * f.z * (kp.z + b2v.z);
        o3 += wk * f.w * (kp.w + b2v.w);
    }

    float s = o0 + o1 + o2 + o3;
#pragma unroll
    for (int off = 16; off > 0; off >>= 1) s += __shfl_xor(s, off, 32);
    const float mu = s * (1.0f / 128.0f);
    const float v0 = o0 - mu, v1 = o1 - mu, v2 = o2 - mu, v3 = o3 - mu;
    float vs = v0 * v0 + v1 * v1 + v2 * v2 + v3 * v3;
#pragma unroll
    for (int off = 16; off > 0; off >>= 1) vs += __shfl_xor(vs, off, 32);
    const float inv = 1.0f / sqrtf(vs * (1.0f / 128.0f) + 1e-5f);

    const float4 gv = *(const float4*)(gmm + dg * 4);
    const float4 bv = *(const float4*)(bta + dg * 4);
    float4 ov;
    ov.x = v0 * inv * gv.x + bv.x;
    ov.y = v1 * inv * gv.y + bv.y;
    ov.z = v2 * inv * gv.z + bv.z;
    ov.w = v3 * inv * gv.w + bv.w;
    *(float4*)(out + (size_t)gq * D_ + dg * 4) = ov;
}

// ---------------------------------------------------------------------------
extern "C" void kernel_launch(void* const* d_in, const int* in_sizes, int n_in,
                              void* d_out, int out_size, void* d_ws, size_t ws_size,
                              hipStream_t stream)
{
    (void)in_sizes; (void)n_in; (void)out_size; (void)ws_size;
    const float* grid_c = (const float*)d_in[0];
    const float* pts    = (const float*)d_in[1];
    const float* feats  = (const float*)d_in[2];
    const float* W1     = (const float*)d_in[3];
    const float* b1     = (const float*)d_in[4];
    const float* W2     = (const float*)d_in[5];
    const float* b2     = (const float*)d_in[6];
    const float* gmm    = (const float*)d_in[7];
    const float* bta    = (const float*)d_in[8];
    float* out = (float*)d_out;

    char* w = (char*)d_ws;
    int*    kidx   = (int*)(w);                  // 2 MB
    float*  kw     = (float*)(w + 2097152);      // -> 4194304
    float4* p4s    = (float4*)(w + 4194304);     // -> 4325376
    float4* q4s    = (float4*)(w + 4325376);     // -> 5373952
    int*    sidx   = (int*)(w + 5373952);        // -> 5406720
    int*    qmap   = (int*)(w + 5406720);        // -> 5668864
    int*    cstart = (int*)(w + 5668864);        // -> 5701640
    int*    qstart = (int*)(w + 5701640);        // -> 5734416
    int*    ccur   = (int*)(w + 5734416);        // -> 5767184
    int*    qcur   = (int*)(w + 5767184);        // -> 5799952
    int*    hist   = (int*)(w + 5799952);        // -> 5832720
    int*    qhist  = (int*)(w + 5832720);        // -> 5865488
    _Float16* w2t_hi = (_Float16*)(w + 5865488); // 32 KB -> 5898256
    _Float16* w2t_lo = (_Float16*)(w + 5898256); // 32 KB -> 5931024

    prep_zero<<<(2 * B_ * NC_ + 255) / 256, 256, 0, stream>>>(hist, 2 * B_ * NC_);
    prep_hist<<<(B_ * N_ + 255) / 256, 256, 0, stream>>>(pts, N_, hist);
    prep_hist<<<(B_ * M_ + 255) / 256, 256, 0, stream>>>(grid_c, M_, qhist);
    prep_w2t<<<(D_ * D_ + 255) / 256, 256, 0, stream>>>(W2, w2t_hi, w2t_lo);
    prep_scan<<<B_, 1024, 0, stream>>>(hist, cstart, ccur);
    prep_scan<<<B_, 1024, 0, stream>>>(qhist, qstart, qcur);
    prep_scatter_p<<<(B_ * N_ + 255) / 256, 256, 0, stream>>>(pts, ccur, p4s, sidx);
    prep_scatter_q<<<(B_ * M_ + 255) / 256, 256, 0, stream>>>(grid_c, qcur, q4s, qmap);
    knn_kernel<<<(B_ * NC_) / 4, 256, 0, stream>>>(q4s, qmap, p4s, sidx, cstart,
                                                   qstart, kidx, kw);
    gno_kernel<<<(B_ * M_) / 8, 256, 0, stream>>>(grid_c, pts, feats, W1, b1,
                                                  w2t_hi, w2t_lo, b2, gmm, bta,
                                                  kidx, kw, out);
}

// Round 26
// 204.975 us; speedup vs baseline: 2.8023x; 1.3613x over previous
//
#include <hip/hip_runtime.h>
#include <math.h>

#define B_ 2
#define M_ 32768
#define N_ 4096
#define D_ 128
#define K_ 8
#define G_ 16
#define NC_ 4096
#define CW_ 0.0625f
#define CAP_ 224

typedef _Float16 half4_t __attribute__((ext_vector_type(4)));
typedef float f32x4 __attribute__((ext_vector_type(4)));
typedef unsigned long long u64;

// ---------------- frozen selection semantics (verified R15) ----------------
//   sp2 = (z*z + y*y) + x*x            descending plain, no FMA
//   sg2 = (gz*gz + gy*gy) + gx*gx      descending plain, no FMA
//   dot = fma(gz,pz, fma(gy,py, gx*px))  ascending FMA chain
//   d2  = fma(dot,-2, sg2+sp2)          == (sg2+sp2) - 2*dot bitwise
//   dist= sqrtf(fmaxf(d2,0)); order by (dist, index) lexicographic.
// u64 key = (dist_bits<<32)|idx: dist>=0 so u64 order == lex(dist,idx).
// ---------------------------------------------------------------------------
__device__ __forceinline__ void lex64_insert(u64 k, u64* kd)
{
    if (k < kd[7]) {
        kd[7] = k;
#pragma unroll
        for (int u = 6; u >= 0; --u) {
            if (kd[u+1] < kd[u]) { u64 t = kd[u]; kd[u] = kd[u+1]; kd[u+1] = t; }
        }
    }
}

__device__ __forceinline__ u64 mk_key(float dist, int idx)
{
    return ((u64)__float_as_uint(dist) << 32) | (unsigned)idx;
}

__device__ __forceinline__ void fold64(u64* kd, int mask)
{
    u64 ok[8];
#pragma unroll
    for (int u = 0; u < 8; ++u) ok[u] = __shfl_xor((long long)kd[u], mask);
#pragma unroll
    for (int u = 0; u < 8; ++u) lex64_insert(ok[u], kd);
}

// ---------------------------- prep kernels ---------------------------------
__global__ __launch_bounds__(256) void prep_zero(int* __restrict__ a, int n)
{
    const int i = blockIdx.x * 256 + threadIdx.x;
    if (i < n) a[i] = 0;
}

__global__ __launch_bounds__(256) void prep_hist(
    const float* __restrict__ xyz, int n_per_b, int* __restrict__ hist)
{
    const int i = blockIdx.x * 256 + threadIdx.x;
    if (i >= B_ * n_per_b) return;
    const int b = i / n_per_b;
    const float x = xyz[i*3+0], y = xyz[i*3+1], z = xyz[i*3+2];
    const int cx = min(G_-1, (int)(x * 16.0f));
    const int cy = min(G_-1, (int)(y * 16.0f));
    const int cz = min(G_-1, (int)(z * 16.0f));
    atomicAdd(&hist[b * NC_ + cz*256 + cy*16 + cx], 1);
}

__global__ __launch_bounds__(1024) void prep_scan(
    const int* __restrict__ hist, int* __restrict__ cstart, int* __restrict__ ccur)
{
    __shared__ int lds[1024];
    const int b = blockIdx.x, t = threadIdx.x;
    int v[4]; int s = 0;
#pragma unroll
    for (int j = 0; j < 4; ++j) { v[j] = hist[b*NC_ + t*4 + j]; s += v[j]; }
    lds[t] = s;
    __syncthreads();
    for (int off = 1; off < 1024; off <<= 1) {
        int x = (t >= off) ? lds[t - off] : 0;
        __syncthreads();
        lds[t] += x;
        __syncthreads();
    }
    int excl = lds[t] - s;
#pragma unroll
    for (int j = 0; j < 4; ++j) {
        cstart[b*(NC_+1) + t*4 + j] = excl;
        ccur[b*NC_ + t*4 + j] = excl;
        excl += v[j];
    }
    if (t == 1023) cstart[b*(NC_+1) + NC_] = excl;
}

__global__ __launch_bounds__(256) void prep_scatter_p(
    const float* __restrict__ pts, int* __restrict__ ccur,
    float4* __restrict__ p4s, int* __restrict__ sidx)
{
#pragma clang fp contract(off)
    const int i = blockIdx.x * 256 + threadIdx.x;
    if (i >= B_ * N_) return;
    const int b = i >> 12, loc = i & (N_-1);
    const float x = pts[i*3+0], y = pts[i*3+1], z = pts[i*3+2];
    const int cx = min(G_-1, (int)(x * 16.0f));
    const int cy = min(G_-1, (int)(y * 16.0f));
    const int cz = min(G_-1, (int)(z * 16.0f));
    const int pos = atomicAdd(&ccur[b*NC_ + cz*256 + cy*16 + cx], 1);
    float4 v; v.x = x; v.y = y; v.z = z;
    v.w = (z * z + y * y) + x * x;              // FROZEN descending plain
    p4s[b*N_ + pos] = v;
    sidx[b*N_ + pos] = loc;
}

__global__ __launch_bounds__(256) void prep_scatter_q(
    const float* __restrict__ grid_c, int* __restrict__ qcur,
    float4* __restrict__ q4s, int* __restrict__ qmap)
{
#pragma clang fp contract(off)
    const int i = blockIdx.x * 256 + threadIdx.x;
    if (i >= B_ * M_) return;
    const int b = i >> 15;
    const float x = grid_c[i*3+0], y = grid_c[i*3+1], z = grid_c[i*3+2];
    const int cx = min(G_-1, (int)(x * 16.0f));
    const int cy = min(G_-1, (int)(y * 16.0f));
    const int cz = min(G_-1, (int)(z * 16.0f));
    const int pos = atomicAdd(&qcur[b*NC_ + cz*256 + cy*16 + cx], 1);
    float4 v; v.x = x; v.y = y; v.z = z;
    v.w = (z * z + y * y) + x * x;              // FROZEN descending plain
    q4s[(size_t)b*M_ + pos] = v;
    qmap[(size_t)b*M_ + pos] = i;
}

// W2T f16: w2t[n*128+k] = (f16)W2[k][n]
__global__ __launch_bounds__(256) void prep_w2t(
    const float* __restrict__ W2, _Float16* __restrict__ w2t_hi)
{
    const int i = blockIdx.x * 256 + threadIdx.x;
    if (i >= D_ * D_) return;
    const int n = i >> 7, k = i & 127;
    w2t_hi[i] = (_Float16)W2[k * D_ + n];
}

// ------------------------------- knn (R25 verified, unchanged) -------------
__global__ __launch_bounds__(256) void knn_kernel(
    const float4* __restrict__ q4s, const int* __restrict__ qmap,
    const float4* __restrict__ p4s, const int* __restrict__ sidx,
    const int* __restrict__ cstart, const int* __restrict__ qstart,
    int* __restrict__ out_idx, float* __restrict__ out_w)
{
#pragma clang fp contract(off)
    __shared__ float4 spt[4][CAP_];
    __shared__ int    sil[4][CAP_];
    __shared__ int    rtab[4][32][2];

    const int tid  = threadIdx.x;
    const int wv   = tid >> 6;
    const int lane = tid & 63;
    const int gci  = blockIdx.x * 4 + wv;
    const int b    = gci >> 12;
    const int cid  = gci & (NC_ - 1);
    const int cx = cid & 15, cy = (cid >> 4) & 15, cz = cid >> 8;

    const int* __restrict__ cs = cstart + b * (NC_ + 1);
    const int qs0 = qstart[b * (NC_ + 1) + cid];
    const int nq  = qstart[b * (NC_ + 1) + cid + 1] - qs0;

    const float4* p4 = p4s + (size_t)b * N_;
    const int*    sx = sidx + (size_t)b * N_;

    const int z0 = max(0, cz-2), z1 = min(G_-1, cz+2);
    const int y0 = max(0, cy-2), y1 = min(G_-1, cy+2);
    const int x0 = max(0, cx-2), x1 = min(G_-1, cx+2);
    const int ny = y1 - y0 + 1;
    const int nrows = (z1 - z0 + 1) * ny;

    int myS = 0, myLen = 0;
    if (nq > 0 && lane < nrows) {
        const int zz = z0 + lane / ny;
        const int yy = y0 + lane % ny;
        const int cb = zz*256 + yy*16;
        myS   = cs[cb + x0];
        myLen = cs[cb + x1 + 1] - myS;
    }
    int inc = myLen;
#pragma unroll
    for (int o = 1; o < 64; o <<= 1) {
        int v = __shfl_up(inc, o);
        if (lane >= o) inc += v;
    }
    const int off = inc - myLen;
    const int tot = __shfl(inc, 63);
    const bool ovf = (tot > CAP_);
    if (nq > 0 && lane < nrows) {
        rtab[wv][lane][0] = myS;
        rtab[wv][lane][1] = myLen;
        if (!ovf) {
            for (int t = 0; t < myLen; ++t) {
                spt[wv][off + t] = p4[myS + t];
                sil[wv][off + t] = sx[myS + t];
            }
        }
    }
    __syncthreads();

    const int qg  = lane >> 2;
    const int sub = lane & 3;

    for (int q0 = 0; q0 < nq; q0 += 16) {
        const bool act = (q0 + qg) < nq;
        float gx = 0.f, gy = 0.f, gz = 0.f, sg2 = 0.f;
        int qorig = 0;
        if (act) {
            const size_t slot = (size_t)b * M_ + qs0 + q0 + qg;
            const float4 qv = q4s[slot];
            gx = qv.x; gy = qv.y; gz = qv.z; sg2 = qv.w;   // FROZEN sg2
            qorig = qmap[slot];
        }

        u64 kd[8];
#pragma unroll
        for (int u = 0; u < 8; ++u) kd[u] = ~0ull;

        if (act) {
            if (!ovf) {
                const int ts = (sub * tot) >> 2;
                const int te = ((sub + 1) * tot) >> 2;
                for (int t = ts; t < te; ++t) {
                    const float4 pp = spt[wv][t];
                    const float dot  = fmaf(gz, pp.z, fmaf(gy, pp.y, gx * pp.x));
                    const float d2   = fmaf(dot, -2.0f, sg2 + pp.w);
                    const float dist = sqrtf(fmaxf(d2, 0.0f));
                    lex64_insert(mk_key(dist, sil[wv][t]), kd);
                }
            } else {
                const int r0 = (sub * nrows) >> 2;
                const int r1 = ((sub + 1) * nrows) >> 2;
                for (int r = r0; r < r1; ++r) {
                    const int gs = rtab[wv][r][0];
                    const int ln = rtab[wv][r][1];
                    for (int t = 0; t < ln; ++t) {
                        const float4 pp = p4[gs + t];
                        const float dot  = fmaf(gz, pp.z, fmaf(gy, pp.y, gx * pp.x));
                        const float d2   = fmaf(dot, -2.0f, sg2 + pp.w);
                        const float dist = sqrtf(fmaxf(d2, 0.0f));
                        lex64_insert(mk_key(dist, sx[gs + t]), kd);
                    }
                }
            }
        }
        fold64(kd, 1);
        fold64(kd, 2);

        int R = 2;
        while (R < G_ - 1) {
            const float bd7 = __uint_as_float((unsigned)(kd[7] >> 32));
            const bool need = act && !(bd7 < (float)R * CW_ - 1e-5f);
            if (!__any(need)) break;
            ++R;
            if (need) {
                u64 fk[8];
#pragma unroll
                for (int u = 0; u < 8; ++u) fk[u] = ~0ull;
                int m2 = 0;
                for (int zz = cz - R; zz <= cz + R; ++zz) {
                    if (zz < 0 || zz > G_-1) continue;
                    for (int yy = cy - R; yy <= cy + R; ++yy) {
                        if (yy < 0 || yy > G_-1) continue;
                        const int ch = max(abs(zz - cz), abs(yy - cy));
                        if (((m2++) & 3) != sub) continue;
                        const int cb = zz*256 + yy*16;
                        int s0, e0, s1 = 0, e1 = 0;
                        if (ch == R) {
                            s0 = cs[cb + max(0, cx-R)];
                            e0 = cs[cb + min(G_-1, cx+R) + 1];
                        } else {
                            const int xl = cx - R, xr = cx + R;
                            s0 = (xl >= 0)    ? cs[cb+xl]   : 0;
                            e0 = (xl >= 0)    ? cs[cb+xl+1] : 0;
                            s1 = (xr <= G_-1) ? cs[cb+xr]   : 0;
                            e1 = (xr <= G_-1) ? cs[cb+xr+1] : 0;
                        }
                        for (int t = s0; t < e0; ++t) {
                            const float4 pp = p4[t];
                            const float dot  = fmaf(gz, pp.z, fmaf(gy, pp.y, gx * pp.x));
                            const float d2   = fmaf(dot, -2.0f, sg2 + pp.w);
                            const float dist = sqrtf(fmaxf(d2, 0.0f));
                            lex64_insert(mk_key(dist, sx[t]), fk);
                        }
                        for (int t = s1; t < e1; ++t) {
                            const float4 pp = p4[t];
                            const float dot  = fmaf(gz, pp.z, fmaf(gy, pp.y, gx * pp.x));
                            const float d2   = fmaf(dot, -2.0f, sg2 + pp.w);
                            const float dist = sqrtf(fmaxf(d2, 0.0f));
                            lex64_insert(mk_key(dist, sx[t]), fk);
                        }
                    }
                }
                fold64(fk, 1);
                fold64(fk, 2);
#pragma unroll
                for (int u = 0; u < 8; ++u) lex64_insert(fk[u], kd);
            }
        }

        if (act && sub == 0) {
            float wk8[8];
#pragma unroll
            for (int u = 0; u < 8; ++u) {
                const float dist = __uint_as_float((unsigned)(kd[u] >> 32));
                wk8[u] = 1.0f / (dist + 1e-6f);
            }
            float wsum = wk8[0];
#pragma unroll
            for (int u = 1; u < 8; ++u) wsum = wsum + wk8[u];
            const float winv = 1.0f / wsum;
#pragma unroll
            for (int u = 0; u < 8; ++u) {
                out_idx[qorig * 8 + u] = (int)(kd[u] & 0xffffffffu);
                out_w[qorig * 8 + u]   = wk8[u] * winv;
            }
        }
    }
}

// ------------------------- gno: PURE f16 MFMA, high occupancy --------------
// Error budget: h,W2 in f16 give kappa err ~7e-7 abs; post-LN (eps-dominated
// gain ~286) -> ~2e-4 rms, max ~1.5e-3: negligible vs 0.042 threshold.
// LDS: single h buffer [64][132] f16 (16.9KB), kappa f16 aliased -> 18.4KB
// total -> 8 blocks/CU (wave cap) = 2x occupancy of R25. 64 MFMAs (was 192).
__device__ __forceinline__ float gelu_f(float u)
{
    const float t  = u * 0.70710678118654752f;
    const float t2 = t * t;
    float p = fmaf(t2, 1.0f/9360.0f, -1.0f/1320.0f);
    p = fmaf(t2, p, 1.0f/216.0f);
    p = fmaf(t2, p, -1.0f/42.0f);
    p = fmaf(t2, p, 1.0f/10.0f);
    p = fmaf(t2, p, -1.0f/3.0f);
    p = fmaf(t2, p, 1.0f);
    float er = 1.1283791670955126f * t * p;
    if (fabsf(t) > 0.5f) er = erff(t);      // rare: skipped when execz
    return 0.5f * u * (1.0f + er);
}

#define HSTR 132
__global__ __launch_bounds__(256) void gno_kernel(
    const float* __restrict__ grid_c, const float* __restrict__ pts,
    const float* __restrict__ feats,
    const float* __restrict__ W1, const float* __restrict__ b1,
    const _Float16* __restrict__ w2t_hi,
    const float* __restrict__ b2,
    const float* __restrict__ gmm, const float* __restrict__ bta,
    const int* __restrict__ kidx, const float* __restrict__ kw,
    float* __restrict__ out)
{
    __shared__ __align__(16) _Float16 smem_h[64][HSTR];      // 16896 B
    _Float16 (*kappa)[HSTR] = (_Float16(*)[HSTR])&smem_h[0][0]; // alias
    __shared__ float srel[8][8][4];
    __shared__ float swt[8][8];
    __shared__ int   sid[8][8];

    const int tid = threadIdx.x;
    const int qb8 = blockIdx.x * 8;

    if (tid < 64) {
        const int qq = tid >> 3, k = tid & 7;
        const int gq = qb8 + qq;
        const int id = kidx[gq * 8 + k];
        sid[qq][k] = id;
        swt[qq][k] = kw[gq * 8 + k];
        const int bb = gq >> 15;
        const float* pp = pts + ((size_t)bb * N_ + id) * 3;
        srel[qq][k][0] = grid_c[gq * 3 + 0] - pp[0];
        srel[qq][k][1] = grid_c[gq * 3 + 1] - pp[1];
        srel[qq][k][2] = grid_c[gq * 3 + 2] - pp[2];
    }

    const int qs = tid >> 5;
    const int dg = tid & 31;

    const float4 w1r0 = *(const float4*)(W1 + dg * 4);
    const float4 w1r1 = *(const float4*)(W1 + D_ + dg * 4);
    const float4 w1r2 = *(const float4*)(W1 + 2 * D_ + dg * 4);
    const float4 w1bb = *(const float4*)(b1 + dg * 4);
    __syncthreads();

    // ---- Phase A: h -> f16 in LDS ---------------------------------------
#pragma unroll
    for (int k = 0; k < 8; ++k) {
        const float rx = srel[qs][k][0];
        const float ry = srel[qs][k][1];
        const float rz = srel[qs][k][2];
        half4_t hv;
        hv[0] = (_Float16)gelu_f(rx * w1r0.x + ry * w1r1.x + rz * w1r2.x + w1bb.x);
        hv[1] = (_Float16)gelu_f(rx * w1r0.y + ry * w1r1.y + rz * w1r2.y + w1bb.y);
        hv[2] = (_Float16)gelu_f(rx * w1r0.z + ry * w1r1.z + rz * w1r2.z + w1bb.z);
        hv[3] = (_Float16)gelu_f(rx * w1r0.w + ry * w1r1.w + rz * w1r2.w + w1bb.w);
        *(half4_t*)&smem_h[qs * 8 + k][dg * 4] = hv;
    }
    __syncthreads();

    // ---- MFMA: kappa = h @ W2 (pure f16, 64 MFMAs) ----------------------
    const int wv   = tid >> 6;
    const int lane = tid & 63;
    const int mrow = lane & 15;
    const int kq   = lane >> 4;

    f32x4 acc[4][2];
#pragma unroll
    for (int mt = 0; mt < 4; ++mt)
#pragma unroll
        for (int ntl = 0; ntl < 2; ++ntl)
            acc[mt][ntl] = (f32x4){0.f, 0.f, 0.f, 0.f};

#pragma unroll
    for (int ntl = 0; ntl < 2; ++ntl) {
        const int n = (wv * 2 + ntl) * 16 + mrow;
        half4_t Bh[8];
#pragma unroll
        for (int ks = 0; ks < 8; ++ks)
            Bh[ks] = *(const half4_t*)(w2t_hi + n * D_ + ks * 16 + kq * 4);
#pragma unroll
        for (int mt = 0; mt < 4; ++mt) {
            const int row = mt * 16 + mrow;
#pragma unroll
            for (int ks = 0; ks < 8; ++ks) {
                const half4_t Ah = *(const half4_t*)&smem_h[row][ks * 16 + kq * 4];
                acc[mt][ntl] = __builtin_amdgcn_mfma_f32_16x16x16f16(
                    Ah, Bh[ks], acc[mt][ntl], 0, 0, 0);
            }
        }
    }
    __syncthreads();   // all h reads done -> safe to alias kappa

    // D write (f16): row = (lane>>4)*4 + reg, col = lane&15 (m89-verified)
#pragma unroll
    for (int mt = 0; mt < 4; ++mt)
#pragma unroll
        for (int ntl = 0; ntl < 2; ++ntl) {
            const int col = (wv * 2 + ntl) * 16 + mrow;
#pragma unroll
            for (int r = 0; r < 4; ++r)
                kappa[mt * 16 + kq * 4 + r][col] = (_Float16)acc[mt][ntl][r];
        }
    __syncthreads();

    // ---- Epilogue: gather feats, weighted reduce, LayerNorm -------------
    const int gq = qb8 + qs;
    const int bb = gq >> 15;
    const float4 b2v = *(const float4*)(b2 + dg * 4);

    float o0 = 0.0f, o1 = 0.0f, o2 = 0.0f, o3 = 0.0f;
#pragma unroll
    for (int k = 0; k < 8; ++k) {
        const half4_t kp = *(const half4_t*)&kappa[qs * 8 + k][dg * 4];
        const float4 f =
            *(const float4*)(feats + ((size_t)bb * N_ + sid[qs][k]) * D_ + dg * 4);
        const float wk = swt[qs][k];
        o0 += wk * f.x * ((float)kp[0] + b2v.x);
        o1 += wk * f.y * ((float)kp[1] + b2v.y);
        o2 += wk * f.z * ((float)kp[2] + b2v.z);
        o3 += wk * f.w * ((float)kp[3] + b2v.w);
    }

    float s = o0 + o1 + o2 + o3;
#pragma unroll
    for (int off = 16; off > 0; off >>= 1) s += __shfl_xor(s, off, 32);
    const float mu = s * (1.0f / 128.0f);
    const float v0 = o0 - mu, v1 = o1 - mu, v2 = o2 - mu, v3 = o3 - mu;
    float vs = v0 * v0 + v1 * v1 + v2 * v2 + v3 * v3;
#pragma unroll
    for (int off = 16; off > 0; off >>= 1) vs += __shfl_xor(vs, off, 32);
    const float inv = 1.0f / sqrtf(vs * (1.0f / 128.0f) + 1e-5f);

    const float4 gv = *(const float4*)(gmm + dg * 4);
    const float4 bv = *(const float4*)(bta + dg * 4);
    float4 ov;
    ov.x = v0 * inv * gv.x + bv.x;
    ov.y = v1 * inv * gv.y + bv.y;
    ov.z = v2 * inv * gv.z + bv.z;
    ov.w = v3 * inv * gv.w + bv.w;
    *(float4*)(out + (size_t)gq * D_ + dg * 4) = ov;
}

// ---------------------------------------------------------------------------
extern "C" void kernel_launch(void* const* d_in, const int* in_sizes, int n_in,
                              void* d_out, int out_size, void* d_ws, size_t ws_size,
                              hipStream_t stream)
{
    (void)in_sizes; (void)n_in; (void)out_size; (void)ws_size;
    const float* grid_c = (const float*)d_in[0];
    const float* pts    = (const float*)d_in[1];
    const float* feats  = (const float*)d_in[2];
    const float* W1     = (const float*)d_in[3];
    const float* b1     = (const float*)d_in[4];
    const float* W2     = (const float*)d_in[5];
    const float* b2     = (const float*)d_in[6];
    const float* gmm    = (const float*)d_in[7];
    const float* bta    = (const float*)d_in[8];
    float* out = (float*)d_out;

    char* w = (char*)d_ws;
    int*    kidx   = (int*)(w);                  // 2 MB
    float*  kw     = (float*)(w + 2097152);      // -> 4194304
    float4* p4s    = (float4*)(w + 4194304);     // -> 4325376
    float4* q4s    = (float4*)(w + 4325376);     // -> 5373952
    int*    sidx   = (int*)(w + 5373952);        // -> 5406720
    int*    qmap   = (int*)(w + 5406720);        // -> 5668864
    int*    cstart = (int*)(w + 5668864);        // -> 5701640
    int*    qstart = (int*)(w + 5701640);        // -> 5734416
    int*    ccur   = (int*)(w + 5734416);        // -> 5767184
    int*    qcur   = (int*)(w + 5767184);        // -> 5799952
    int*    hist   = (int*)(w + 5799952);        // -> 5832720
    int*    qhist  = (int*)(w + 5832720);        // -> 5865488
    _Float16* w2t_hi = (_Float16*)(w + 5865488); // 32 KB -> 5898256

    prep_zero<<<(2 * B_ * NC_ + 255) / 256, 256, 0, stream>>>(hist, 2 * B_ * NC_);
    prep_hist<<<(B_ * N_ + 255) / 256, 256, 0, stream>>>(pts, N_, hist);
    prep_hist<<<(B_ * M_ + 255) / 256, 256, 0, stream>>>(grid_c, M_, qhist);
    prep_w2t<<<(D_ * D_ + 255) / 256, 256, 0, stream>>>(W2, w2t_hi);
    prep_scan<<<B_, 1024, 0, stream>>>(hist, cstart, ccur);
    prep_scan<<<B_, 1024, 0, stream>>>(qhist, qstart, qcur);
    prep_scatter_p<<<(B_ * N_ + 255) / 256, 256, 0, stream>>>(pts, ccur, p4s, sidx);
    prep_scatter_q<<<(B_ * M_ + 255) / 256, 256, 0, stream>>>(grid_c, qcur, q4s, qmap);
    knn_kernel<<<(B_ * NC_) / 4, 256, 0, stream>>>(q4s, qmap, p4s, sidx, cstart,
                                                   qstart, kidx, kw);
    gno_kernel<<<(B_ * M_) / 8, 256, 0, stream>>>(grid_c, pts, feats, W1, b1,
                                                  w2t_hi, b2, gmm, bta,
                                                  kidx, kw, out);
}

// Round 27
// 193.187 us; speedup vs baseline: 2.9732x; 1.0610x over previous
//
#include <hip/hip_runtime.h>
#include <math.h>

#define B_ 2
#define M_ 32768
#define N_ 4096
#define D_ 128
#define K_ 8
#define G_ 16
#define NC_ 4096
#define CW_ 0.0625f
#define CAP_ 224

typedef _Float16 half4_t __attribute__((ext_vector_type(4)));
typedef float f32x4 __attribute__((ext_vector_type(4)));
typedef unsigned long long u64;

// ---------------- frozen selection semantics (verified R15) ----------------
//   sp2 = (z*z + y*y) + x*x            descending plain, no FMA
//   sg2 = (gz*gz + gy*gy) + gx*gx      descending plain, no FMA
//   dot = fma(gz,pz, fma(gy,py, gx*px))  ascending FMA chain
//   d2  = fma(dot,-2, sg2+sp2)          == (sg2+sp2) - 2*dot bitwise
//   dist= sqrtf(fmaxf(d2,0)); order by (dist, index) lexicographic.
// u64 key = (dist_bits<<32)|idx: dist>=0 so u64 order == lex(dist,idx).
// ---------------------------------------------------------------------------
__device__ __forceinline__ void lex64_insert(u64 k, u64* kd)
{
    if (k < kd[7]) {
        kd[7] = k;
#pragma unroll
        for (int u = 6; u >= 0; --u) {
            if (kd[u+1] < kd[u]) { u64 t = kd[u]; kd[u] = kd[u+1]; kd[u+1] = t; }
        }
    }
}

__device__ __forceinline__ u64 mk_key(float dist, int idx)
{
    return ((u64)__float_as_uint(dist) << 32) | (unsigned)idx;
}

__device__ __forceinline__ void fold64(u64* kd, int mask)
{
    u64 ok[8];
#pragma unroll
    for (int u = 0; u < 8; ++u) ok[u] = __shfl_xor((long long)kd[u], mask);
#pragma unroll
    for (int u = 0; u < 8; ++u) lex64_insert(ok[u], kd);
}

// ---------------------------- prep kernels (fused) -------------------------
// hist_all: points -> hist[0..B), queries -> hist[B..2B) (qhist adjacent)
__global__ __launch_bounds__(256) void prep_hist_all(
    const float* __restrict__ pts, const float* __restrict__ grid_c,
    int* __restrict__ hist)
{
    const int i = blockIdx.x * 256 + threadIdx.x;
    const int NP = B_ * N_;
    if (i < NP) {
        const float x = pts[i*3+0], y = pts[i*3+1], z = pts[i*3+2];
        const int cx = min(G_-1, (int)(x * 16.0f));
        const int cy = min(G_-1, (int)(y * 16.0f));
        const int cz = min(G_-1, (int)(z * 16.0f));
        atomicAdd(&hist[(i >> 12) * NC_ + cz*256 + cy*16 + cx], 1);
    } else if (i < NP + B_ * M_) {
        const int j = i - NP;
        const float x = grid_c[j*3+0], y = grid_c[j*3+1], z = grid_c[j*3+2];
        const int cx = min(G_-1, (int)(x * 16.0f));
        const int cy = min(G_-1, (int)(y * 16.0f));
        const int cz = min(G_-1, (int)(z * 16.0f));
        atomicAdd(&hist[(B_ + (j >> 15)) * NC_ + cz*256 + cy*16 + cx], 1);
    }
}

// scan: 2*B_ blocks (points then queries); 256 thr x 16 cells; 1 barrier
__global__ __launch_bounds__(256) void prep_scan(
    const int* __restrict__ hist, int* __restrict__ cstart, int* __restrict__ ccur)
{
    __shared__ int wsum[4];
    const int b = blockIdx.x, t = threadIdx.x;
    const int lane = t & 63, wv = t >> 6;
    int v[16]; int s = 0;
#pragma unroll
    for (int j = 0; j < 16; ++j) { v[j] = hist[b*NC_ + t*16 + j]; s += v[j]; }
    int inc = s;
#pragma unroll
    for (int o = 1; o < 64; o <<= 1) {
        int x = __shfl_up(inc, o);
        if (lane >= o) inc += x;
    }
    if (lane == 63) wsum[wv] = inc;
    __syncthreads();
    int woff = 0;
    for (int w2 = 0; w2 < wv; ++w2) woff += wsum[w2];
    int excl = woff + inc - s;
#pragma unroll
    for (int j = 0; j < 16; ++j) {
        cstart[b*(NC_+1) + t*16 + j] = excl;
        ccur[b*NC_ + t*16 + j] = excl;
        excl += v[j];
    }
    if (t == 255) cstart[b*(NC_+1) + NC_] = excl;
}

// scatter_all: points, then queries, then w2t pack
__global__ __launch_bounds__(256) void prep_scatter_all(
    const float* __restrict__ pts, const float* __restrict__ grid_c,
    const float* __restrict__ W2, int* __restrict__ ccur,
    float4* __restrict__ p4s, int* __restrict__ sidx,
    float4* __restrict__ q4s, int* __restrict__ qmap,
    _Float16* __restrict__ w2t_hi)
{
#pragma clang fp contract(off)
    const int i = blockIdx.x * 256 + threadIdx.x;
    const int NP = B_ * N_, NQ = B_ * M_;
    if (i < NP) {
        const int b = i >> 12, loc = i & (N_-1);
        const float x = pts[i*3+0], y = pts[i*3+1], z = pts[i*3+2];
        const int cx = min(G_-1, (int)(x * 16.0f));
        const int cy = min(G_-1, (int)(y * 16.0f));
        const int cz = min(G_-1, (int)(z * 16.0f));
        const int pos = atomicAdd(&ccur[b*NC_ + cz*256 + cy*16 + cx], 1);
        float4 v; v.x = x; v.y = y; v.z = z;
        v.w = (z * z + y * y) + x * x;          // FROZEN descending plain
        p4s[b*N_ + pos] = v;
        sidx[b*N_ + pos] = loc;
    } else if (i < NP + NQ) {
        const int j = i - NP;
        const int b = j >> 15;
        const float x = grid_c[j*3+0], y = grid_c[j*3+1], z = grid_c[j*3+2];
        const int cx = min(G_-1, (int)(x * 16.0f));
        const int cy = min(G_-1, (int)(y * 16.0f));
        const int cz = min(G_-1, (int)(z * 16.0f));
        const int pos = atomicAdd(&ccur[(B_ + b)*NC_ + cz*256 + cy*16 + cx], 1);
        float4 v; v.x = x; v.y = y; v.z = z;
        v.w = (z * z + y * y) + x * x;          // FROZEN descending plain
        q4s[(size_t)b*M_ + pos] = v;
        qmap[(size_t)b*M_ + pos] = j;
    } else if (i < NP + NQ + D_ * D_) {
        const int m = i - NP - NQ;
        const int n = m >> 7, k = m & 127;
        w2t_hi[m] = (_Float16)W2[k * D_ + n];
    }
}

// ------------------------------- knn (R25 verified, unchanged) -------------
__global__ __launch_bounds__(256) void knn_kernel(
    const float4* __restrict__ q4s, const int* __restrict__ qmap,
    const float4* __restrict__ p4s, const int* __restrict__ sidx,
    const int* __restrict__ cstart, const int* __restrict__ qstart,
    int* __restrict__ out_idx, float* __restrict__ out_w)
{
#pragma clang fp contract(off)
    __shared__ float4 spt[4][CAP_];
    __shared__ int    sil[4][CAP_];
    __shared__ int    rtab[4][32][2];

    const int tid  = threadIdx.x;
    const int wv   = tid >> 6;
    const int lane = tid & 63;
    const int gci  = blockIdx.x * 4 + wv;
    const int b    = gci >> 12;
    const int cid  = gci & (NC_ - 1);
    const int cx = cid & 15, cy = (cid >> 4) & 15, cz = cid >> 8;

    const int* __restrict__ cs = cstart + b * (NC_ + 1);
    const int qs0 = qstart[b * (NC_ + 1) + cid];
    const int nq  = qstart[b * (NC_ + 1) + cid + 1] - qs0;

    const float4* p4 = p4s + (size_t)b * N_;
    const int*    sx = sidx + (size_t)b * N_;

    const int z0 = max(0, cz-2), z1 = min(G_-1, cz+2);
    const int y0 = max(0, cy-2), y1 = min(G_-1, cy+2);
    const int x0 = max(0, cx-2), x1 = min(G_-1, cx+2);
    const int ny = y1 - y0 + 1;
    const int nrows = (z1 - z0 + 1) * ny;

    int myS = 0, myLen = 0;
    if (nq > 0 && lane < nrows) {
        const int zz = z0 + lane / ny;
        const int yy = y0 + lane % ny;
        const int cb = zz*256 + yy*16;
        myS   = cs[cb + x0];
        myLen = cs[cb + x1 + 1] - myS;
    }
    int inc = myLen;
#pragma unroll
    for (int o = 1; o < 64; o <<= 1) {
        int v = __shfl_up(inc, o);
        if (lane >= o) inc += v;
    }
    const int off = inc - myLen;
    const int tot = __shfl(inc, 63);
    const bool ovf = (tot > CAP_);
    if (nq > 0 && lane < nrows) {
        rtab[wv][lane][0] = myS;
        rtab[wv][lane][1] = myLen;
        if (!ovf) {
            for (int t = 0; t < myLen; ++t) {
                spt[wv][off + t] = p4[myS + t];
                sil[wv][off + t] = sx[myS + t];
            }
        }
    }
    __syncthreads();

    const int qg  = lane >> 2;
    const int sub = lane & 3;

    for (int q0 = 0; q0 < nq; q0 += 16) {
        const bool act = (q0 + qg) < nq;
        float gx = 0.f, gy = 0.f, gz = 0.f, sg2 = 0.f;
        int qorig = 0;
        if (act) {
            const size_t slot = (size_t)b * M_ + qs0 + q0 + qg;
            const float4 qv = q4s[slot];
            gx = qv.x; gy = qv.y; gz = qv.z; sg2 = qv.w;   // FROZEN sg2
            qorig = qmap[slot];
        }

        u64 kd[8];
#pragma unroll
        for (int u = 0; u < 8; ++u) kd[u] = ~0ull;

        if (act) {
            if (!ovf) {
                const int ts = (sub * tot) >> 2;
                const int te = ((sub + 1) * tot) >> 2;
                for (int t = ts; t < te; ++t) {
                    const float4 pp = spt[wv][t];
                    const float dot  = fmaf(gz, pp.z, fmaf(gy, pp.y, gx * pp.x));
                    const float d2   = fmaf(dot, -2.0f, sg2 + pp.w);
                    const float dist = sqrtf(fmaxf(d2, 0.0f));
                    lex64_insert(mk_key(dist, sil[wv][t]), kd);
                }
            } else {
                const int r0 = (sub * nrows) >> 2;
                const int r1 = ((sub + 1) * nrows) >> 2;
                for (int r = r0; r < r1; ++r) {
                    const int gs = rtab[wv][r][0];
                    const int ln = rtab[wv][r][1];
                    for (int t = 0; t < ln; ++t) {
                        const float4 pp = p4[gs + t];
                        const float dot  = fmaf(gz, pp.z, fmaf(gy, pp.y, gx * pp.x));
                        const float d2   = fmaf(dot, -2.0f, sg2 + pp.w);
                        const float dist = sqrtf(fmaxf(d2, 0.0f));
                        lex64_insert(mk_key(dist, sx[gs + t]), kd);
                    }
                }
            }
        }
        fold64(kd, 1);
        fold64(kd, 2);

        int R = 2;
        while (R < G_ - 1) {
            const float bd7 = __uint_as_float((unsigned)(kd[7] >> 32));
            const bool need = act && !(bd7 < (float)R * CW_ - 1e-5f);
            if (!__any(need)) break;
            ++R;
            if (need) {
                u64 fk[8];
#pragma unroll
                for (int u = 0; u < 8; ++u) fk[u] = ~0ull;
                int m2 = 0;
                for (int zz = cz - R; zz <= cz + R; ++zz) {
                    if (zz < 0 || zz > G_-1) continue;
                    for (int yy = cy - R; yy <= cy + R; ++yy) {
                        if (yy < 0 || yy > G_-1) continue;
                        const int ch = max(abs(zz - cz), abs(yy - cy));
                        if (((m2++) & 3) != sub) continue;
                        const int cb = zz*256 + yy*16;
                        int s0, e0, s1 = 0, e1 = 0;
                        if (ch == R) {
                            s0 = cs[cb + max(0, cx-R)];
                            e0 = cs[cb + min(G_-1, cx+R) + 1];
                        } else {
                            const int xl = cx - R, xr = cx + R;
                            s0 = (xl >= 0)    ? cs[cb+xl]   : 0;
                            e0 = (xl >= 0)    ? cs[cb+xl+1] : 0;
                            s1 = (xr <= G_-1) ? cs[cb+xr]   : 0;
                            e1 = (xr <= G_-1) ? cs[cb+xr+1] : 0;
                        }
                        for (int t = s0; t < e0; ++t) {
                            const float4 pp = p4[t];
                            const float dot  = fmaf(gz, pp.z, fmaf(gy, pp.y, gx * pp.x));
                            const float d2   = fmaf(dot, -2.0f, sg2 + pp.w);
                            const float dist = sqrtf(fmaxf(d2, 0.0f));
                            lex64_insert(mk_key(dist, sx[t]), fk);
                        }
                        for (int t = s1; t < e1; ++t) {
                            const float4 pp = p4[t];
                            const float dot  = fmaf(gz, pp.z, fmaf(gy, pp.y, gx * pp.x));
                            const float d2   = fmaf(dot, -2.0f, sg2 + pp.w);
                            const float dist = sqrtf(fmaxf(d2, 0.0f));
                            lex64_insert(mk_key(dist, sx[t]), fk);
                        }
                    }
                }
                fold64(fk, 1);
                fold64(fk, 2);
#pragma unroll
                for (int u = 0; u < 8; ++u) lex64_insert(fk[u], kd);
            }
        }

        if (act && sub == 0) {
            float wk8[8];
#pragma unroll
            for (int u = 0; u < 8; ++u) {
                const float dist = __uint_as_float((unsigned)(kd[u] >> 32));
                wk8[u] = 1.0f / (dist + 1e-6f);
            }
            float wsum = wk8[0];
#pragma unroll
            for (int u = 1; u < 8; ++u) wsum = wsum + wk8[u];
            const float winv = 1.0f / wsum;
#pragma unroll
            for (int u = 0; u < 8; ++u) {
                out_idx[qorig * 8 + u] = (int)(kd[u] & 0xffffffffu);
                out_w[qorig * 8 + u]   = wk8[u] * winv;
            }
        }
    }
}

// ------------------------- gno: f16 MFMA + packed-f16 GELU -----------------
// GELU in packed f16: |t| <= ~0.15 in practice, 3-term erf series truncation
// (5e-5 rel) is below f16 rounding of h (2.4e-4) which we already apply.
// Guarded f32-erff fallback for |u| > 0.5 (never in practice; execz-skipped).
#define HSTR 132
__global__ __launch_bounds__(256) void gno_kernel(
    const float* __restrict__ grid_c, const float* __restrict__ pts,
    const float* __restrict__ feats,
    const float* __restrict__ W1, const float* __restrict__ b1,
    const _Float16* __restrict__ w2t_hi,
    const float* __restrict__ b2,
    const float* __restrict__ gmm, const float* __restrict__ bta,
    const int* __restrict__ kidx, const float* __restrict__ kw,
    float* __restrict__ out)
{
    __shared__ __align__(16) _Float16 smem_h[64][HSTR];      // 16896 B
    _Float16 (*kappa)[HSTR] = (_Float16(*)[HSTR])&smem_h[0][0]; // alias
    __shared__ float srel[8][8][4];
    __shared__ float swt[8][8];
    __shared__ int   sid[8][8];

    const int tid = threadIdx.x;
    const int qb8 = blockIdx.x * 8;

    if (tid < 64) {
        const int qq = tid >> 3, k = tid & 7;
        const int gq = qb8 + qq;
        const int id = kidx[gq * 8 + k];
        sid[qq][k] = id;
        swt[qq][k] = kw[gq * 8 + k];
        const int bb = gq >> 15;
        const float* pp = pts + ((size_t)bb * N_ + id) * 3;
        srel[qq][k][0] = grid_c[gq * 3 + 0] - pp[0];
        srel[qq][k][1] = grid_c[gq * 3 + 1] - pp[1];
        srel[qq][k][2] = grid_c[gq * 3 + 2] - pp[2];
    }

    const int qs = tid >> 5;
    const int dg = tid & 31;

    const float4 w1r0 = *(const float4*)(W1 + dg * 4);
    const float4 w1r1 = *(const float4*)(W1 + D_ + dg * 4);
    const float4 w1r2 = *(const float4*)(W1 + 2 * D_ + dg * 4);
    const float4 w1bb = *(const float4*)(b1 + dg * 4);
    __syncthreads();

    // ---- Phase A: h via packed-f16 GELU -> LDS --------------------------
#pragma unroll
    for (int k = 0; k < 8; ++k) {
        const float rx = srel[qs][k][0];
        const float ry = srel[qs][k][1];
        const float rz = srel[qs][k][2];
        const float u0 = rx * w1r0.x + ry * w1r1.x + rz * w1r2.x + w1bb.x;
        const float u1 = rx * w1r0.y + ry * w1r1.y + rz * w1r2.y + w1bb.y;
        const float u2 = rx * w1r0.z + ry * w1r1.z + rz * w1r2.z + w1bb.z;
        const float u3 = rx * w1r0.w + ry * w1r1.w + rz * w1r2.w + w1bb.w;
        half4_t uh;
        uh[0] = (_Float16)u0; uh[1] = (_Float16)u1;
        uh[2] = (_Float16)u2; uh[3] = (_Float16)u3;
        const half4_t t  = uh * (_Float16)0.70710678118654752f;
        const half4_t t2 = t * t;
        half4_t p = t2 * (_Float16)0.1f + (_Float16)(-1.0f/3.0f);
        p = t2 * p + (_Float16)1.0f;
        const half4_t er = (t * p) * (_Float16)1.1283791670955126f;
        half4_t hv = (uh * (_Float16)0.5f) * (er + (_Float16)1.0f);
        // safety: exact f32 path if |u| large (never fires for this data)
        const float am = fmaxf(fmaxf(fabsf(u0), fabsf(u1)),
                               fmaxf(fabsf(u2), fabsf(u3)));
        if (am > 0.5f) {
            hv[0] = (_Float16)(0.5f*u0*(1.0f+erff(u0*0.70710678118654752f)));
            hv[1] = (_Float16)(0.5f*u1*(1.0f+erff(u1*0.70710678118654752f)));
            hv[2] = (_Float16)(0.5f*u2*(1.0f+erff(u2*0.70710678118654752f)));
            hv[3] = (_Float16)(0.5f*u3*(1.0f+erff(u3*0.70710678118654752f)));
        }
        *(half4_t*)&smem_h[qs * 8 + k][dg * 4] = hv;
    }
    __syncthreads();

    // ---- MFMA: kappa = h @ W2 (pure f16, 64 MFMAs) ----------------------
    const int wv   = tid >> 6;
    const int lane = tid & 63;
    const int mrow = lane & 15;
    const int kq   = lane >> 4;

    f32x4 acc[4][2];
#pragma unroll
    for (int mt = 0; mt < 4; ++mt)
#pragma unroll
        for (int ntl = 0; ntl < 2; ++ntl)
            acc[mt][ntl] = (f32x4){0.f, 0.f, 0.f, 0.f};

#pragma unroll
    for (int ntl = 0; ntl < 2; ++ntl) {
        const int n = (wv * 2 + ntl) * 16 + mrow;
        half4_t Bh[8];
#pragma unroll
        for (int ks = 0; ks < 8; ++ks)
            Bh[ks] = *(const half4_t*)(w2t_hi + n * D_ + ks * 16 + kq * 4);
#pragma unroll
        for (int mt = 0; mt < 4; ++mt) {
            const int row = mt * 16 + mrow;
#pragma unroll
            for (int ks = 0; ks < 8; ++ks) {
                const half4_t Ah = *(const half4_t*)&smem_h[row][ks * 16 + kq * 4];
                acc[mt][ntl] = __builtin_amdgcn_mfma_f32_16x16x16f16(
                    Ah, Bh[ks], acc[mt][ntl], 0, 0, 0);
            }
        }
    }
    __syncthreads();   // all h reads done -> safe to alias kappa

    // D write (f16): row = (lane>>4)*4 + reg, col = lane&15 (m89-verified)
#pragma unroll
    for (int mt = 0; mt < 4; ++mt)
#pragma unroll
        for (int ntl = 0; ntl < 2; ++ntl) {
            const int col = (wv * 2 + ntl) * 16 + mrow;
#pragma unroll
            for (int r = 0; r < 4; ++r)
                kappa[mt * 16 + kq * 4 + r][col] = (_Float16)acc[mt][ntl][r];
        }
    __syncthreads();

    // ---- Epilogue: gather feats, weighted reduce, LayerNorm -------------
    const int gq = qb8 + qs;
    const int bb = gq >> 15;
    const float4 b2v = *(const float4*)(b2 + dg * 4);

    float o0 = 0.0f, o1 = 0.0f, o2 = 0.0f, o3 = 0.0f;
#pragma unroll
    for (int k = 0; k < 8; ++k) {
        const half4_t kp = *(const half4_t*)&kappa[qs * 8 + k][dg * 4];
        const float4 f =
            *(const float4*)(feats + ((size_t)bb * N_ + sid[qs][k]) * D_ + dg * 4);
        const float wk = swt[qs][k];
        o0 += wk * f.x * ((float)kp[0] + b2v.x);
        o1 += wk * f.y * ((float)kp[1] + b2v.y);
        o2 += wk * f.z * ((float)kp[2] + b2v.z);
        o3 += wk * f.w * ((float)kp[3] + b2v.w);
    }

    float s = o0 + o1 + o2 + o3;
#pragma unroll
    for (int off = 16; off > 0; off >>= 1) s += __shfl_xor(s, off, 32);
    const float mu = s * (1.0f / 128.0f);
    const float v0 = o0 - mu, v1 = o1 - mu, v2 = o2 - mu, v3 = o3 - mu;
    float vs = v0 * v0 + v1 * v1 + v2 * v2 + v3 * v3;
#pragma unroll
    for (int off = 16; off > 0; off >>= 1) vs += __shfl_xor(vs, off, 32);
    const float inv = 1.0f / sqrtf(vs * (1.0f / 128.0f) + 1e-5f);

    const float4 gv = *(const float4*)(gmm + dg * 4);
    const float4 bv = *(const float4*)(bta + dg * 4);
    float4 ov;
    ov.x = v0 * inv * gv.x + bv.x;
    ov.y = v1 * inv * gv.y + bv.y;
    ov.z = v2 * inv * gv.z + bv.z;
    ov.w = v3 * inv * gv.w + bv.w;
    *(float4*)(out + (size_t)gq * D_ + dg * 4) = ov;
}

// ---------------------------------------------------------------------------
extern "C" void kernel_launch(void* const* d_in, const int* in_sizes, int n_in,
                              void* d_out, int out_size, void* d_ws, size_t ws_size,
                              hipStream_t stream)
{
    (void)in_sizes; (void)n_in; (void)out_size; (void)ws_size;
    const float* grid_c = (const float*)d_in[0];
    const float* pts    = (const float*)d_in[1];
    const float* feats  = (const float*)d_in[2];
    const float* W1     = (const float*)d_in[3];
    const float* b1     = (const float*)d_in[4];
    const float* W2     = (const float*)d_in[5];
    const float* b2     = (const float*)d_in[6];
    const float* gmm    = (const float*)d_in[7];
    const float* bta    = (const float*)d_in[8];
    float* out = (float*)d_out;

    char* w = (char*)d_ws;
    int*    kidx   = (int*)(w);                  // 2 MB
    float*  kw     = (float*)(w + 2097152);      // -> 4194304
    float4* p4s    = (float4*)(w + 4194304);     // -> 4325376
    float4* q4s    = (float4*)(w + 4325376);     // -> 5373952
    int*    sidx   = (int*)(w + 5373952);        // -> 5406720
    int*    qmap   = (int*)(w + 5406720);        // -> 5668864
    int*    cstart = (int*)(w + 5668864);        // [2][NC+1] -> 5701640
    int*    qstart = (int*)(w + 5701640);        // [2][NC+1] -> 5734416
    int*    ccur   = (int*)(w + 5734416);        // [2][NC]   -> 5767184
    int*    qcur   = (int*)(w + 5767184);        // [2][NC]   -> 5799952
    int*    hist   = (int*)(w + 5799952);        // [2][NC]   -> 5832720
    int*    qhist  = (int*)(w + 5832720);        // [2][NC]   -> 5865488
    _Float16* w2t_hi = (_Float16*)(w + 5865488); // 32 KB -> 5898256
    (void)qhist; (void)qcur;

    // hist/qhist adjacent -> one memset; scans/scatters treat them as [4][NC]
    hipMemsetAsync(hist, 0, (size_t)2 * B_ * NC_ * sizeof(int), stream);
    prep_hist_all<<<(B_ * (N_ + M_) + 255) / 256, 256, 0, stream>>>(
        pts, grid_c, hist);
    // cstart/qstart adjacent, ccur/qcur adjacent -> 2*B_ blocks in one launch
    prep_scan<<<2 * B_, 256, 0, stream>>>(hist, cstart, ccur);
    prep_scatter_all<<<(B_ * (N_ + M_) + D_ * D_ + 255) / 256, 256, 0, stream>>>(
        pts, grid_c, W2, ccur, p4s, sidx, q4s, qmap, w2t_hi);
    knn_kernel<<<(B_ * NC_) / 4, 256, 0, stream>>>(q4s, qmap, p4s, sidx, cstart,
                                                   qstart, kidx, kw);
    gno_kernel<<<(B_ * M_) / 8, 256, 0, stream>>>(grid_c, pts, feats, W1, b1,
                                                  w2t_hi, b2, gmm, bta,
                                                  kidx, kw, out);
}